// Round 8
// baseline (248.899 us; speedup 1.0000x reference)
//
#include <hip/hip_runtime.h>

// FullAttention_Spatial: N=4, L=S=1024, H=16, E=D=64, NUM_POS=2, fp32 in/out.
//
// score = temp*(QK + attn_mask[l,s] + klm[n,s]) + pos_table[pos[n,l,s]][h]
// pos in {0,1} => bias = T0[h] + bit*(T1[h]-T0[h]); T0 cancels in softmax.
// Log2-domain softmax; Q pre-scaled by temp2 = temp*log2e.
//
// R7: S-split for occupancy. Block = 2 waves on the SAME 32 q-rows; wave w
// sweeps s-tiles [w*8, w*8+8). Grid 2048 -> 4096 waves -> 4 waves/SIMD.
// Exact (m,l,O) merge via one LDS exchange + single barrier at the end.
// Reg-resident K/V fragments (prepacked fragment order, no K/V LDS, no
// per-tile barriers), cross-tile pipeline QK(T) || PV(T-1), P in-register
// via permlane32_swap. CM-zero flag skips all mask bias work when masks==0.
//
// Fragment layouts (shorts, per (n,h) panel of 65536):
//  Kp: ((t*4+ks)*2+sh)*512 + (h5*32+s31)*8  holds K[s=t*64+sh*32+s31][e=ks*16+h5*8+j]
//  Vt: ((t*4+ks)*2+dh)*512 + (h5*32+d31)*8  holds V^T[d=dh*32+d31][s=t*64+ks*16+h5*8+j]
// MFMA 32x32x16: C col=lane&31, row=(reg&3)+8*(reg>>2)+4*(lane>>5);
// A row=lane&31, k=8*(lane>>5)+j; B col=lane&31, k=8*(lane>>5)+j.

typedef __attribute__((ext_vector_type(8))) __bf16 bf16x8;
typedef __attribute__((ext_vector_type(16))) float f32x16;
typedef __attribute__((ext_vector_type(4))) unsigned int u32x4;

#define TEMP2 (0.125f * 1.4426950408889634f)
#define LG2E 1.4426950408889634f

static __device__ __forceinline__ unsigned short f2bf(float x) {
  unsigned int u = __builtin_bit_cast(unsigned int, x);
  u += 0x7FFFu + ((u >> 16) & 1u);
  return (unsigned short)(u >> 16);
}
static __device__ __forceinline__ unsigned int cvtpk(float lo, float hi) {
  unsigned int r;
  asm("v_cvt_pk_bf16_f32 %0, %1, %2" : "=v"(r) : "v"(lo), "v"(hi));
  return r;
}
// After: a = {a.lo32, b.lo32}, b = {a.hi32, b.hi32}
static __device__ __forceinline__ void plswap(unsigned int& a, unsigned int& b) {
  asm("v_permlane32_swap_b32 %0, %1" : "+v"(a), "+v"(b));
}

// ---------------- fused prepass ----------------
__global__ __launch_bounds__(256) void k_prep(
    const int* __restrict__ pos, unsigned int* __restrict__ pospk,
    const float* __restrict__ K, unsigned short* __restrict__ Kp,
    const float* __restrict__ V, unsigned short* __restrict__ Vt,
    const float* __restrict__ mask, const float* __restrict__ klm,
    unsigned short* __restrict__ CM, int* __restrict__ cmflag, int use_cm) {
  __shared__ float ld[64][65];
  int b = blockIdx.x;
  int tid = threadIdx.x;
  if (b < 256) {
    // ---- K -> fragment order ----
    int idx = b * 256 + tid;           // ((n*1024+s)*16+h)
    int s = (idx >> 4) & 1023;
    const float* src = K + idx * 64;
    unsigned short row[64];
#pragma unroll
    for (int j = 0; j < 16; ++j) {
      float4 v = *(const float4*)(src + j * 4);
      row[j*4+0] = f2bf(v.x); row[j*4+1] = f2bf(v.y);
      row[j*4+2] = f2bf(v.z); row[j*4+3] = f2bf(v.w);
    }
    int n = idx >> 14, h = idx & 15;
    unsigned short* panel = Kp + (n * 16 + h) * 65536;
    int t = s >> 6, sh = (s >> 5) & 1, s31 = s & 31;
#pragma unroll
    for (int bb = 0; bb < 8; ++bb) {
      int ks = bb >> 1, hf = bb & 1;
      int off = ((t * 4 + ks) * 2 + sh) * 512 + (hf * 32 + s31) * 8;
      *(u32x4*)(panel + off) = *(const u32x4*)(&row[bb * 8]);
    }
  } else if (b < 1280) {
    // ---- V transpose -> fragment order ----
    int vb = b - 256;
    int t = vb & 15, h = (vb >> 4) & 15, n = vb >> 8;
    {
      int s = tid >> 2, dq = (tid & 3) * 16;
      const float* src = V + ((n * 1024 + t * 64 + s) * 16 + h) * 64 + dq;
#pragma unroll
      for (int j = 0; j < 4; ++j) {
        float4 v = *(const float4*)(src + j * 4);
        ld[s][dq + j*4 + 0] = v.x; ld[s][dq + j*4 + 1] = v.y;
        ld[s][dq + j*4 + 2] = v.z; ld[s][dq + j*4 + 3] = v.w;
      }
    }
    __syncthreads();
    {
      int d = tid >> 2, sq = (tid & 3) * 16;
      unsigned short vals[16];
#pragma unroll
      for (int k = 0; k < 16; ++k) vals[k] = f2bf(ld[sq + k][d]);
      unsigned short* panel = Vt + (n * 16 + h) * 65536;
      int dh = d >> 5, d31 = d & 31;
#pragma unroll
      for (int cb = 0; cb < 2; ++cb) {
        int sl = sq + cb * 8;
        int ks = sl >> 4, hf = (sl >> 3) & 1;
        int off = ((t * 4 + ks) * 2 + dh) * 512 + (hf * 32 + d31) * 8;
        *(u32x4*)(panel + off) = *(const u32x4*)(&vals[cb * 8]);
      }
    }
  } else if (b < 2304) {
    // ---- combined mask (bf16, pre-scaled) + nonzero flag ----
    int flat = (b - 1280) * 256 * 16 + tid * 16;
    int n = flat >> 20, l = (flat >> 10) & 1023, s0 = flat & 1023;
    const float* mrow = mask + l * 1024 + s0;
    const float* krow = klm + n * 1024 + s0;
    float acc = 0.f;
    unsigned int o[8];
#pragma unroll
    for (int j = 0; j < 4; ++j) {
      float4 mv = *(const float4*)(mrow + j * 4);
      float4 kv = *(const float4*)(krow + j * 4);
      acc += __builtin_fabsf(mv.x) + __builtin_fabsf(mv.y) +
             __builtin_fabsf(mv.z) + __builtin_fabsf(mv.w) +
             __builtin_fabsf(kv.x) + __builtin_fabsf(kv.y) +
             __builtin_fabsf(kv.z) + __builtin_fabsf(kv.w);
      o[j*2+0] = cvtpk((mv.x + kv.x) * TEMP2, (mv.y + kv.y) * TEMP2);
      o[j*2+1] = cvtpk((mv.z + kv.z) * TEMP2, (mv.w + kv.w) * TEMP2);
    }
    if (use_cm) {
      *(u32x4*)(CM + flat)     = *(const u32x4*)(&o[0]);
      *(u32x4*)(CM + flat + 8) = *(const u32x4*)(&o[4]);
    }
    if (cmflag) {
      unsigned long long bal = __ballot(acc != 0.f);
      if ((tid & 63) == 0 && bal != 0ull) atomicOr(cmflag, 1);
    }
  } else {
    // ---- pack pos bits ----
    int gi = (b - 2304) * 256 + tid;
    int v = pos[gi];
    unsigned long long m = __ballot(v & 1);
    int lane = tid & 63;
    if (lane == 0) pospk[gi >> 5] = (unsigned int)m;
    else if (lane == 32) pospk[gi >> 5] = (unsigned int)(m >> 32);
  }
}

// ---------------- main flash-attention kernel ----------------
// grid 2048 = lblk*64 + n*16 + h ; 2 waves (128 thr) on same 32 q-rows,
// wave w sweeps s-tiles [w*8, w*8+8); exact merge at end via LDS.
template <bool USE_CM>
__global__ __launch_bounds__(128, 4) void k_attn(
    const float* __restrict__ Q, const float* __restrict__ mask,
    const float* __restrict__ klm, const float* __restrict__ ptab,
    const unsigned int* __restrict__ pospk,
    const unsigned short* __restrict__ Kp, const unsigned short* __restrict__ Vt,
    const unsigned short* __restrict__ CMp, const int* __restrict__ cmf,
    float* __restrict__ out) {
  __shared__ float mbuf[64 * 36];      // wave1's {Oc0[16],Oc1[16],m,l} per lane

  int bid = blockIdx.x;
  int nh = bid & 63;
  int n = nh >> 4, h = nh & 15, lblk = bid >> 6;
  int tid = threadIdx.x;
  int w = tid >> 6, lane = tid & 63;
  int l31 = lane & 31, h5 = lane >> 5;
  int l = lblk * 32 + l31;             // this lane's q-row (global)
  const int ln8 = lane * 8;
  const int hcm = cmf ? *cmf : 1;      // uniform: masks nonzero anywhere?

  // Q fragments (B of swapped QK^T), pre-scaled by temp2
  const float* qrow = Q + ((n * 1024 + l) * 16 + h) * 64;
  bf16x8 qf[4];
#pragma unroll
  for (int ke = 0; ke < 4; ++ke) {
    float4 a = *(const float4*)(qrow + ke * 16 + h5 * 8);
    float4 bq = *(const float4*)(qrow + ke * 16 + h5 * 8 + 4);
    u32x4 pk;
    pk[0] = cvtpk(a.x * TEMP2, a.y * TEMP2);
    pk[1] = cvtpk(a.z * TEMP2, a.w * TEMP2);
    pk[2] = cvtpk(bq.x * TEMP2, bq.y * TEMP2);
    pk[3] = cvtpk(bq.z * TEMP2, bq.w * TEMP2);
    qf[ke] = __builtin_bit_cast(bf16x8, pk);
  }
  const float delta2 = (ptab[16 + h] - ptab[h]) * LG2E;

  float mrun = -1e30f, lrun = 0.f;
  f32x16 Oc0 = {0,0,0,0,0,0,0,0,0,0,0,0,0,0,0,0};
  f32x16 Oc1 = {0,0,0,0,0,0,0,0,0,0,0,0,0,0,0,0};
  u32x4 pfA = {0,0,0,0}, pfB = {0,0,0,0}, pfC = {0,0,0,0}, pfD = {0,0,0,0};
  u32x4 kf[2][4], vf[2][4];

  // per-wave s-range base pointers (8 tiles each)
  const unsigned short* KpT = Kp + nh * 65536 + w * 32768;
  const unsigned short* VtT = Vt + nh * 65536 + w * 32768;
  const unsigned short* CMb = USE_CM ? (CMp + (n * 1024 + l) * 1024 + w * 512) : nullptr;
  const float* mrowB = mask + l * 1024 + w * 512;
  const float* krowB = klm + n * 1024 + w * 512;
  const unsigned int* posB = pospk + (n * 1024 + l) * 32 + w * 16;
  const int h4 = h5 * 4;

#define BF(x) __builtin_bit_cast(bf16x8, x)
#define MFMA(A, B, C) __builtin_amdgcn_mfma_f32_32x32x16_bf16(A, B, C, 0, 0, 0)

  // ---- prologue: K-frags for this wave's first tile ----
  {
    const unsigned short* k0 = KpT + ln8;
#pragma unroll
    for (int ks = 0; ks < 4; ++ks) {
      kf[0][ks] = *(const u32x4*)(k0 + (ks * 2 + 0) * 512);
      kf[1][ks] = *(const u32x4*)(k0 + (ks * 2 + 1) * 512);
    }
  }

#define BODY(T, DO_PV, STG)                                                    \
  {                                                                            \
    /* current-tile pos bits + bias (issued early, consumed after MFMAs) */    \
    uint2 pwvL = *(const uint2*)(posB + (T) * 2);                              \
    uint2 cmqL[8];                                                             \
    float4 mvL[8];                                                             \
    if (hcm) {                                                                 \
      if constexpr (USE_CM) {                                                  \
        _Pragma("unroll")                                                      \
        for (int q8 = 0; q8 < 8; ++q8)                                         \
          cmqL[q8] = *(const uint2*)(CMb + (T) * 64 + (q8 >> 2) * 32 +         \
                                     (q8 & 3) * 8 + h4);                       \
      } else {                                                                 \
        _Pragma("unroll")                                                      \
        for (int r2 = 0; r2 < 4; ++r2) {                                       \
          mvL[r2]     = *(const float4*)(mrowB + (T) * 64 + r2 * 8 + h4);      \
          mvL[4 + r2] = *(const float4*)(mrowB + (T) * 64 + 32 + r2 * 8 + h4); \
        }                                                                      \
      }                                                                        \
    }                                                                          \
    const unsigned short* kN = KpT + ((T) + 1) * 4096 + ln8;                   \
    const unsigned short* vC = VtT + (T) * 4096 + ln8;                         \
    f32x16 sv0 = {0,0,0,0,0,0,0,0,0,0,0,0,0,0,0,0};                            \
    f32x16 sv1 = {0,0,0,0,0,0,0,0,0,0,0,0,0,0,0,0};                            \
    /* ---- MFMA block: QK(T) || PV(T-1); reload frags right after use ---- */ \
    __builtin_amdgcn_s_setprio(1);                                             \
    sv0 = MFMA(BF(kf[0][0]), qf[0], sv0);                                      \
    sv1 = MFMA(BF(kf[1][0]), qf[0], sv1);                                      \
    if (DO_PV) {                                                               \
      Oc0 = MFMA(BF(vf[0][0]), BF(pfA), Oc0);                                  \
      Oc1 = MFMA(BF(vf[1][0]), BF(pfA), Oc1);                                  \
    }                                                                          \
    if (STG) {                                                                 \
      kf[0][0] = *(const u32x4*)(kN + 0 * 512);                                \
      kf[1][0] = *(const u32x4*)(kN + 1 * 512);                                \
    }                                                                          \
    vf[0][0] = *(const u32x4*)(vC + 0 * 512);                                  \
    vf[1][0] = *(const u32x4*)(vC + 1 * 512);                                  \
    sv0 = MFMA(BF(kf[0][1]), qf[1], sv0);                                      \
    sv1 = MFMA(BF(kf[1][1]), qf[1], sv1);                                      \
    if (DO_PV) {                                                               \
      Oc0 = MFMA(BF(vf[0][1]), BF(pfB), Oc0);                                  \
      Oc1 = MFMA(BF(vf[1][1]), BF(pfB), Oc1);                                  \
    }                                                                          \
    if (STG) {                                                                 \
      kf[0][1] = *(const u32x4*)(kN + 2 * 512);                                \
      kf[1][1] = *(const u32x4*)(kN + 3 * 512);                                \
    }                                                                          \
    vf[0][1] = *(const u32x4*)(vC + 2 * 512);                                  \
    vf[1][1] = *(const u32x4*)(vC + 3 * 512);                                  \
    sv0 = MFMA(BF(kf[0][2]), qf[2], sv0);                                      \
    sv1 = MFMA(BF(kf[1][2]), qf[2], sv1);                                      \
    if (DO_PV) {                                                               \
      Oc0 = MFMA(BF(vf[0][2]), BF(pfC), Oc0);                                  \
      Oc1 = MFMA(BF(vf[1][2]), BF(pfC), Oc1);                                  \
    }                                                                          \
    if (STG) {                                                                 \
      kf[0][2] = *(const u32x4*)(kN + 4 * 512);                                \
      kf[1][2] = *(const u32x4*)(kN + 5 * 512);                                \
    }                                                                          \
    vf[0][2] = *(const u32x4*)(vC + 4 * 512);                                  \
    vf[1][2] = *(const u32x4*)(vC + 5 * 512);                                  \
    sv0 = MFMA(BF(kf[0][3]), qf[3], sv0);                                      \
    sv1 = MFMA(BF(kf[1][3]), qf[3], sv1);                                      \
    if (DO_PV) {                                                               \
      Oc0 = MFMA(BF(vf[0][3]), BF(pfD), Oc0);                                  \
      Oc1 = MFMA(BF(vf[1][3]), BF(pfD), Oc1);                                  \
    }                                                                          \
    if (STG) {                                                                 \
      kf[0][3] = *(const u32x4*)(kN + 6 * 512);                                \
      kf[1][3] = *(const u32x4*)(kN + 7 * 512);                                \
    }                                                                          \
    vf[0][3] = *(const u32x4*)(vC + 6 * 512);                                  \
    vf[1][3] = *(const u32x4*)(vC + 7 * 512);                                  \
    __builtin_amdgcn_s_setprio(0);                                             \
    /* ---- bias: CM (skipped when masks==0) + pos bit ---- */                 \
    if (hcm) {                                                                 \
      _Pragma("unroll")                                                        \
      for (int r2 = 0; r2 < 4; ++r2) {                                         \
        float b0[4], b1[4];                                                    \
        if constexpr (USE_CM) {                                                \
          b0[0] = __builtin_bit_cast(float, cmqL[r2].x << 16);                 \
          b0[1] = __builtin_bit_cast(float, cmqL[r2].x & 0xFFFF0000u);         \
          b0[2] = __builtin_bit_cast(float, cmqL[r2].y << 16);                 \
          b0[3] = __builtin_bit_cast(float, cmqL[r2].y & 0xFFFF0000u);         \
          b1[0] = __builtin_bit_cast(float, cmqL[4 + r2].x << 16);             \
          b1[1] = __builtin_bit_cast(float, cmqL[4 + r2].x & 0xFFFF0000u);     \
          b1[2] = __builtin_bit_cast(float, cmqL[4 + r2].y << 16);             \
          b1[3] = __builtin_bit_cast(float, cmqL[4 + r2].y & 0xFFFF0000u);     \
        } else {                                                               \
          float4 kv0 = *(const float4*)(krowB + (T) * 64 + r2 * 8 + h4);       \
          float4 kv1 = *(const float4*)(krowB + (T) * 64 + 32 + r2 * 8 + h4);  \
          b0[0] = (mvL[r2].x + kv0.x) * TEMP2;                                 \
          b0[1] = (mvL[r2].y + kv0.y) * TEMP2;                                 \
          b0[2] = (mvL[r2].z + kv0.z) * TEMP2;                                 \
          b0[3] = (mvL[r2].w + kv0.w) * TEMP2;                                 \
          b1[0] = (mvL[4 + r2].x + kv1.x) * TEMP2;                             \
          b1[1] = (mvL[4 + r2].y + kv1.y) * TEMP2;                             \
          b1[2] = (mvL[4 + r2].z + kv1.z) * TEMP2;                             \
          b1[3] = (mvL[4 + r2].w + kv1.w) * TEMP2;                             \
        }                                                                      \
        _Pragma("unroll")                                                      \
        for (int i = 0; i < 4; ++i) {                                          \
          sv0[r2 * 4 + i] += b0[i];                                            \
          sv1[r2 * 4 + i] += b1[i];                                            \
        }                                                                      \
      }                                                                        \
    }                                                                          \
    {                                                                          \
      unsigned pws0 = pwvL.x >> h4;                                            \
      unsigned pws1 = pwvL.y >> h4;                                            \
      _Pragma("unroll")                                                        \
      for (int r2 = 0; r2 < 4; ++r2)                                           \
        _Pragma("unroll")                                                      \
        for (int i = 0; i < 4; ++i) {                                          \
          float bit0 = (float)((pws0 >> (r2 * 8 + i)) & 1u);                   \
          float bit1 = (float)((pws1 >> (r2 * 8 + i)) & 1u);                   \
          sv0[r2 * 4 + i] = fmaf(bit0, delta2, sv0[r2 * 4 + i]);               \
          sv1[r2 * 4 + i] = fmaf(bit1, delta2, sv1[r2 * 4 + i]);               \
        }                                                                      \
    }                                                                          \
    /* ---- online softmax (row q: lanes l31, l31+32) ---- */                  \
    {                                                                          \
      float m8[8];                                                             \
      _Pragma("unroll")                                                        \
      for (int i = 0; i < 8; ++i)                                              \
        m8[i] = fmaxf(fmaxf(sv0[2 * i], sv0[2 * i + 1]),                       \
                      fmaxf(sv1[2 * i], sv1[2 * i + 1]));                      \
      float m4a = fmaxf(m8[0], m8[1]), m4b = fmaxf(m8[2], m8[3]);              \
      float m4c = fmaxf(m8[4], m8[5]), m4d = fmaxf(m8[6], m8[7]);              \
      float tmax = fmaxf(fmaxf(m4a, m4b), fmaxf(m4c, m4d));                    \
      tmax = fmaxf(tmax, __shfl_xor(tmax, 32));                                \
      if (!__all(tmax <= mrun + 4.0f)) {                                       \
        float mnew = fmaxf(mrun, tmax);                                        \
        float sc = __builtin_amdgcn_exp2f(mrun - mnew);                        \
        lrun *= sc;                                                            \
        Oc0 *= sc; Oc1 *= sc;                                                  \
        mrun = mnew;                                                           \
      }                                                                        \
      float s8[8];                                                             \
      _Pragma("unroll")                                                        \
      for (int i = 0; i < 8; ++i) {                                            \
        float p0 = __builtin_amdgcn_exp2f(sv0[2 * i] - mrun);                  \
        float p1 = __builtin_amdgcn_exp2f(sv0[2 * i + 1] - mrun);              \
        float p2 = __builtin_amdgcn_exp2f(sv1[2 * i] - mrun);                  \
        float p3 = __builtin_amdgcn_exp2f(sv1[2 * i + 1] - mrun);              \
        sv0[2 * i] = p0; sv0[2 * i + 1] = p1;                                  \
        sv1[2 * i] = p2; sv1[2 * i + 1] = p3;                                  \
        s8[i] = (p0 + p1) + (p2 + p3);                                         \
      }                                                                        \
      float s4a = s8[0] + s8[1], s4b = s8[2] + s8[3];                          \
      float s4c = s8[4] + s8[5], s4d = s8[6] + s8[7];                          \
      lrun += (s4a + s4b) + (s4c + s4d);   /* lane-partial; combined at end */ \
    }                                                                          \
    /* ---- pack P(T) -> pfA..pfD (pre-swapped B-frags) ---- */                \
    {                                                                          \
      unsigned a0 = cvtpk(sv0[0], sv0[1]),   a1 = cvtpk(sv0[2], sv0[3]);       \
      unsigned a2 = cvtpk(sv0[4], sv0[5]),   a3 = cvtpk(sv0[6], sv0[7]);       \
      plswap(a0, a2); plswap(a1, a3);                                          \
      pfA[0] = a0; pfA[1] = a1; pfA[2] = a2; pfA[3] = a3;                      \
      unsigned b0_ = cvtpk(sv0[8], sv0[9]),   b1_ = cvtpk(sv0[10], sv0[11]);   \
      unsigned b2_ = cvtpk(sv0[12], sv0[13]), b3_ = cvtpk(sv0[14], sv0[15]);   \
      plswap(b0_, b2_); plswap(b1_, b3_);                                      \
      pfB[0] = b0_; pfB[1] = b1_; pfB[2] = b2_; pfB[3] = b3_;                  \
      unsigned c0 = cvtpk(sv1[0], sv1[1]),   c1 = cvtpk(sv1[2], sv1[3]);       \
      unsigned c2 = cvtpk(sv1[4], sv1[5]),   c3 = cvtpk(sv1[6], sv1[7]);       \
      plswap(c0, c2); plswap(c1, c3);                                          \
      pfC[0] = c0; pfC[1] = c1; pfC[2] = c2; pfC[3] = c3;                      \
      unsigned d0 = cvtpk(sv1[8], sv1[9]),   d1 = cvtpk(sv1[10], sv1[11]);     \
      unsigned d2 = cvtpk(sv1[12], sv1[13]), d3 = cvtpk(sv1[14], sv1[15]);     \
      plswap(d0, d2); plswap(d1, d3);                                          \
      pfD[0] = d0; pfD[1] = d1; pfD[2] = d2; pfD[3] = d3;                      \
    }                                                                          \
  }

  //     T  PV STG
  BODY( 0, 0, 1)
  BODY( 1, 1, 1)
  BODY( 2, 1, 1)
  BODY( 3, 1, 1)
  BODY( 4, 1, 1)
  BODY( 5, 1, 1)
  BODY( 6, 1, 1)
  BODY( 7, 1, 0)
#undef BODY

  // ---- epilogue PV(last): vf holds this wave's tile 7 ----
  __builtin_amdgcn_s_setprio(1);
  Oc0 = MFMA(BF(vf[0][0]), BF(pfA), Oc0);
  Oc1 = MFMA(BF(vf[1][0]), BF(pfA), Oc1);
  Oc0 = MFMA(BF(vf[0][1]), BF(pfB), Oc0);
  Oc1 = MFMA(BF(vf[1][1]), BF(pfB), Oc1);
  Oc0 = MFMA(BF(vf[0][2]), BF(pfC), Oc0);
  Oc1 = MFMA(BF(vf[1][2]), BF(pfC), Oc1);
  Oc0 = MFMA(BF(vf[0][3]), BF(pfD), Oc0);
  Oc1 = MFMA(BF(vf[1][3]), BF(pfD), Oc1);
  __builtin_amdgcn_s_setprio(0);
#undef MFMA
#undef BF

  // ---- merge the two s-halves (exact) and store ----
  float lw = lrun + __shfl_xor(lrun, 32);   // full row-sum for this s-half
  if (w == 1) {
    float* row = mbuf + lane * 36;
#pragma unroll
    for (int r2 = 0; r2 < 4; ++r2) {
      *(float4*)(row + r2 * 4) =
          make_float4(Oc0[4*r2+0], Oc0[4*r2+1], Oc0[4*r2+2], Oc0[4*r2+3]);
      *(float4*)(row + 16 + r2 * 4) =
          make_float4(Oc1[4*r2+0], Oc1[4*r2+1], Oc1[4*r2+2], Oc1[4*r2+3]);
    }
    row[32] = mrun;
    row[33] = lw;
  }
  __syncthreads();
  if (w == 0) {
    const float* row = mbuf + lane * 36;
    float m1 = row[32], l1 = row[33];
    float mm = fmaxf(mrun, m1);
    float s0e = __builtin_amdgcn_exp2f(mrun - mm);
    float s1e = __builtin_amdgcn_exp2f(m1 - mm);
    float ltot = lw * s0e + l1 * s1e;
    float inv = 1.0f / ltot;
    float* orow = out + ((n * 1024 + l) * 16 + h) * 64;
#pragma unroll
    for (int r2 = 0; r2 < 4; ++r2) {
      float4 o;
      o.x = (Oc0[4*r2+0] * s0e + row[r2*4+0] * s1e) * inv;
      o.y = (Oc0[4*r2+1] * s0e + row[r2*4+1] * s1e) * inv;
      o.z = (Oc0[4*r2+2] * s0e + row[r2*4+2] * s1e) * inv;
      o.w = (Oc0[4*r2+3] * s0e + row[r2*4+3] * s1e) * inv;
      *(float4*)(orow + r2 * 8 + h4) = o;
      o.x = (Oc1[4*r2+0] * s0e + row[16+r2*4+0] * s1e) * inv;
      o.y = (Oc1[4*r2+1] * s0e + row[16+r2*4+1] * s1e) * inv;
      o.z = (Oc1[4*r2+2] * s0e + row[16+r2*4+2] * s1e) * inv;
      o.w = (Oc1[4*r2+3] * s0e + row[16+r2*4+3] * s1e) * inv;
      *(float4*)(orow + 32 + r2 * 8 + h4) = o;
    }
  }
}

extern "C" void kernel_launch(void* const* d_in, const int* in_sizes, int n_in,
                              void* d_out, int out_size, void* d_ws, size_t ws_size,
                              hipStream_t stream) {
  const float* Q    = (const float*)d_in[0];
  const float* K    = (const float*)d_in[1];
  const float* V    = (const float*)d_in[2];
  const float* mask = (const float*)d_in[3];
  const float* klm  = (const float*)d_in[4];
  const float* ptab = (const float*)d_in[5];
  const int*   pos  = (const int*)d_in[6];
  float* out = (float*)d_out;

  char* ws = (char*)d_ws;
  // layout: pospk 512K | Kp 8M | Vt 8M | flag 64B | CM 8M
  unsigned int*   pospk = (unsigned int*)ws;
  unsigned short* Kp    = (unsigned short*)(ws + (1 << 19));
  unsigned short* Vt    = (unsigned short*)(ws + (1 << 19) + (8 << 20));
  int*            cmf   = (int*)(ws + (1 << 19) + (16 << 20));
  unsigned short* CM    = (unsigned short*)(ws + (1 << 19) + (16 << 20) + 64);
  const size_t need_flag = (size_t)(1 << 19) + (size_t)(16 << 20) + 64;
  const size_t need_cm   = need_flag + (size_t)(8 << 20);
  const bool use_flag = ws_size >= need_flag;
  const bool use_cm   = ws_size >= need_cm;
  if (!use_flag) cmf = nullptr;

  if (use_flag) hipMemsetAsync(cmf, 0, 4, stream);
  k_prep<<<18688, 256, 0, stream>>>(pos, pospk, K, Kp, V, Vt, mask, klm, CM,
                                    cmf, use_cm ? 1 : 0);
  if (use_cm) {
    k_attn<true><<<2048, 128, 0, stream>>>(Q, mask, klm, ptab, pospk, Kp, Vt,
                                           CM, cmf, out);
  } else {
    k_attn<false><<<2048, 128, 0, stream>>>(Q, mask, klm, ptab, pospk, Kp, Vt,
                                            nullptr, cmf, out);
  }
}

// Round 9
// 179.536 us; speedup vs baseline: 1.3863x; 1.3863x over previous
//
#include <hip/hip_runtime.h>

// FullAttention_Spatial: N=4, L=S=1024, H=16, E=D=64, NUM_POS=2, fp32 in/out.
//
// score = temp*(QK + attn_mask[l,s] + klm[n,s]) + pos_table[pos[n,l,s]][h]
// pos in {0,1} => bias = T0[h] + bit*(T1[h]-T0[h]); T0 cancels in softmax.
// Log2-domain softmax; Q pre-scaled by temp2 = temp*log2e.
//
// R8: R7 S-split kept (2 waves/block on same 32 q-rows, wave w sweeps
// s-tiles [w*8,w*8+8), grid 2048 -> 4096 waves), but launch_bounds(128,3):
// VGPR cap 170 (natural ~155, NO spill) -> 3 waves/SIMD resident.
// R7's (128,4) capped VGPR=64 -> 622MB scratch writes -> 313us. Lesson:
// this structure needs ~150 VGPR; 4 waves/SIMD unreachable without redesign.
// Mask-bias loads moved AFTER the MFMA block (shorter live range; skipped
// entirely at runtime when masks==0 via cmflag).
//
// Fragment layouts (shorts, per (n,h) panel of 65536):
//  Kp: ((t*4+ks)*2+sh)*512 + (h5*32+s31)*8  holds K[s=t*64+sh*32+s31][e=ks*16+h5*8+j]
//  Vt: ((t*4+ks)*2+dh)*512 + (h5*32+d31)*8  holds V^T[d=dh*32+d31][s=t*64+ks*16+h5*8+j]
// MFMA 32x32x16: C col=lane&31, row=(reg&3)+8*(reg>>2)+4*(lane>>5);
// A row=lane&31, k=8*(lane>>5)+j; B col=lane&31, k=8*(lane>>5)+j.

typedef __attribute__((ext_vector_type(8))) __bf16 bf16x8;
typedef __attribute__((ext_vector_type(16))) float f32x16;
typedef __attribute__((ext_vector_type(4))) unsigned int u32x4;

#define TEMP2 (0.125f * 1.4426950408889634f)
#define LG2E 1.4426950408889634f

static __device__ __forceinline__ unsigned short f2bf(float x) {
  unsigned int u = __builtin_bit_cast(unsigned int, x);
  u += 0x7FFFu + ((u >> 16) & 1u);
  return (unsigned short)(u >> 16);
}
static __device__ __forceinline__ unsigned int cvtpk(float lo, float hi) {
  unsigned int r;
  asm("v_cvt_pk_bf16_f32 %0, %1, %2" : "=v"(r) : "v"(lo), "v"(hi));
  return r;
}
// After: a = {a.lo32, b.lo32}, b = {a.hi32, b.hi32}
static __device__ __forceinline__ void plswap(unsigned int& a, unsigned int& b) {
  asm("v_permlane32_swap_b32 %0, %1" : "+v"(a), "+v"(b));
}

// ---------------- fused prepass ----------------
__global__ __launch_bounds__(256) void k_prep(
    const int* __restrict__ pos, unsigned int* __restrict__ pospk,
    const float* __restrict__ K, unsigned short* __restrict__ Kp,
    const float* __restrict__ V, unsigned short* __restrict__ Vt,
    const float* __restrict__ mask, const float* __restrict__ klm,
    unsigned short* __restrict__ CM, int* __restrict__ cmflag, int use_cm) {
  __shared__ float ld[64][65];
  int b = blockIdx.x;
  int tid = threadIdx.x;
  if (b < 256) {
    // ---- K -> fragment order ----
    int idx = b * 256 + tid;           // ((n*1024+s)*16+h)
    int s = (idx >> 4) & 1023;
    const float* src = K + idx * 64;
    unsigned short row[64];
#pragma unroll
    for (int j = 0; j < 16; ++j) {
      float4 v = *(const float4*)(src + j * 4);
      row[j*4+0] = f2bf(v.x); row[j*4+1] = f2bf(v.y);
      row[j*4+2] = f2bf(v.z); row[j*4+3] = f2bf(v.w);
    }
    int n = idx >> 14, h = idx & 15;
    unsigned short* panel = Kp + (n * 16 + h) * 65536;
    int t = s >> 6, sh = (s >> 5) & 1, s31 = s & 31;
#pragma unroll
    for (int bb = 0; bb < 8; ++bb) {
      int ks = bb >> 1, hf = bb & 1;
      int off = ((t * 4 + ks) * 2 + sh) * 512 + (hf * 32 + s31) * 8;
      *(u32x4*)(panel + off) = *(const u32x4*)(&row[bb * 8]);
    }
  } else if (b < 1280) {
    // ---- V transpose -> fragment order ----
    int vb = b - 256;
    int t = vb & 15, h = (vb >> 4) & 15, n = vb >> 8;
    {
      int s = tid >> 2, dq = (tid & 3) * 16;
      const float* src = V + ((n * 1024 + t * 64 + s) * 16 + h) * 64 + dq;
#pragma unroll
      for (int j = 0; j < 4; ++j) {
        float4 v = *(const float4*)(src + j * 4);
        ld[s][dq + j*4 + 0] = v.x; ld[s][dq + j*4 + 1] = v.y;
        ld[s][dq + j*4 + 2] = v.z; ld[s][dq + j*4 + 3] = v.w;
      }
    }
    __syncthreads();
    {
      int d = tid >> 2, sq = (tid & 3) * 16;
      unsigned short vals[16];
#pragma unroll
      for (int k = 0; k < 16; ++k) vals[k] = f2bf(ld[sq + k][d]);
      unsigned short* panel = Vt + (n * 16 + h) * 65536;
      int dh = d >> 5, d31 = d & 31;
#pragma unroll
      for (int cb = 0; cb < 2; ++cb) {
        int sl = sq + cb * 8;
        int ks = sl >> 4, hf = (sl >> 3) & 1;
        int off = ((t * 4 + ks) * 2 + dh) * 512 + (hf * 32 + d31) * 8;
        *(u32x4*)(panel + off) = *(const u32x4*)(&vals[cb * 8]);
      }
    }
  } else if (b < 2304) {
    // ---- combined mask (bf16, pre-scaled) + nonzero flag ----
    int flat = (b - 1280) * 256 * 16 + tid * 16;
    int n = flat >> 20, l = (flat >> 10) & 1023, s0 = flat & 1023;
    const float* mrow = mask + l * 1024 + s0;
    const float* krow = klm + n * 1024 + s0;
    float acc = 0.f;
    unsigned int o[8];
#pragma unroll
    for (int j = 0; j < 4; ++j) {
      float4 mv = *(const float4*)(mrow + j * 4);
      float4 kv = *(const float4*)(krow + j * 4);
      acc += __builtin_fabsf(mv.x) + __builtin_fabsf(mv.y) +
             __builtin_fabsf(mv.z) + __builtin_fabsf(mv.w) +
             __builtin_fabsf(kv.x) + __builtin_fabsf(kv.y) +
             __builtin_fabsf(kv.z) + __builtin_fabsf(kv.w);
      o[j*2+0] = cvtpk((mv.x + kv.x) * TEMP2, (mv.y + kv.y) * TEMP2);
      o[j*2+1] = cvtpk((mv.z + kv.z) * TEMP2, (mv.w + kv.w) * TEMP2);
    }
    if (use_cm) {
      *(u32x4*)(CM + flat)     = *(const u32x4*)(&o[0]);
      *(u32x4*)(CM + flat + 8) = *(const u32x4*)(&o[4]);
    }
    if (cmflag) {
      unsigned long long bal = __ballot(acc != 0.f);
      if ((tid & 63) == 0 && bal != 0ull) atomicOr(cmflag, 1);
    }
  } else {
    // ---- pack pos bits ----
    int gi = (b - 2304) * 256 + tid;
    int v = pos[gi];
    unsigned long long m = __ballot(v & 1);
    int lane = tid & 63;
    if (lane == 0) pospk[gi >> 5] = (unsigned int)m;
    else if (lane == 32) pospk[gi >> 5] = (unsigned int)(m >> 32);
  }
}

// ---------------- main flash-attention kernel ----------------
// grid 2048 = lblk*64 + n*16 + h ; 2 waves (128 thr) on same 32 q-rows,
// wave w sweeps s-tiles [w*8, w*8+8); exact merge at end via LDS.
template <bool USE_CM>
__global__ __launch_bounds__(128, 3) void k_attn(
    const float* __restrict__ Q, const float* __restrict__ mask,
    const float* __restrict__ klm, const float* __restrict__ ptab,
    const unsigned int* __restrict__ pospk,
    const unsigned short* __restrict__ Kp, const unsigned short* __restrict__ Vt,
    const unsigned short* __restrict__ CMp, const int* __restrict__ cmf,
    float* __restrict__ out) {
  __shared__ float mbuf[64 * 36];      // wave1's {Oc0[16],Oc1[16],m,l} per lane

  int bid = blockIdx.x;
  int nh = bid & 63;
  int n = nh >> 4, h = nh & 15, lblk = bid >> 6;
  int tid = threadIdx.x;
  int w = tid >> 6, lane = tid & 63;
  int l31 = lane & 31, h5 = lane >> 5;
  int l = lblk * 32 + l31;             // this lane's q-row (global)
  const int ln8 = lane * 8;
  const int hcm = cmf ? *cmf : 1;      // uniform: masks nonzero anywhere?

  // Q fragments (B of swapped QK^T), pre-scaled by temp2
  const float* qrow = Q + ((n * 1024 + l) * 16 + h) * 64;
  bf16x8 qf[4];
#pragma unroll
  for (int ke = 0; ke < 4; ++ke) {
    float4 a = *(const float4*)(qrow + ke * 16 + h5 * 8);
    float4 bq = *(const float4*)(qrow + ke * 16 + h5 * 8 + 4);
    u32x4 pk;
    pk[0] = cvtpk(a.x * TEMP2, a.y * TEMP2);
    pk[1] = cvtpk(a.z * TEMP2, a.w * TEMP2);
    pk[2] = cvtpk(bq.x * TEMP2, bq.y * TEMP2);
    pk[3] = cvtpk(bq.z * TEMP2, bq.w * TEMP2);
    qf[ke] = __builtin_bit_cast(bf16x8, pk);
  }
  const float delta2 = (ptab[16 + h] - ptab[h]) * LG2E;

  float mrun = -1e30f, lrun = 0.f;
  f32x16 Oc0 = {0,0,0,0,0,0,0,0,0,0,0,0,0,0,0,0};
  f32x16 Oc1 = {0,0,0,0,0,0,0,0,0,0,0,0,0,0,0,0};
  u32x4 pfA = {0,0,0,0}, pfB = {0,0,0,0}, pfC = {0,0,0,0}, pfD = {0,0,0,0};
  u32x4 kf[2][4], vf[2][4];

  // per-wave s-range base pointers (8 tiles each)
  const unsigned short* KpT = Kp + nh * 65536 + w * 32768;
  const unsigned short* VtT = Vt + nh * 65536 + w * 32768;
  const unsigned short* CMb = USE_CM ? (CMp + (n * 1024 + l) * 1024 + w * 512) : nullptr;
  const float* mrowB = mask + l * 1024 + w * 512;
  const float* krowB = klm + n * 1024 + w * 512;
  const unsigned int* posB = pospk + (n * 1024 + l) * 32 + w * 16;
  const int h4 = h5 * 4;

#define BF(x) __builtin_bit_cast(bf16x8, x)
#define MFMA(A, B, C) __builtin_amdgcn_mfma_f32_32x32x16_bf16(A, B, C, 0, 0, 0)

  // ---- prologue: K-frags for this wave's first tile ----
  {
    const unsigned short* k0 = KpT + ln8;
#pragma unroll
    for (int ks = 0; ks < 4; ++ks) {
      kf[0][ks] = *(const u32x4*)(k0 + (ks * 2 + 0) * 512);
      kf[1][ks] = *(const u32x4*)(k0 + (ks * 2 + 1) * 512);
    }
  }

#define BODY(T, DO_PV, STG)                                                    \
  {                                                                            \
    uint2 pwvL = *(const uint2*)(posB + (T) * 2);                              \
    const unsigned short* kN = KpT + ((T) + 1) * 4096 + ln8;                   \
    const unsigned short* vC = VtT + (T) * 4096 + ln8;                         \
    f32x16 sv0 = {0,0,0,0,0,0,0,0,0,0,0,0,0,0,0,0};                            \
    f32x16 sv1 = {0,0,0,0,0,0,0,0,0,0,0,0,0,0,0,0};                            \
    /* ---- MFMA block: QK(T) || PV(T-1); reload frags right after use ---- */ \
    __builtin_amdgcn_s_setprio(1);                                             \
    sv0 = MFMA(BF(kf[0][0]), qf[0], sv0);                                      \
    sv1 = MFMA(BF(kf[1][0]), qf[0], sv1);                                      \
    if (DO_PV) {                                                               \
      Oc0 = MFMA(BF(vf[0][0]), BF(pfA), Oc0);                                  \
      Oc1 = MFMA(BF(vf[1][0]), BF(pfA), Oc1);                                  \
    }                                                                          \
    if (STG) {                                                                 \
      kf[0][0] = *(const u32x4*)(kN + 0 * 512);                                \
      kf[1][0] = *(const u32x4*)(kN + 1 * 512);                                \
    }                                                                          \
    vf[0][0] = *(const u32x4*)(vC + 0 * 512);                                  \
    vf[1][0] = *(const u32x4*)(vC + 1 * 512);                                  \
    sv0 = MFMA(BF(kf[0][1]), qf[1], sv0);                                      \
    sv1 = MFMA(BF(kf[1][1]), qf[1], sv1);                                      \
    if (DO_PV) {                                                               \
      Oc0 = MFMA(BF(vf[0][1]), BF(pfB), Oc0);                                  \
      Oc1 = MFMA(BF(vf[1][1]), BF(pfB), Oc1);                                  \
    }                                                                          \
    if (STG) {                                                                 \
      kf[0][1] = *(const u32x4*)(kN + 2 * 512);                                \
      kf[1][1] = *(const u32x4*)(kN + 3 * 512);                                \
    }                                                                          \
    vf[0][1] = *(const u32x4*)(vC + 2 * 512);                                  \
    vf[1][1] = *(const u32x4*)(vC + 3 * 512);                                  \
    sv0 = MFMA(BF(kf[0][2]), qf[2], sv0);                                      \
    sv1 = MFMA(BF(kf[1][2]), qf[2], sv1);                                      \
    if (DO_PV) {                                                               \
      Oc0 = MFMA(BF(vf[0][2]), BF(pfC), Oc0);                                  \
      Oc1 = MFMA(BF(vf[1][2]), BF(pfC), Oc1);                                  \
    }                                                                          \
    if (STG) {                                                                 \
      kf[0][2] = *(const u32x4*)(kN + 4 * 512);                                \
      kf[1][2] = *(const u32x4*)(kN + 5 * 512);                                \
    }                                                                          \
    vf[0][2] = *(const u32x4*)(vC + 4 * 512);                                  \
    vf[1][2] = *(const u32x4*)(vC + 5 * 512);                                  \
    sv0 = MFMA(BF(kf[0][3]), qf[3], sv0);                                      \
    sv1 = MFMA(BF(kf[1][3]), qf[3], sv1);                                      \
    if (DO_PV) {                                                               \
      Oc0 = MFMA(BF(vf[0][3]), BF(pfD), Oc0);                                  \
      Oc1 = MFMA(BF(vf[1][3]), BF(pfD), Oc1);                                  \
    }                                                                          \
    if (STG) {                                                                 \
      kf[0][3] = *(const u32x4*)(kN + 6 * 512);                                \
      kf[1][3] = *(const u32x4*)(kN + 7 * 512);                                \
    }                                                                          \
    vf[0][3] = *(const u32x4*)(vC + 6 * 512);                                  \
    vf[1][3] = *(const u32x4*)(vC + 7 * 512);                                  \
    __builtin_amdgcn_s_setprio(0);                                             \
    /* ---- bias: CM (loaded HERE, short live range; skipped if masks==0) ---- */ \
    if (hcm) {                                                                 \
      _Pragma("unroll")                                                        \
      for (int r2 = 0; r2 < 4; ++r2) {                                         \
        float b0[4], b1[4];                                                    \
        if constexpr (USE_CM) {                                                \
          uint2 c0 = *(const uint2*)(CMb + (T) * 64 + r2 * 8 + h4);            \
          uint2 c1 = *(const uint2*)(CMb + (T) * 64 + 32 + r2 * 8 + h4);       \
          b0[0] = __builtin_bit_cast(float, c0.x << 16);                       \
          b0[1] = __builtin_bit_cast(float, c0.x & 0xFFFF0000u);               \
          b0[2] = __builtin_bit_cast(float, c0.y << 16);                       \
          b0[3] = __builtin_bit_cast(float, c0.y & 0xFFFF0000u);               \
          b1[0] = __builtin_bit_cast(float, c1.x << 16);                       \
          b1[1] = __builtin_bit_cast(float, c1.x & 0xFFFF0000u);               \
          b1[2] = __builtin_bit_cast(float, c1.y << 16);                       \
          b1[3] = __builtin_bit_cast(float, c1.y & 0xFFFF0000u);               \
        } else {                                                               \
          float4 mv0 = *(const float4*)(mrowB + (T) * 64 + r2 * 8 + h4);       \
          float4 kv0 = *(const float4*)(krowB + (T) * 64 + r2 * 8 + h4);       \
          float4 mv1 = *(const float4*)(mrowB + (T) * 64 + 32 + r2 * 8 + h4);  \
          float4 kv1 = *(const float4*)(krowB + (T) * 64 + 32 + r2 * 8 + h4);  \
          b0[0] = (mv0.x + kv0.x) * TEMP2; b0[1] = (mv0.y + kv0.y) * TEMP2;    \
          b0[2] = (mv0.z + kv0.z) * TEMP2; b0[3] = (mv0.w + kv0.w) * TEMP2;    \
          b1[0] = (mv1.x + kv1.x) * TEMP2; b1[1] = (mv1.y + kv1.y) * TEMP2;    \
          b1[2] = (mv1.z + kv1.z) * TEMP2; b1[3] = (mv1.w + kv1.w) * TEMP2;    \
        }                                                                      \
        _Pragma("unroll")                                                      \
        for (int i = 0; i < 4; ++i) {                                          \
          sv0[r2 * 4 + i] += b0[i];                                            \
          sv1[r2 * 4 + i] += b1[i];                                            \
        }                                                                      \
      }                                                                        \
    }                                                                          \
    {                                                                          \
      unsigned pws0 = pwvL.x >> h4;                                            \
      unsigned pws1 = pwvL.y >> h4;                                            \
      _Pragma("unroll")                                                        \
      for (int r2 = 0; r2 < 4; ++r2)                                           \
        _Pragma("unroll")                                                      \
        for (int i = 0; i < 4; ++i) {                                          \
          float bit0 = (float)((pws0 >> (r2 * 8 + i)) & 1u);                   \
          float bit1 = (float)((pws1 >> (r2 * 8 + i)) & 1u);                   \
          sv0[r2 * 4 + i] = fmaf(bit0, delta2, sv0[r2 * 4 + i]);               \
          sv1[r2 * 4 + i] = fmaf(bit1, delta2, sv1[r2 * 4 + i]);               \
        }                                                                      \
    }                                                                          \
    /* ---- online softmax (row q: lanes l31, l31+32) ---- */                  \
    {                                                                          \
      float m8[8];                                                             \
      _Pragma("unroll")                                                        \
      for (int i = 0; i < 8; ++i)                                              \
        m8[i] = fmaxf(fmaxf(sv0[2 * i], sv0[2 * i + 1]),                       \
                      fmaxf(sv1[2 * i], sv1[2 * i + 1]));                      \
      float m4a = fmaxf(m8[0], m8[1]), m4b = fmaxf(m8[2], m8[3]);              \
      float m4c = fmaxf(m8[4], m8[5]), m4d = fmaxf(m8[6], m8[7]);              \
      float tmax = fmaxf(fmaxf(m4a, m4b), fmaxf(m4c, m4d));                    \
      tmax = fmaxf(tmax, __shfl_xor(tmax, 32));                                \
      if (!__all(tmax <= mrun + 4.0f)) {                                       \
        float mnew = fmaxf(mrun, tmax);                                        \
        float sc = __builtin_amdgcn_exp2f(mrun - mnew);                        \
        lrun *= sc;                                                            \
        Oc0 *= sc; Oc1 *= sc;                                                  \
        mrun = mnew;                                                           \
      }                                                                        \
      float s8[8];                                                             \
      _Pragma("unroll")                                                        \
      for (int i = 0; i < 8; ++i) {                                            \
        float p0 = __builtin_amdgcn_exp2f(sv0[2 * i] - mrun);                  \
        float p1 = __builtin_amdgcn_exp2f(sv0[2 * i + 1] - mrun);              \
        float p2 = __builtin_amdgcn_exp2f(sv1[2 * i] - mrun);                  \
        float p3 = __builtin_amdgcn_exp2f(sv1[2 * i + 1] - mrun);              \
        sv0[2 * i] = p0; sv0[2 * i + 1] = p1;                                  \
        sv1[2 * i] = p2; sv1[2 * i + 1] = p3;                                  \
        s8[i] = (p0 + p1) + (p2 + p3);                                         \
      }                                                                        \
      float s4a = s8[0] + s8[1], s4b = s8[2] + s8[3];                          \
      float s4c = s8[4] + s8[5], s4d = s8[6] + s8[7];                          \
      lrun += (s4a + s4b) + (s4c + s4d);   /* lane-partial; combined at end */ \
    }                                                                          \
    /* ---- pack P(T) -> pfA..pfD (pre-swapped B-frags) ---- */                \
    {                                                                          \
      unsigned a0 = cvtpk(sv0[0], sv0[1]),   a1 = cvtpk(sv0[2], sv0[3]);       \
      unsigned a2 = cvtpk(sv0[4], sv0[5]),   a3 = cvtpk(sv0[6], sv0[7]);       \
      plswap(a0, a2); plswap(a1, a3);                                          \
      pfA[0] = a0; pfA[1] = a1; pfA[2] = a2; pfA[3] = a3;                      \
      unsigned b0_ = cvtpk(sv0[8], sv0[9]),   b1_ = cvtpk(sv0[10], sv0[11]);   \
      unsigned b2_ = cvtpk(sv0[12], sv0[13]), b3_ = cvtpk(sv0[14], sv0[15]);   \
      plswap(b0_, b2_); plswap(b1_, b3_);                                      \
      pfB[0] = b0_; pfB[1] = b1_; pfB[2] = b2_; pfB[3] = b3_;                  \
      unsigned c0 = cvtpk(sv1[0], sv1[1]),   c1 = cvtpk(sv1[2], sv1[3]);       \
      unsigned c2 = cvtpk(sv1[4], sv1[5]),   c3 = cvtpk(sv1[6], sv1[7]);       \
      plswap(c0, c2); plswap(c1, c3);                                          \
      pfC[0] = c0; pfC[1] = c1; pfC[2] = c2; pfC[3] = c3;                      \
      unsigned d0 = cvtpk(sv1[8], sv1[9]),   d1 = cvtpk(sv1[10], sv1[11]);     \
      unsigned d2 = cvtpk(sv1[12], sv1[13]), d3 = cvtpk(sv1[14], sv1[15]);     \
      plswap(d0, d2); plswap(d1, d3);                                          \
      pfD[0] = d0; pfD[1] = d1; pfD[2] = d2; pfD[3] = d3;                      \
    }                                                                          \
  }

  //     T  PV STG
  BODY( 0, 0, 1)
  BODY( 1, 1, 1)
  BODY( 2, 1, 1)
  BODY( 3, 1, 1)
  BODY( 4, 1, 1)
  BODY( 5, 1, 1)
  BODY( 6, 1, 1)
  BODY( 7, 1, 0)
#undef BODY

  // ---- epilogue PV(last): vf holds this wave's tile 7 ----
  __builtin_amdgcn_s_setprio(1);
  Oc0 = MFMA(BF(vf[0][0]), BF(pfA), Oc0);
  Oc1 = MFMA(BF(vf[1][0]), BF(pfA), Oc1);
  Oc0 = MFMA(BF(vf[0][1]), BF(pfB), Oc0);
  Oc1 = MFMA(BF(vf[1][1]), BF(pfB), Oc1);
  Oc0 = MFMA(BF(vf[0][2]), BF(pfC), Oc0);
  Oc1 = MFMA(BF(vf[1][2]), BF(pfC), Oc1);
  Oc0 = MFMA(BF(vf[0][3]), BF(pfD), Oc0);
  Oc1 = MFMA(BF(vf[1][3]), BF(pfD), Oc1);
  __builtin_amdgcn_s_setprio(0);
#undef MFMA
#undef BF

  // ---- merge the two s-halves (exact) and store ----
  float lw = lrun + __shfl_xor(lrun, 32);   // full row-sum for this s-half
  if (w == 1) {
    float* row = mbuf + lane * 36;
#pragma unroll
    for (int r2 = 0; r2 < 4; ++r2) {
      *(float4*)(row + r2 * 4) =
          make_float4(Oc0[4*r2+0], Oc0[4*r2+1], Oc0[4*r2+2], Oc0[4*r2+3]);
      *(float4*)(row + 16 + r2 * 4) =
          make_float4(Oc1[4*r2+0], Oc1[4*r2+1], Oc1[4*r2+2], Oc1[4*r2+3]);
    }
    row[32] = mrun;
    row[33] = lw;
  }
  __syncthreads();
  if (w == 0) {
    const float* row = mbuf + lane * 36;
    float m1 = row[32], l1 = row[33];
    float mm = fmaxf(mrun, m1);
    float s0e = __builtin_amdgcn_exp2f(mrun - mm);
    float s1e = __builtin_amdgcn_exp2f(m1 - mm);
    float ltot = lw * s0e + l1 * s1e;
    float inv = 1.0f / ltot;
    float* orow = out + ((n * 1024 + l) * 16 + h) * 64;
#pragma unroll
    for (int r2 = 0; r2 < 4; ++r2) {
      float4 o;
      o.x = (Oc0[4*r2+0] * s0e + row[r2*4+0] * s1e) * inv;
      o.y = (Oc0[4*r2+1] * s0e + row[r2*4+1] * s1e) * inv;
      o.z = (Oc0[4*r2+2] * s0e + row[r2*4+2] * s1e) * inv;
      o.w = (Oc0[4*r2+3] * s0e + row[r2*4+3] * s1e) * inv;
      *(float4*)(orow + r2 * 8 + h4) = o;
      o.x = (Oc1[4*r2+0] * s0e + row[16+r2*4+0] * s1e) * inv;
      o.y = (Oc1[4*r2+1] * s0e + row[16+r2*4+1] * s1e) * inv;
      o.z = (Oc1[4*r2+2] * s0e + row[16+r2*4+2] * s1e) * inv;
      o.w = (Oc1[4*r2+3] * s0e + row[16+r2*4+3] * s1e) * inv;
      *(float4*)(orow + 32 + r2 * 8 + h4) = o;
    }
  }
}

extern "C" void kernel_launch(void* const* d_in, const int* in_sizes, int n_in,
                              void* d_out, int out_size, void* d_ws, size_t ws_size,
                              hipStream_t stream) {
  const float* Q    = (const float*)d_in[0];
  const float* K    = (const float*)d_in[1];
  const float* V    = (const float*)d_in[2];
  const float* mask = (const float*)d_in[3];
  const float* klm  = (const float*)d_in[4];
  const float* ptab = (const float*)d_in[5];
  const int*   pos  = (const int*)d_in[6];
  float* out = (float*)d_out;

  char* ws = (char*)d_ws;
  // layout: pospk 512K | Kp 8M | Vt 8M | flag 64B | CM 8M
  unsigned int*   pospk = (unsigned int*)ws;
  unsigned short* Kp    = (unsigned short*)(ws + (1 << 19));
  unsigned short* Vt    = (unsigned short*)(ws + (1 << 19) + (8 << 20));
  int*            cmf   = (int*)(ws + (1 << 19) + (16 << 20));
  unsigned short* CM    = (unsigned short*)(ws + (1 << 19) + (16 << 20) + 64);
  const size_t need_flag = (size_t)(1 << 19) + (size_t)(16 << 20) + 64;
  const size_t need_cm   = need_flag + (size_t)(8 << 20);
  const bool use_flag = ws_size >= need_flag;
  const bool use_cm   = ws_size >= need_cm;
  if (!use_flag) cmf = nullptr;

  if (use_flag) hipMemsetAsync(cmf, 0, 4, stream);
  k_prep<<<18688, 256, 0, stream>>>(pos, pospk, K, Kp, V, Vt, mask, klm, CM,
                                    cmf, use_cm ? 1 : 0);
  if (use_cm) {
    k_attn<true><<<2048, 128, 0, stream>>>(Q, mask, klm, ptab, pospk, Kp, Vt,
                                           CM, cmf, out);
  } else {
    k_attn<false><<<2048, 128, 0, stream>>>(Q, mask, klm, ptab, pospk, Kp, Vt,
                                            nullptr, cmf, out);
  }
}

// Round 10
// 175.389 us; speedup vs baseline: 1.4191x; 1.0236x over previous
//
#include <hip/hip_runtime.h>

// FullAttention_Spatial: N=4, L=S=1024, H=16, E=D=64, NUM_POS=2, fp32 in/out.
//
// score = temp*(QK + attn_mask[l,s] + klm[n,s]) + pos_table[pos[n,l,s]][h]
// pos in {0,1} => bias = T0[h] + bit*(T1[h]-T0[h]); T0 cancels in softmax.
// Log2-domain softmax; Q pre-scaled by temp2 = temp*log2e.
//
// R9: R8 S-split kept (2 waves/block on same 32 q-rows, wave w sweeps
// s-tiles [w*8,w*8+8), grid 2048 -> 4096 waves). Occupancy control FIXED:
// hipcc multiplies launch_bounds' 2nd arg by waves/block (R7: (128,4)->64
// VGPR=512/8; R8: (128,3)->84=512/6 -> both spilled to scratch). Use
// amdgpu_waves_per_eu(3) instead: VGPR cap 168, natural ~155 -> no spill,
// 3 waves/SIMD resident.
//
// Fragment layouts (shorts, per (n,h) panel of 65536):
//  Kp: ((t*4+ks)*2+sh)*512 + (h5*32+s31)*8  holds K[s=t*64+sh*32+s31][e=ks*16+h5*8+j]
//  Vt: ((t*4+ks)*2+dh)*512 + (h5*32+d31)*8  holds V^T[d=dh*32+d31][s=t*64+ks*16+h5*8+j]
// MFMA 32x32x16: C col=lane&31, row=(reg&3)+8*(reg>>2)+4*(lane>>5);
// A row=lane&31, k=8*(lane>>5)+j; B col=lane&31, k=8*(lane>>5)+j.

typedef __attribute__((ext_vector_type(8))) __bf16 bf16x8;
typedef __attribute__((ext_vector_type(16))) float f32x16;
typedef __attribute__((ext_vector_type(4))) unsigned int u32x4;

#define TEMP2 (0.125f * 1.4426950408889634f)
#define LG2E 1.4426950408889634f

static __device__ __forceinline__ unsigned short f2bf(float x) {
  unsigned int u = __builtin_bit_cast(unsigned int, x);
  u += 0x7FFFu + ((u >> 16) & 1u);
  return (unsigned short)(u >> 16);
}
static __device__ __forceinline__ unsigned int cvtpk(float lo, float hi) {
  unsigned int r;
  asm("v_cvt_pk_bf16_f32 %0, %1, %2" : "=v"(r) : "v"(lo), "v"(hi));
  return r;
}
// After: a = {a.lo32, b.lo32}, b = {a.hi32, b.hi32}
static __device__ __forceinline__ void plswap(unsigned int& a, unsigned int& b) {
  asm("v_permlane32_swap_b32 %0, %1" : "+v"(a), "+v"(b));
}

// ---------------- fused prepass ----------------
__global__ __launch_bounds__(256) void k_prep(
    const int* __restrict__ pos, unsigned int* __restrict__ pospk,
    const float* __restrict__ K, unsigned short* __restrict__ Kp,
    const float* __restrict__ V, unsigned short* __restrict__ Vt,
    const float* __restrict__ mask, const float* __restrict__ klm,
    unsigned short* __restrict__ CM, int* __restrict__ cmflag, int use_cm) {
  __shared__ float ld[64][65];
  int b = blockIdx.x;
  int tid = threadIdx.x;
  if (b < 256) {
    // ---- K -> fragment order ----
    int idx = b * 256 + tid;           // ((n*1024+s)*16+h)
    int s = (idx >> 4) & 1023;
    const float* src = K + idx * 64;
    unsigned short row[64];
#pragma unroll
    for (int j = 0; j < 16; ++j) {
      float4 v = *(const float4*)(src + j * 4);
      row[j*4+0] = f2bf(v.x); row[j*4+1] = f2bf(v.y);
      row[j*4+2] = f2bf(v.z); row[j*4+3] = f2bf(v.w);
    }
    int n = idx >> 14, h = idx & 15;
    unsigned short* panel = Kp + (n * 16 + h) * 65536;
    int t = s >> 6, sh = (s >> 5) & 1, s31 = s & 31;
#pragma unroll
    for (int bb = 0; bb < 8; ++bb) {
      int ks = bb >> 1, hf = bb & 1;
      int off = ((t * 4 + ks) * 2 + sh) * 512 + (hf * 32 + s31) * 8;
      *(u32x4*)(panel + off) = *(const u32x4*)(&row[bb * 8]);
    }
  } else if (b < 1280) {
    // ---- V transpose -> fragment order ----
    int vb = b - 256;
    int t = vb & 15, h = (vb >> 4) & 15, n = vb >> 8;
    {
      int s = tid >> 2, dq = (tid & 3) * 16;
      const float* src = V + ((n * 1024 + t * 64 + s) * 16 + h) * 64 + dq;
#pragma unroll
      for (int j = 0; j < 4; ++j) {
        float4 v = *(const float4*)(src + j * 4);
        ld[s][dq + j*4 + 0] = v.x; ld[s][dq + j*4 + 1] = v.y;
        ld[s][dq + j*4 + 2] = v.z; ld[s][dq + j*4 + 3] = v.w;
      }
    }
    __syncthreads();
    {
      int d = tid >> 2, sq = (tid & 3) * 16;
      unsigned short vals[16];
#pragma unroll
      for (int k = 0; k < 16; ++k) vals[k] = f2bf(ld[sq + k][d]);
      unsigned short* panel = Vt + (n * 16 + h) * 65536;
      int dh = d >> 5, d31 = d & 31;
#pragma unroll
      for (int cb = 0; cb < 2; ++cb) {
        int sl = sq + cb * 8;
        int ks = sl >> 4, hf = (sl >> 3) & 1;
        int off = ((t * 4 + ks) * 2 + dh) * 512 + (hf * 32 + d31) * 8;
        *(u32x4*)(panel + off) = *(const u32x4*)(&vals[cb * 8]);
      }
    }
  } else if (b < 2304) {
    // ---- combined mask (bf16, pre-scaled) + nonzero flag ----
    int flat = (b - 1280) * 256 * 16 + tid * 16;
    int n = flat >> 20, l = (flat >> 10) & 1023, s0 = flat & 1023;
    const float* mrow = mask + l * 1024 + s0;
    const float* krow = klm + n * 1024 + s0;
    float acc = 0.f;
    unsigned int o[8];
#pragma unroll
    for (int j = 0; j < 4; ++j) {
      float4 mv = *(const float4*)(mrow + j * 4);
      float4 kv = *(const float4*)(krow + j * 4);
      acc += __builtin_fabsf(mv.x) + __builtin_fabsf(mv.y) +
             __builtin_fabsf(mv.z) + __builtin_fabsf(mv.w) +
             __builtin_fabsf(kv.x) + __builtin_fabsf(kv.y) +
             __builtin_fabsf(kv.z) + __builtin_fabsf(kv.w);
      o[j*2+0] = cvtpk((mv.x + kv.x) * TEMP2, (mv.y + kv.y) * TEMP2);
      o[j*2+1] = cvtpk((mv.z + kv.z) * TEMP2, (mv.w + kv.w) * TEMP2);
    }
    if (use_cm) {
      *(u32x4*)(CM + flat)     = *(const u32x4*)(&o[0]);
      *(u32x4*)(CM + flat + 8) = *(const u32x4*)(&o[4]);
    }
    if (cmflag) {
      unsigned long long bal = __ballot(acc != 0.f);
      if ((tid & 63) == 0 && bal != 0ull) atomicOr(cmflag, 1);
    }
  } else {
    // ---- pack pos bits ----
    int gi = (b - 2304) * 256 + tid;
    int v = pos[gi];
    unsigned long long m = __ballot(v & 1);
    int lane = tid & 63;
    if (lane == 0) pospk[gi >> 5] = (unsigned int)m;
    else if (lane == 32) pospk[gi >> 5] = (unsigned int)(m >> 32);
  }
}

// ---------------- main flash-attention kernel ----------------
// grid 2048 = lblk*64 + n*16 + h ; 2 waves (128 thr) on same 32 q-rows,
// wave w sweeps s-tiles [w*8, w*8+8); exact merge at end via LDS.
template <bool USE_CM>
__global__ __launch_bounds__(128)
__attribute__((amdgpu_waves_per_eu(3))) void k_attn(
    const float* __restrict__ Q, const float* __restrict__ mask,
    const float* __restrict__ klm, const float* __restrict__ ptab,
    const unsigned int* __restrict__ pospk,
    const unsigned short* __restrict__ Kp, const unsigned short* __restrict__ Vt,
    const unsigned short* __restrict__ CMp, const int* __restrict__ cmf,
    float* __restrict__ out) {
  __shared__ float mbuf[64 * 36];      // wave1's {Oc0[16],Oc1[16],m,l} per lane

  int bid = blockIdx.x;
  int nh = bid & 63;
  int n = nh >> 4, h = nh & 15, lblk = bid >> 6;
  int tid = threadIdx.x;
  int w = tid >> 6, lane = tid & 63;
  int l31 = lane & 31, h5 = lane >> 5;
  int l = lblk * 32 + l31;             // this lane's q-row (global)
  const int ln8 = lane * 8;
  const int hcm = cmf ? *cmf : 1;      // uniform: masks nonzero anywhere?

  // Q fragments (B of swapped QK^T), pre-scaled by temp2
  const float* qrow = Q + ((n * 1024 + l) * 16 + h) * 64;
  bf16x8 qf[4];
#pragma unroll
  for (int ke = 0; ke < 4; ++ke) {
    float4 a = *(const float4*)(qrow + ke * 16 + h5 * 8);
    float4 bq = *(const float4*)(qrow + ke * 16 + h5 * 8 + 4);
    u32x4 pk;
    pk[0] = cvtpk(a.x * TEMP2, a.y * TEMP2);
    pk[1] = cvtpk(a.z * TEMP2, a.w * TEMP2);
    pk[2] = cvtpk(bq.x * TEMP2, bq.y * TEMP2);
    pk[3] = cvtpk(bq.z * TEMP2, bq.w * TEMP2);
    qf[ke] = __builtin_bit_cast(bf16x8, pk);
  }
  const float delta2 = (ptab[16 + h] - ptab[h]) * LG2E;

  float mrun = -1e30f, lrun = 0.f;
  f32x16 Oc0 = {0,0,0,0,0,0,0,0,0,0,0,0,0,0,0,0};
  f32x16 Oc1 = {0,0,0,0,0,0,0,0,0,0,0,0,0,0,0,0};
  u32x4 pfA = {0,0,0,0}, pfB = {0,0,0,0}, pfC = {0,0,0,0}, pfD = {0,0,0,0};
  u32x4 kf[2][4], vf[2][4];

  // per-wave s-range base pointers (8 tiles each)
  const unsigned short* KpT = Kp + nh * 65536 + w * 32768;
  const unsigned short* VtT = Vt + nh * 65536 + w * 32768;
  const unsigned short* CMb = USE_CM ? (CMp + (n * 1024 + l) * 1024 + w * 512) : nullptr;
  const float* mrowB = mask + l * 1024 + w * 512;
  const float* krowB = klm + n * 1024 + w * 512;
  const unsigned int* posB = pospk + (n * 1024 + l) * 32 + w * 16;
  const int h4 = h5 * 4;

#define BF(x) __builtin_bit_cast(bf16x8, x)
#define MFMA(A, B, C) __builtin_amdgcn_mfma_f32_32x32x16_bf16(A, B, C, 0, 0, 0)

  // ---- prologue: K-frags for this wave's first tile ----
  {
    const unsigned short* k0 = KpT + ln8;
#pragma unroll
    for (int ks = 0; ks < 4; ++ks) {
      kf[0][ks] = *(const u32x4*)(k0 + (ks * 2 + 0) * 512);
      kf[1][ks] = *(const u32x4*)(k0 + (ks * 2 + 1) * 512);
    }
  }

#define BODY(T, DO_PV, STG)                                                    \
  {                                                                            \
    uint2 pwvL = *(const uint2*)(posB + (T) * 2);                              \
    const unsigned short* kN = KpT + ((T) + 1) * 4096 + ln8;                   \
    const unsigned short* vC = VtT + (T) * 4096 + ln8;                         \
    f32x16 sv0 = {0,0,0,0,0,0,0,0,0,0,0,0,0,0,0,0};                            \
    f32x16 sv1 = {0,0,0,0,0,0,0,0,0,0,0,0,0,0,0,0};                            \
    /* ---- MFMA block: QK(T) || PV(T-1); reload frags right after use ---- */ \
    __builtin_amdgcn_s_setprio(1);                                             \
    sv0 = MFMA(BF(kf[0][0]), qf[0], sv0);                                      \
    sv1 = MFMA(BF(kf[1][0]), qf[0], sv1);                                      \
    if (DO_PV) {                                                               \
      Oc0 = MFMA(BF(vf[0][0]), BF(pfA), Oc0);                                  \
      Oc1 = MFMA(BF(vf[1][0]), BF(pfA), Oc1);                                  \
    }                                                                          \
    if (STG) {                                                                 \
      kf[0][0] = *(const u32x4*)(kN + 0 * 512);                                \
      kf[1][0] = *(const u32x4*)(kN + 1 * 512);                                \
    }                                                                          \
    vf[0][0] = *(const u32x4*)(vC + 0 * 512);                                  \
    vf[1][0] = *(const u32x4*)(vC + 1 * 512);                                  \
    sv0 = MFMA(BF(kf[0][1]), qf[1], sv0);                                      \
    sv1 = MFMA(BF(kf[1][1]), qf[1], sv1);                                      \
    if (DO_PV) {                                                               \
      Oc0 = MFMA(BF(vf[0][1]), BF(pfB), Oc0);                                  \
      Oc1 = MFMA(BF(vf[1][1]), BF(pfB), Oc1);                                  \
    }                                                                          \
    if (STG) {                                                                 \
      kf[0][1] = *(const u32x4*)(kN + 2 * 512);                                \
      kf[1][1] = *(const u32x4*)(kN + 3 * 512);                                \
    }                                                                          \
    vf[0][1] = *(const u32x4*)(vC + 2 * 512);                                  \
    vf[1][1] = *(const u32x4*)(vC + 3 * 512);                                  \
    sv0 = MFMA(BF(kf[0][2]), qf[2], sv0);                                      \
    sv1 = MFMA(BF(kf[1][2]), qf[2], sv1);                                      \
    if (DO_PV) {                                                               \
      Oc0 = MFMA(BF(vf[0][2]), BF(pfC), Oc0);                                  \
      Oc1 = MFMA(BF(vf[1][2]), BF(pfC), Oc1);                                  \
    }                                                                          \
    if (STG) {                                                                 \
      kf[0][2] = *(const u32x4*)(kN + 4 * 512);                                \
      kf[1][2] = *(const u32x4*)(kN + 5 * 512);                                \
    }                                                                          \
    vf[0][2] = *(const u32x4*)(vC + 4 * 512);                                  \
    vf[1][2] = *(const u32x4*)(vC + 5 * 512);                                  \
    sv0 = MFMA(BF(kf[0][3]), qf[3], sv0);                                      \
    sv1 = MFMA(BF(kf[1][3]), qf[3], sv1);                                      \
    if (DO_PV) {                                                               \
      Oc0 = MFMA(BF(vf[0][3]), BF(pfD), Oc0);                                  \
      Oc1 = MFMA(BF(vf[1][3]), BF(pfD), Oc1);                                  \
    }                                                                          \
    if (STG) {                                                                 \
      kf[0][3] = *(const u32x4*)(kN + 6 * 512);                                \
      kf[1][3] = *(const u32x4*)(kN + 7 * 512);                                \
    }                                                                          \
    vf[0][3] = *(const u32x4*)(vC + 6 * 512);                                  \
    vf[1][3] = *(const u32x4*)(vC + 7 * 512);                                  \
    __builtin_amdgcn_s_setprio(0);                                             \
    /* ---- bias: CM (loaded HERE, short live range; skipped if masks==0) ---- */ \
    if (hcm) {                                                                 \
      _Pragma("unroll")                                                        \
      for (int r2 = 0; r2 < 4; ++r2) {                                         \
        float b0[4], b1[4];                                                    \
        if constexpr (USE_CM) {                                                \
          uint2 c0 = *(const uint2*)(CMb + (T) * 64 + r2 * 8 + h4);            \
          uint2 c1 = *(const uint2*)(CMb + (T) * 64 + 32 + r2 * 8 + h4);       \
          b0[0] = __builtin_bit_cast(float, c0.x << 16);                       \
          b0[1] = __builtin_bit_cast(float, c0.x & 0xFFFF0000u);               \
          b0[2] = __builtin_bit_cast(float, c0.y << 16);                       \
          b0[3] = __builtin_bit_cast(float, c0.y & 0xFFFF0000u);               \
          b1[0] = __builtin_bit_cast(float, c1.x << 16);                       \
          b1[1] = __builtin_bit_cast(float, c1.x & 0xFFFF0000u);               \
          b1[2] = __builtin_bit_cast(float, c1.y << 16);                       \
          b1[3] = __builtin_bit_cast(float, c1.y & 0xFFFF0000u);               \
        } else {                                                               \
          float4 mv0 = *(const float4*)(mrowB + (T) * 64 + r2 * 8 + h4);       \
          float4 kv0 = *(const float4*)(krowB + (T) * 64 + r2 * 8 + h4);       \
          float4 mv1 = *(const float4*)(mrowB + (T) * 64 + 32 + r2 * 8 + h4);  \
          float4 kv1 = *(const float4*)(krowB + (T) * 64 + 32 + r2 * 8 + h4);  \
          b0[0] = (mv0.x + kv0.x) * TEMP2; b0[1] = (mv0.y + kv0.y) * TEMP2;    \
          b0[2] = (mv0.z + kv0.z) * TEMP2; b0[3] = (mv0.w + kv0.w) * TEMP2;    \
          b1[0] = (mv1.x + kv1.x) * TEMP2; b1[1] = (mv1.y + kv1.y) * TEMP2;    \
          b1[2] = (mv1.z + kv1.z) * TEMP2; b1[3] = (mv1.w + kv1.w) * TEMP2;    \
        }                                                                      \
        _Pragma("unroll")                                                      \
        for (int i = 0; i < 4; ++i) {                                          \
          sv0[r2 * 4 + i] += b0[i];                                            \
          sv1[r2 * 4 + i] += b1[i];                                            \
        }                                                                      \
      }                                                                        \
    }                                                                          \
    {                                                                          \
      unsigned pws0 = pwvL.x >> h4;                                            \
      unsigned pws1 = pwvL.y >> h4;                                            \
      _Pragma("unroll")                                                        \
      for (int r2 = 0; r2 < 4; ++r2)                                           \
        _Pragma("unroll")                                                      \
        for (int i = 0; i < 4; ++i) {                                          \
          float bit0 = (float)((pws0 >> (r2 * 8 + i)) & 1u);                   \
          float bit1 = (float)((pws1 >> (r2 * 8 + i)) & 1u);                   \
          sv0[r2 * 4 + i] = fmaf(bit0, delta2, sv0[r2 * 4 + i]);               \
          sv1[r2 * 4 + i] = fmaf(bit1, delta2, sv1[r2 * 4 + i]);               \
        }                                                                      \
    }                                                                          \
    /* ---- online softmax (row q: lanes l31, l31+32) ---- */                  \
    {                                                                          \
      float m8[8];                                                             \
      _Pragma("unroll")                                                        \
      for (int i = 0; i < 8; ++i)                                              \
        m8[i] = fmaxf(fmaxf(sv0[2 * i], sv0[2 * i + 1]),                       \
                      fmaxf(sv1[2 * i], sv1[2 * i + 1]));                      \
      float m4a = fmaxf(m8[0], m8[1]), m4b = fmaxf(m8[2], m8[3]);              \
      float m4c = fmaxf(m8[4], m8[5]), m4d = fmaxf(m8[6], m8[7]);              \
      float tmax = fmaxf(fmaxf(m4a, m4b), fmaxf(m4c, m4d));                    \
      tmax = fmaxf(tmax, __shfl_xor(tmax, 32));                                \
      if (!__all(tmax <= mrun + 4.0f)) {                                       \
        float mnew = fmaxf(mrun, tmax);                                        \
        float sc = __builtin_amdgcn_exp2f(mrun - mnew);                        \
        lrun *= sc;                                                            \
        Oc0 *= sc; Oc1 *= sc;                                                  \
        mrun = mnew;                                                           \
      }                                                                        \
      float s8[8];                                                             \
      _Pragma("unroll")                                                        \
      for (int i = 0; i < 8; ++i) {                                            \
        float p0 = __builtin_amdgcn_exp2f(sv0[2 * i] - mrun);                  \
        float p1 = __builtin_amdgcn_exp2f(sv0[2 * i + 1] - mrun);              \
        float p2 = __builtin_amdgcn_exp2f(sv1[2 * i] - mrun);                  \
        float p3 = __builtin_amdgcn_exp2f(sv1[2 * i + 1] - mrun);              \
        sv0[2 * i] = p0; sv0[2 * i + 1] = p1;                                  \
        sv1[2 * i] = p2; sv1[2 * i + 1] = p3;                                  \
        s8[i] = (p0 + p1) + (p2 + p3);                                         \
      }                                                                        \
      float s4a = s8[0] + s8[1], s4b = s8[2] + s8[3];                          \
      float s4c = s8[4] + s8[5], s4d = s8[6] + s8[7];                          \
      lrun += (s4a + s4b) + (s4c + s4d);   /* lane-partial; combined at end */ \
    }                                                                          \
    /* ---- pack P(T) -> pfA..pfD (pre-swapped B-frags) ---- */                \
    {                                                                          \
      unsigned a0 = cvtpk(sv0[0], sv0[1]),   a1 = cvtpk(sv0[2], sv0[3]);       \
      unsigned a2 = cvtpk(sv0[4], sv0[5]),   a3 = cvtpk(sv0[6], sv0[7]);       \
      plswap(a0, a2); plswap(a1, a3);                                          \
      pfA[0] = a0; pfA[1] = a1; pfA[2] = a2; pfA[3] = a3;                      \
      unsigned b0_ = cvtpk(sv0[8], sv0[9]),   b1_ = cvtpk(sv0[10], sv0[11]);   \
      unsigned b2_ = cvtpk(sv0[12], sv0[13]), b3_ = cvtpk(sv0[14], sv0[15]);   \
      plswap(b0_, b2_); plswap(b1_, b3_);                                      \
      pfB[0] = b0_; pfB[1] = b1_; pfB[2] = b2_; pfB[3] = b3_;                  \
      unsigned c0 = cvtpk(sv1[0], sv1[1]),   c1 = cvtpk(sv1[2], sv1[3]);       \
      unsigned c2 = cvtpk(sv1[4], sv1[5]),   c3 = cvtpk(sv1[6], sv1[7]);       \
      plswap(c0, c2); plswap(c1, c3);                                          \
      pfC[0] = c0; pfC[1] = c1; pfC[2] = c2; pfC[3] = c3;                      \
      unsigned d0 = cvtpk(sv1[8], sv1[9]),   d1 = cvtpk(sv1[10], sv1[11]);     \
      unsigned d2 = cvtpk(sv1[12], sv1[13]), d3 = cvtpk(sv1[14], sv1[15]);     \
      plswap(d0, d2); plswap(d1, d3);                                          \
      pfD[0] = d0; pfD[1] = d1; pfD[2] = d2; pfD[3] = d3;                      \
    }                                                                          \
  }

  //     T  PV STG
  BODY( 0, 0, 1)
  BODY( 1, 1, 1)
  BODY( 2, 1, 1)
  BODY( 3, 1, 1)
  BODY( 4, 1, 1)
  BODY( 5, 1, 1)
  BODY( 6, 1, 1)
  BODY( 7, 1, 0)
#undef BODY

  // ---- epilogue PV(last): vf holds this wave's tile 7 ----
  __builtin_amdgcn_s_setprio(1);
  Oc0 = MFMA(BF(vf[0][0]), BF(pfA), Oc0);
  Oc1 = MFMA(BF(vf[1][0]), BF(pfA), Oc1);
  Oc0 = MFMA(BF(vf[0][1]), BF(pfB), Oc0);
  Oc1 = MFMA(BF(vf[1][1]), BF(pfB), Oc1);
  Oc0 = MFMA(BF(vf[0][2]), BF(pfC), Oc0);
  Oc1 = MFMA(BF(vf[1][2]), BF(pfC), Oc1);
  Oc0 = MFMA(BF(vf[0][3]), BF(pfD), Oc0);
  Oc1 = MFMA(BF(vf[1][3]), BF(pfD), Oc1);
  __builtin_amdgcn_s_setprio(0);
#undef MFMA
#undef BF

  // ---- merge the two s-halves (exact) and store ----
  float lw = lrun + __shfl_xor(lrun, 32);   // full row-sum for this s-half
  if (w == 1) {
    float* row = mbuf + lane * 36;
#pragma unroll
    for (int r2 = 0; r2 < 4; ++r2) {
      *(float4*)(row + r2 * 4) =
          make_float4(Oc0[4*r2+0], Oc0[4*r2+1], Oc0[4*r2+2], Oc0[4*r2+3]);
      *(float4*)(row + 16 + r2 * 4) =
          make_float4(Oc1[4*r2+0], Oc1[4*r2+1], Oc1[4*r2+2], Oc1[4*r2+3]);
    }
    row[32] = mrun;
    row[33] = lw;
  }
  __syncthreads();
  if (w == 0) {
    const float* row = mbuf + lane * 36;
    float m1 = row[32], l1 = row[33];
    float mm = fmaxf(mrun, m1);
    float s0e = __builtin_amdgcn_exp2f(mrun - mm);
    float s1e = __builtin_amdgcn_exp2f(m1 - mm);
    float ltot = lw * s0e + l1 * s1e;
    float inv = 1.0f / ltot;
    float* orow = out + ((n * 1024 + l) * 16 + h) * 64;
#pragma unroll
    for (int r2 = 0; r2 < 4; ++r2) {
      float4 o;
      o.x = (Oc0[4*r2+0] * s0e + row[r2*4+0] * s1e) * inv;
      o.y = (Oc0[4*r2+1] * s0e + row[r2*4+1] * s1e) * inv;
      o.z = (Oc0[4*r2+2] * s0e + row[r2*4+2] * s1e) * inv;
      o.w = (Oc0[4*r2+3] * s0e + row[r2*4+3] * s1e) * inv;
      *(float4*)(orow + r2 * 8 + h4) = o;
      o.x = (Oc1[4*r2+0] * s0e + row[16+r2*4+0] * s1e) * inv;
      o.y = (Oc1[4*r2+1] * s0e + row[16+r2*4+1] * s1e) * inv;
      o.z = (Oc1[4*r2+2] * s0e + row[16+r2*4+2] * s1e) * inv;
      o.w = (Oc1[4*r2+3] * s0e + row[16+r2*4+3] * s1e) * inv;
      *(float4*)(orow + 32 + r2 * 8 + h4) = o;
    }
  }
}

extern "C" void kernel_launch(void* const* d_in, const int* in_sizes, int n_in,
                              void* d_out, int out_size, void* d_ws, size_t ws_size,
                              hipStream_t stream) {
  const float* Q    = (const float*)d_in[0];
  const float* K    = (const float*)d_in[1];
  const float* V    = (const float*)d_in[2];
  const float* mask = (const float*)d_in[3];
  const float* klm  = (const float*)d_in[4];
  const float* ptab = (const float*)d_in[5];
  const int*   pos  = (const int*)d_in[6];
  float* out = (float*)d_out;

  char* ws = (char*)d_ws;
  // layout: pospk 512K | Kp 8M | Vt 8M | flag 64B | CM 8M
  unsigned int*   pospk = (unsigned int*)ws;
  unsigned short* Kp    = (unsigned short*)(ws + (1 << 19));
  unsigned short* Vt    = (unsigned short*)(ws + (1 << 19) + (8 << 20));
  int*            cmf   = (int*)(ws + (1 << 19) + (16 << 20));
  unsigned short* CM    = (unsigned short*)(ws + (1 << 19) + (16 << 20) + 64);
  const size_t need_flag = (size_t)(1 << 19) + (size_t)(16 << 20) + 64;
  const size_t need_cm   = need_flag + (size_t)(8 << 20);
  const bool use_flag = ws_size >= need_flag;
  const bool use_cm   = ws_size >= need_cm;
  if (!use_flag) cmf = nullptr;

  if (use_flag) hipMemsetAsync(cmf, 0, 4, stream);
  k_prep<<<18688, 256, 0, stream>>>(pos, pospk, K, Kp, V, Vt, mask, klm, CM,
                                    cmf, use_cm ? 1 : 0);
  if (use_cm) {
    k_attn<true><<<2048, 128, 0, stream>>>(Q, mask, klm, ptab, pospk, Kp, Vt,
                                           CM, cmf, out);
  } else {
    k_attn<false><<<2048, 128, 0, stream>>>(Q, mask, klm, ptab, pospk, Kp, Vt,
                                            nullptr, cmf, out);
  }
}

// Round 11
// 70.602 us; speedup vs baseline: 3.5254x; 2.4842x over previous
//
#include <hip/hip_runtime.h>

// FullAttention_Spatial: N=4, L=S=1024, H=16, E=D=64, NUM_POS=2, fp32 in/out.
//
// score = temp*(QK + attn_mask[l,s] + klm[n,s]) + pos_table[pos[n,l,s]][h]
// pos in {0,1} => bias = T0[h] + bit*(T1[h]-T0[h]); T0 cancels in softmax.
// Log2-domain softmax; Q pre-scaled by temp2 = temp*log2e.
//
// R10: 8-wave (512-thr) blocks = 2 s-half groups x 4 waves. Each group runs
// the R4 LDS-staged structure (K dbuf x2 + V dbuf x2 = 32KB/group, 64KB/block)
// over its 8 s-tiles. Grid 512 -> 4096 waves; LDS clamps 2 blocks/CU ->
// 16 waves/CU -> 4 waves/SIMD, natural VGPR ~120 (NO occupancy attribute --
// R7-R10 showed hipcc treats min-occ spec as arg*waves_per_block, LDS-clamped;
// any spec here would cap VGPR at 64 and spill). In-block s-half merge via
// reused LDS pool. Keeps: 32x32 swapped QK^T, in-register P (permlane32_swap),
// defer-max, hcm mask-skip, swizzled LDS-layout panels.
//
// MFMA 32x32x16: C col=lane&31, row=(reg&3)+8*(reg>>2)+4*(lane>>5);
// A row=lane&31, k=8*(lane>>5)+j; B col=lane&31, k=8*(lane>>5)+j.

typedef __attribute__((ext_vector_type(8))) __bf16 bf16x8;
typedef __attribute__((ext_vector_type(16))) float f32x16;
typedef __attribute__((ext_vector_type(4))) unsigned int u32x4;

#define TEMP2 (0.125f * 1.4426950408889634f)
#define LG2E 1.4426950408889634f

static __device__ __forceinline__ unsigned short f2bf(float x) {
  unsigned int u = __builtin_bit_cast(unsigned int, x);
  u += 0x7FFFu + ((u >> 16) & 1u);
  return (unsigned short)(u >> 16);
}
static __device__ __forceinline__ unsigned int cvtpk(float lo, float hi) {
  unsigned int r;
  asm("v_cvt_pk_bf16_f32 %0, %1, %2" : "=v"(r) : "v"(lo), "v"(hi));
  return r;
}
static __device__ __forceinline__ void gload16(const void* g, void* l) {
  __builtin_amdgcn_global_load_lds((const __attribute__((address_space(1))) void*)g,
                                   (__attribute__((address_space(3))) void*)l, 16, 0, 0);
}
// After: a = {a.lo32, b.lo32}, b = {a.hi32, b.hi32}
static __device__ __forceinline__ void plswap(unsigned int& a, unsigned int& b) {
  asm("v_permlane32_swap_b32 %0, %1" : "+v"(a), "+v"(b));
}

// ---------------- fused prepass (R2-R5 LDS-layout panels) ----------------
__global__ __launch_bounds__(256) void k_prep(
    const int* __restrict__ pos, unsigned int* __restrict__ pospk,
    const float* __restrict__ K, unsigned short* __restrict__ Kp,
    const float* __restrict__ V, unsigned short* __restrict__ Vt,
    const float* __restrict__ mask, const float* __restrict__ klm,
    unsigned short* __restrict__ CM, int* __restrict__ cmflag, int use_cm) {
  __shared__ float ld[64][65];
  int b = blockIdx.x;
  int tid = threadIdx.x;
  if (b < 256) {
    // ---- K relayout: [n][h][s][e], 16B blocks ^= (s&7) ----
    int idx = b * 256 + tid;           // ((n*1024+s)*16+h)
    int s = (idx >> 4) & 1023;
    const float* src = K + idx * 64;
    unsigned short row[64];
#pragma unroll
    for (int j = 0; j < 16; ++j) {
      float4 v = *(const float4*)(src + j * 4);
      row[j*4+0] = f2bf(v.x); row[j*4+1] = f2bf(v.y);
      row[j*4+2] = f2bf(v.z); row[j*4+3] = f2bf(v.w);
    }
    int n = idx >> 14, h = idx & 15;
    unsigned short* dst = Kp + ((n * 16 + h) * 1024 + s) * 64;
#pragma unroll
    for (int bb = 0; bb < 8; ++bb) {
      int pb = bb ^ (s & 7);
      *(u32x4*)(dst + pb * 8) = *(const u32x4*)(&row[bb * 8]);
    }
  } else if (b < 1280) {
    // ---- V transpose: [n][h][d][s], per-64s-seg 16B blocks ^= (d&7) ----
    int vb = b - 256;
    int t = vb & 15, h = (vb >> 4) & 15, n = vb >> 8;
    {
      int s = tid >> 2, dq = (tid & 3) * 16;
      const float* src = V + ((n * 1024 + t * 64 + s) * 16 + h) * 64 + dq;
#pragma unroll
      for (int j = 0; j < 4; ++j) {
        float4 v = *(const float4*)(src + j * 4);
        ld[s][dq + j*4 + 0] = v.x; ld[s][dq + j*4 + 1] = v.y;
        ld[s][dq + j*4 + 2] = v.z; ld[s][dq + j*4 + 3] = v.w;
      }
    }
    __syncthreads();
    {
      int d = tid >> 2, sq = (tid & 3) * 16;
      unsigned short vals[16];
#pragma unroll
      for (int k = 0; k < 16; ++k) vals[k] = f2bf(ld[sq + k][d]);
      unsigned short* dst = Vt + ((n * 16 + h) * 64 + d) * 1024 + t * 64;
#pragma unroll
      for (int cb = 0; cb < 2; ++cb) {
        int blk = (sq >> 3) + cb;
        int pb = blk ^ (d & 7);
        *(u32x4*)(dst + pb * 8) = *(const u32x4*)(&vals[cb * 8]);
      }
    }
  } else if (b < 2304) {
    // ---- combined mask (bf16, pre-scaled) + nonzero flag ----
    int flat = (b - 1280) * 256 * 16 + tid * 16;
    int n = flat >> 20, l = (flat >> 10) & 1023, s0 = flat & 1023;
    const float* mrow = mask + l * 1024 + s0;
    const float* krow = klm + n * 1024 + s0;
    float acc = 0.f;
    unsigned int o[8];
#pragma unroll
    for (int j = 0; j < 4; ++j) {
      float4 mv = *(const float4*)(mrow + j * 4);
      float4 kv = *(const float4*)(krow + j * 4);
      acc += __builtin_fabsf(mv.x) + __builtin_fabsf(mv.y) +
             __builtin_fabsf(mv.z) + __builtin_fabsf(mv.w) +
             __builtin_fabsf(kv.x) + __builtin_fabsf(kv.y) +
             __builtin_fabsf(kv.z) + __builtin_fabsf(kv.w);
      o[j*2+0] = cvtpk((mv.x + kv.x) * TEMP2, (mv.y + kv.y) * TEMP2);
      o[j*2+1] = cvtpk((mv.z + kv.z) * TEMP2, (mv.w + kv.w) * TEMP2);
    }
    if (use_cm) {
      *(u32x4*)(CM + flat)     = *(const u32x4*)(&o[0]);
      *(u32x4*)(CM + flat + 8) = *(const u32x4*)(&o[4]);
    }
    if (cmflag) {
      unsigned long long bal = __ballot(acc != 0.f);
      if ((tid & 63) == 0 && bal != 0ull) atomicOr(cmflag, 1);
    }
  } else {
    // ---- pack pos bits ----
    int gi = (b - 2304) * 256 + tid;
    int v = pos[gi];
    unsigned long long m = __ballot(v & 1);
    int lane = tid & 63;
    if (lane == 0) pospk[gi >> 5] = (unsigned int)m;
    else if (lane == 32) pospk[gi >> 5] = (unsigned int)(m >> 32);
  }
}

// ---------------- main flash-attention kernel ----------------
// grid 512 = lblk*64 + n*16 + h ; 512 thr = 2 s-groups x 4 waves x 64.
// Group g covers s-tiles [g*8, g*8+8); 128 q-rows per block.
template <bool USE_CM>
__global__ __launch_bounds__(512) void k_attn(
    const float* __restrict__ Q, const float* __restrict__ mask,
    const float* __restrict__ klm, const float* __restrict__ ptab,
    const unsigned int* __restrict__ pospk,
    const unsigned short* __restrict__ Kp, const unsigned short* __restrict__ Vt,
    const unsigned short* __restrict__ CMp, const int* __restrict__ cmf,
    float* __restrict__ out) {
  // 64 KB pool: per group g: Kt[2] (2x8KB) then Vts[2] (2x8KB).
  // Reused as the merge buffer after the final tile barrier.
  __shared__ __align__(16) char pool[65536];

  int bid = blockIdx.x;
  int nh = bid & 63;
  int n = nh >> 4, h = nh & 15, lblk = bid >> 6;
  int tid = threadIdx.x;
  int w8 = tid >> 6, lane = tid & 63;
  int g = w8 >> 2, w4 = w8 & 3;
  int l31 = lane & 31, h5 = lane >> 5;
  int l = lblk * 128 + w4 * 32 + l31;  // this lane's q-row (global)
  const int hcm = cmf ? *cmf : 1;      // uniform: masks nonzero anywhere?

  unsigned short* KtB  = (unsigned short*)pool + g * 16384;         // [2][4096]
  unsigned short* VtsB = (unsigned short*)pool + g * 16384 + 8192;  // [2][4096]

  // Q fragments (B of swapped QK^T), pre-scaled by temp2
  const float* qrow = Q + ((n * 1024 + l) * 16 + h) * 64;
  bf16x8 qf[4];
#pragma unroll
  for (int ke = 0; ke < 4; ++ke) {
    float4 a = *(const float4*)(qrow + ke * 16 + h5 * 8);
    float4 bq = *(const float4*)(qrow + ke * 16 + h5 * 8 + 4);
    u32x4 pk;
    pk[0] = cvtpk(a.x * TEMP2, a.y * TEMP2);
    pk[1] = cvtpk(a.z * TEMP2, a.w * TEMP2);
    pk[2] = cvtpk(bq.x * TEMP2, bq.y * TEMP2);
    pk[3] = cvtpk(bq.z * TEMP2, bq.w * TEMP2);
    qf[ke] = __builtin_bit_cast(bf16x8, pk);
  }
  const float delta2 = (ptab[16 + h] - ptab[h]) * LG2E;

  float mrun = -1e30f, lrun = 0.f;
  f32x16 Oc0 = {0,0,0,0,0,0,0,0,0,0,0,0,0,0,0,0};
  f32x16 Oc1 = {0,0,0,0,0,0,0,0,0,0,0,0,0,0,0,0};
  u32x4 pfA = {0,0,0,0}, pfB = {0,0,0,0}, pfC = {0,0,0,0}, pfD = {0,0,0,0};

  const unsigned short* KpB = Kp + nh * 65536;
  const unsigned short* VtB = Vt + nh * 65536;
  const unsigned short* CMb = USE_CM ? (CMp + (n * 1024 + l) * 1024 + g * 512) : nullptr;
  const float* mrowB = mask + l * 1024 + g * 512;
  const float* krowB = klm + n * 1024 + g * 512;
  const unsigned int* posB = pospk + (n * 1024 + l) * 32 + g * 16;
  const int h4 = h5 * 4;

  // loop-invariant LDS read offsets (shorts)
  const int x7 = l31 & 7;
  const int co0 = ((0 + h5) ^ x7) * 8;
  const int co1 = ((2 + h5) ^ x7) * 8;
  const int co2 = ((4 + h5) ^ x7) * 8;
  const int co3 = ((6 + h5) ^ x7) * 8;
  const int rb = l31 * 64;

  // staging addresses: group stages its tile tg = g*8 + T
  const unsigned short* kS = KpB + g * 32768 + w4 * 1024 + lane * 8;
  const unsigned short* vS = VtB + (w4 * 16 + (lane >> 3)) * 1024 + g * 512 + (lane & 7) * 8;
  const int kD = w4 * 1024 + lane * 8;  // dst offset within Kt/Vts buf (shorts)

#define BF(x) __builtin_bit_cast(bf16x8, x)
#define MFMA(A, B, C) __builtin_amdgcn_mfma_f32_32x32x16_bf16(A, B, C, 0, 0, 0)
#define LDK(B_, OFF) BF(*(const u32x4*)&KtB[(B_) * 4096 + (OFF)])
#define LDV(B_, OFF) BF(*(const u32x4*)&VtsB[(B_) * 4096 + (OFF)])

  // ---- prologue: stage tile (g*8) into buf 0 ----
#pragma unroll
  for (int j = 0; j < 2; ++j) {
    gload16(kS + j * 512, &KtB[kD + j * 512]);
    gload16(vS + j * 8192, &VtsB[kD + j * 512]);
  }
  __syncthreads();

#define BODY(T, DO_PV, STG)                                                    \
  {                                                                            \
    const int b_ = (T) & 1;                                                    \
    uint2 pwvL = *(const uint2*)(posB + (T) * 2);                              \
    /* ---- MFMA block: QK(T) from Kt[b], PV(T-1) from Vts[b^1] ---- */        \
    f32x16 sv0 = {0,0,0,0,0,0,0,0,0,0,0,0,0,0,0,0};                            \
    f32x16 sv1 = {0,0,0,0,0,0,0,0,0,0,0,0,0,0,0,0};                            \
    __builtin_amdgcn_s_setprio(1);                                             \
    sv0 = MFMA(LDK(b_, rb + co0), qf[0], sv0);                                 \
    sv1 = MFMA(LDK(b_, rb + 2048 + co0), qf[0], sv1);                          \
    if (DO_PV) {                                                               \
      Oc0 = MFMA(LDV(b_ ^ 1, rb + co0), BF(pfA), Oc0);                         \
      Oc1 = MFMA(LDV(b_ ^ 1, rb + 2048 + co0), BF(pfA), Oc1);                  \
    }                                                                          \
    sv0 = MFMA(LDK(b_, rb + co1), qf[1], sv0);                                 \
    sv1 = MFMA(LDK(b_, rb + 2048 + co1), qf[1], sv1);                          \
    if (DO_PV) {                                                               \
      Oc0 = MFMA(LDV(b_ ^ 1, rb + co1), BF(pfB), Oc0);                         \
      Oc1 = MFMA(LDV(b_ ^ 1, rb + 2048 + co1), BF(pfB), Oc1);                  \
    }                                                                          \
    sv0 = MFMA(LDK(b_, rb + co2), qf[2], sv0);                                 \
    sv1 = MFMA(LDK(b_, rb + 2048 + co2), qf[2], sv1);                          \
    if (DO_PV) {                                                               \
      Oc0 = MFMA(LDV(b_ ^ 1, rb + co2), BF(pfC), Oc0);                         \
      Oc1 = MFMA(LDV(b_ ^ 1, rb + 2048 + co2), BF(pfC), Oc1);                  \
    }                                                                          \
    sv0 = MFMA(LDK(b_, rb + co3), qf[3], sv0);                                 \
    sv1 = MFMA(LDK(b_, rb + 2048 + co3), qf[3], sv1);                          \
    if (DO_PV) {                                                               \
      Oc0 = MFMA(LDV(b_ ^ 1, rb + co3), BF(pfD), Oc0);                         \
      Oc1 = MFMA(LDV(b_ ^ 1, rb + 2048 + co3), BF(pfD), Oc1);                  \
    }                                                                          \
    __builtin_amdgcn_s_setprio(0);                                             \
    __syncthreads();   /* all LDS reads of Kt[b], Vts[b^1] complete */         \
    if (STG) {         /* stage tile T+1 into Kt[b^1], Vts[b^1] */             \
      _Pragma("unroll")                                                        \
      for (int j = 0; j < 2; ++j) {                                            \
        gload16(kS + ((T) + 1) * 4096 + j * 512, &KtB[(b_ ^ 1) * 4096 + kD + j * 512]); \
        gload16(vS + ((T) + 1) * 64 + j * 8192, &VtsB[(b_ ^ 1) * 4096 + kD + j * 512]); \
      }                                                                        \
    }                                                                          \
    /* ---- bias: CM (skipped when masks==0) + pos bit ---- */                 \
    if (hcm) {                                                                 \
      _Pragma("unroll")                                                        \
      for (int r2 = 0; r2 < 4; ++r2) {                                         \
        float b0[4], b1[4];                                                    \
        if constexpr (USE_CM) {                                                \
          uint2 c0 = *(const uint2*)(CMb + (T) * 64 + r2 * 8 + h4);            \
          uint2 c1 = *(const uint2*)(CMb + (T) * 64 + 32 + r2 * 8 + h4);       \
          b0[0] = __builtin_bit_cast(float, c0.x << 16);                       \
          b0[1] = __builtin_bit_cast(float, c0.x & 0xFFFF0000u);               \
          b0[2] = __builtin_bit_cast(float, c0.y << 16);                       \
          b0[3] = __builtin_bit_cast(float, c0.y & 0xFFFF0000u);               \
          b1[0] = __builtin_bit_cast(float, c1.x << 16);                       \
          b1[1] = __builtin_bit_cast(float, c1.x & 0xFFFF0000u);               \
          b1[2] = __builtin_bit_cast(float, c1.y << 16);                       \
          b1[3] = __builtin_bit_cast(float, c1.y & 0xFFFF0000u);               \
        } else {                                                               \
          float4 mv0 = *(const float4*)(mrowB + (T) * 64 + r2 * 8 + h4);       \
          float4 kv0 = *(const float4*)(krowB + (T) * 64 + r2 * 8 + h4);       \
          float4 mv1 = *(const float4*)(mrowB + (T) * 64 + 32 + r2 * 8 + h4);  \
          float4 kv1 = *(const float4*)(krowB + (T) * 64 + 32 + r2 * 8 + h4);  \
          b0[0] = (mv0.x + kv0.x) * TEMP2; b0[1] = (mv0.y + kv0.y) * TEMP2;    \
          b0[2] = (mv0.z + kv0.z) * TEMP2; b0[3] = (mv0.w + kv0.w) * TEMP2;    \
          b1[0] = (mv1.x + kv1.x) * TEMP2; b1[1] = (mv1.y + kv1.y) * TEMP2;    \
          b1[2] = (mv1.z + kv1.z) * TEMP2; b1[3] = (mv1.w + kv1.w) * TEMP2;    \
        }                                                                      \
        _Pragma("unroll")                                                      \
        for (int i = 0; i < 4; ++i) {                                          \
          sv0[r2 * 4 + i] += b0[i];                                            \
          sv1[r2 * 4 + i] += b1[i];                                            \
        }                                                                      \
      }                                                                        \
    }                                                                          \
    {                                                                          \
      unsigned pws0 = pwvL.x >> h4;                                            \
      unsigned pws1 = pwvL.y >> h4;                                            \
      _Pragma("unroll")                                                        \
      for (int r2 = 0; r2 < 4; ++r2)                                           \
        _Pragma("unroll")                                                      \
        for (int i = 0; i < 4; ++i) {                                          \
          float bit0 = (float)((pws0 >> (r2 * 8 + i)) & 1u);                   \
          float bit1 = (float)((pws1 >> (r2 * 8 + i)) & 1u);                   \
          sv0[r2 * 4 + i] = fmaf(bit0, delta2, sv0[r2 * 4 + i]);               \
          sv1[r2 * 4 + i] = fmaf(bit1, delta2, sv1[r2 * 4 + i]);               \
        }                                                                      \
    }                                                                          \
    /* ---- online softmax (row q: lanes l31, l31+32) ---- */                  \
    {                                                                          \
      float m8[8];                                                             \
      _Pragma("unroll")                                                        \
      for (int i = 0; i < 8; ++i)                                              \
        m8[i] = fmaxf(fmaxf(sv0[2 * i], sv0[2 * i + 1]),                       \
                      fmaxf(sv1[2 * i], sv1[2 * i + 1]));                      \
      float m4a = fmaxf(m8[0], m8[1]), m4b = fmaxf(m8[2], m8[3]);              \
      float m4c = fmaxf(m8[4], m8[5]), m4d = fmaxf(m8[6], m8[7]);              \
      float tmax = fmaxf(fmaxf(m4a, m4b), fmaxf(m4c, m4d));                    \
      tmax = fmaxf(tmax, __shfl_xor(tmax, 32));                                \
      if (!__all(tmax <= mrun + 4.0f)) {                                       \
        float mnew = fmaxf(mrun, tmax);                                        \
        float sc = __builtin_amdgcn_exp2f(mrun - mnew);                        \
        lrun *= sc;                                                            \
        Oc0 *= sc; Oc1 *= sc;                                                  \
        mrun = mnew;                                                           \
      }                                                                        \
      float s8[8];                                                             \
      _Pragma("unroll")                                                        \
      for (int i = 0; i < 8; ++i) {                                            \
        float p0 = __builtin_amdgcn_exp2f(sv0[2 * i] - mrun);                  \
        float p1 = __builtin_amdgcn_exp2f(sv0[2 * i + 1] - mrun);              \
        float p2 = __builtin_amdgcn_exp2f(sv1[2 * i] - mrun);                  \
        float p3 = __builtin_amdgcn_exp2f(sv1[2 * i + 1] - mrun);              \
        sv0[2 * i] = p0; sv0[2 * i + 1] = p1;                                  \
        sv1[2 * i] = p2; sv1[2 * i + 1] = p3;                                  \
        s8[i] = (p0 + p1) + (p2 + p3);                                         \
      }                                                                        \
      float s4a = s8[0] + s8[1], s4b = s8[2] + s8[3];                          \
      float s4c = s8[4] + s8[5], s4d = s8[6] + s8[7];                          \
      lrun += (s4a + s4b) + (s4c + s4d);   /* lane-partial; combined at end */ \
    }                                                                          \
    /* ---- pack P(T) -> pfA..pfD (pre-swapped B-frags) ---- */                \
    {                                                                          \
      unsigned a0 = cvtpk(sv0[0], sv0[1]),   a1 = cvtpk(sv0[2], sv0[3]);       \
      unsigned a2 = cvtpk(sv0[4], sv0[5]),   a3 = cvtpk(sv0[6], sv0[7]);       \
      plswap(a0, a2); plswap(a1, a3);                                          \
      pfA[0] = a0; pfA[1] = a1; pfA[2] = a2; pfA[3] = a3;                      \
      unsigned b0_ = cvtpk(sv0[8], sv0[9]),   b1_ = cvtpk(sv0[10], sv0[11]);   \
      unsigned b2_ = cvtpk(sv0[12], sv0[13]), b3_ = cvtpk(sv0[14], sv0[15]);   \
      plswap(b0_, b2_); plswap(b1_, b3_);                                      \
      pfB[0] = b0_; pfB[1] = b1_; pfB[2] = b2_; pfB[3] = b3_;                  \
      unsigned c0 = cvtpk(sv1[0], sv1[1]),   c1 = cvtpk(sv1[2], sv1[3]);       \
      unsigned c2 = cvtpk(sv1[4], sv1[5]),   c3 = cvtpk(sv1[6], sv1[7]);       \
      plswap(c0, c2); plswap(c1, c3);                                          \
      pfC[0] = c0; pfC[1] = c1; pfC[2] = c2; pfC[3] = c3;                      \
      unsigned d0 = cvtpk(sv1[8], sv1[9]),   d1 = cvtpk(sv1[10], sv1[11]);     \
      unsigned d2 = cvtpk(sv1[12], sv1[13]), d3 = cvtpk(sv1[14], sv1[15]);     \
      plswap(d0, d2); plswap(d1, d3);                                          \
      pfD[0] = d0; pfD[1] = d1; pfD[2] = d2; pfD[3] = d3;                      \
    }                                                                          \
    if (STG) __syncthreads();  /* staged tile ready (vmcnt drained) */         \
  }

  //     T  PV STG
  BODY( 0, 0, 1)
  BODY( 1, 1, 1)
  BODY( 2, 1, 1)
  BODY( 3, 1, 1)
  BODY( 4, 1, 1)
  BODY( 5, 1, 1)
  BODY( 6, 1, 1)
  BODY( 7, 1, 0)
#undef BODY

  // ---- epilogue PV(7): V(7) in Vts buf 1 (staged in body 6, intact) ----
  __builtin_amdgcn_s_setprio(1);
  Oc0 = MFMA(LDV(1, rb + co0), BF(pfA), Oc0);
  Oc1 = MFMA(LDV(1, rb + 2048 + co0), BF(pfA), Oc1);
  Oc0 = MFMA(LDV(1, rb + co1), BF(pfB), Oc0);
  Oc1 = MFMA(LDV(1, rb + 2048 + co1), BF(pfB), Oc1);
  Oc0 = MFMA(LDV(1, rb + co2), BF(pfC), Oc0);
  Oc1 = MFMA(LDV(1, rb + 2048 + co2), BF(pfC), Oc1);
  Oc0 = MFMA(LDV(1, rb + co3), BF(pfD), Oc0);
  Oc1 = MFMA(LDV(1, rb + 2048 + co3), BF(pfD), Oc1);
  __builtin_amdgcn_s_setprio(0);
#undef MFMA
#undef BF
#undef LDK
#undef LDV

  // ---- merge the two s-half groups (exact) and store ----
  float lw = lrun + __shfl_xor(lrun, 32);   // full row-sum for this s-half
  __syncthreads();                           // all K/V LDS reads done -> pool reusable
  float* mpool = (float*)pool;               // [256][36]
  if (g == 1) {
    float* row = mpool + (w4 * 64 + lane) * 36;
#pragma unroll
    for (int r2 = 0; r2 < 4; ++r2) {
      *(float4*)(row + r2 * 4) =
          make_float4(Oc0[4*r2+0], Oc0[4*r2+1], Oc0[4*r2+2], Oc0[4*r2+3]);
      *(float4*)(row + 16 + r2 * 4) =
          make_float4(Oc1[4*r2+0], Oc1[4*r2+1], Oc1[4*r2+2], Oc1[4*r2+3]);
    }
    row[32] = mrun;
    row[33] = lw;
  }
  __syncthreads();
  if (g == 0) {
    const float* row = mpool + (w4 * 64 + lane) * 36;
    float m1 = row[32], l1 = row[33];
    float mm = fmaxf(mrun, m1);
    float s0e = __builtin_amdgcn_exp2f(mrun - mm);
    float s1e = __builtin_amdgcn_exp2f(m1 - mm);
    float ltot = lw * s0e + l1 * s1e;
    float inv = 1.0f / ltot;
    float* orow = out + ((n * 1024 + l) * 16 + h) * 64;
#pragma unroll
    for (int r2 = 0; r2 < 4; ++r2) {
      float4 o;
      o.x = (Oc0[4*r2+0] * s0e + row[r2*4+0] * s1e) * inv;
      o.y = (Oc0[4*r2+1] * s0e + row[r2*4+1] * s1e) * inv;
      o.z = (Oc0[4*r2+2] * s0e + row[r2*4+2] * s1e) * inv;
      o.w = (Oc0[4*r2+3] * s0e + row[r2*4+3] * s1e) * inv;
      *(float4*)(orow + r2 * 8 + h4) = o;
      o.x = (Oc1[4*r2+0] * s0e + row[16+r2*4+0] * s1e) * inv;
      o.y = (Oc1[4*r2+1] * s0e + row[16+r2*4+1] * s1e) * inv;
      o.z = (Oc1[4*r2+2] * s0e + row[16+r2*4+2] * s1e) * inv;
      o.w = (Oc1[4*r2+3] * s0e + row[16+r2*4+3] * s1e) * inv;
      *(float4*)(orow + 32 + r2 * 8 + h4) = o;
    }
  }
}

extern "C" void kernel_launch(void* const* d_in, const int* in_sizes, int n_in,
                              void* d_out, int out_size, void* d_ws, size_t ws_size,
                              hipStream_t stream) {
  const float* Q    = (const float*)d_in[0];
  const float* K    = (const float*)d_in[1];
  const float* V    = (const float*)d_in[2];
  const float* mask = (const float*)d_in[3];
  const float* klm  = (const float*)d_in[4];
  const float* ptab = (const float*)d_in[5];
  const int*   pos  = (const int*)d_in[6];
  float* out = (float*)d_out;

  char* ws = (char*)d_ws;
  // layout: pospk 512K | Kp 8M | Vt 8M | flag 64B | CM 8M
  unsigned int*   pospk = (unsigned int*)ws;
  unsigned short* Kp    = (unsigned short*)(ws + (1 << 19));
  unsigned short* Vt    = (unsigned short*)(ws + (1 << 19) + (8 << 20));
  int*            cmf   = (int*)(ws + (1 << 19) + (16 << 20));
  unsigned short* CM    = (unsigned short*)(ws + (1 << 19) + (16 << 20) + 64);
  const size_t need_flag = (size_t)(1 << 19) + (size_t)(16 << 20) + 64;
  const size_t need_cm   = need_flag + (size_t)(8 << 20);
  const bool use_flag = ws_size >= need_flag;
  const bool use_cm   = ws_size >= need_cm;
  if (!use_flag) cmf = nullptr;

  if (use_flag) hipMemsetAsync(cmf, 0, 4, stream);
  k_prep<<<18688, 256, 0, stream>>>(pos, pospk, K, Kp, V, Vt, mask, klm, CM,
                                    cmf, use_cm ? 1 : 0);
  if (use_cm) {
    k_attn<true><<<512, 512, 0, stream>>>(Q, mask, klm, ptab, pospk, Kp, Vt,
                                          CM, cmf, out);
  } else {
    k_attn<false><<<512, 512, 0, stream>>>(Q, mask, klm, ptab, pospk, Kp, Vt,
                                           nullptr, cmf, out);
  }
}

// Round 12
// 69.083 us; speedup vs baseline: 3.6029x; 1.0220x over previous
//
#include <hip/hip_runtime.h>

// FullAttention_Spatial: N=4, L=S=1024, H=16, E=D=64, NUM_POS=2, fp32 in/out.
//
// score = temp*(QK + attn_mask[l,s] + klm[n,s]) + pos_table[pos[n,l,s]][h]
// pos in {0,1} => bias = T0[h] + bit*(T1[h]-T0[h]); T0 cancels in softmax.
// Log2-domain softmax; Q pre-scaled by temp2 = temp*log2e.
//
// R11 = R10 (best: 47.3us k_attn) + overhead cuts:
//  - CM prepass removed; flag-only scan of mask+klm (each element read once).
//    k_attn uses direct mask/klm loads, skipped entirely when flag==0.
//  - pospk TRANSPOSED to [n][s-word][l]: per-body pos-bit fetch becomes two
//    coalesced b32 loads (was a 64-cache-line gather at 128B lane stride).
// R10 structure kept: 8-wave (512-thr) blocks = 2 s-half groups x 4 waves,
// K dbuf x2 + V dbuf x2 = 64KB/block, grid 512 -> 4096 waves. 32x32x16 MFMA
// swapped QK^T, in-register P (permlane32_swap), defer-max, LDS-pool merge.
// NO occupancy attribute (R7-R10: hipcc min-occ spec = arg*waves_per_block,
// caps VGPR and spills; natural 108 VGPR is fine).
//
// MFMA 32x32x16: C col=lane&31, row=(reg&3)+8*(reg>>2)+4*(lane>>5);
// A row=lane&31, k=8*(lane>>5)+j. B col=lane&31, k=8*(lane>>5)+j.

typedef __attribute__((ext_vector_type(8))) __bf16 bf16x8;
typedef __attribute__((ext_vector_type(16))) float f32x16;
typedef __attribute__((ext_vector_type(4))) unsigned int u32x4;

#define TEMP2 (0.125f * 1.4426950408889634f)
#define LG2E 1.4426950408889634f

static __device__ __forceinline__ unsigned short f2bf(float x) {
  unsigned int u = __builtin_bit_cast(unsigned int, x);
  u += 0x7FFFu + ((u >> 16) & 1u);
  return (unsigned short)(u >> 16);
}
static __device__ __forceinline__ unsigned int cvtpk(float lo, float hi) {
  unsigned int r;
  asm("v_cvt_pk_bf16_f32 %0, %1, %2" : "=v"(r) : "v"(lo), "v"(hi));
  return r;
}
static __device__ __forceinline__ void gload16(const void* g, void* l) {
  __builtin_amdgcn_global_load_lds((const __attribute__((address_space(1))) void*)g,
                                   (__attribute__((address_space(3))) void*)l, 16, 0, 0);
}
// After: a = {a.lo32, b.lo32}, b = {a.hi32, b.hi32}
static __device__ __forceinline__ void plswap(unsigned int& a, unsigned int& b) {
  asm("v_permlane32_swap_b32 %0, %1" : "+v"(a), "+v"(b));
}

// ---------------- fused prepass ----------------
// blocks: [0,256) K relayout | [256,1280) V transpose | [1280,1536) mask scan
//         | 1536 klm scan | [1537, 17921) pos packing (transposed output)
__global__ __launch_bounds__(256) void k_prep(
    const int* __restrict__ pos, unsigned int* __restrict__ pospk,
    const float* __restrict__ K, unsigned short* __restrict__ Kp,
    const float* __restrict__ V, unsigned short* __restrict__ Vt,
    const float* __restrict__ mask, const float* __restrict__ klm,
    int* __restrict__ cmflag) {
  __shared__ float ld[64][65];
  int b = blockIdx.x;
  int tid = threadIdx.x;
  if (b < 256) {
    // ---- K relayout: [n][h][s][e], 16B blocks ^= (s&7) ----
    int idx = b * 256 + tid;           // ((n*1024+s)*16+h)
    int s = (idx >> 4) & 1023;
    const float* src = K + idx * 64;
    unsigned short row[64];
#pragma unroll
    for (int j = 0; j < 16; ++j) {
      float4 v = *(const float4*)(src + j * 4);
      row[j*4+0] = f2bf(v.x); row[j*4+1] = f2bf(v.y);
      row[j*4+2] = f2bf(v.z); row[j*4+3] = f2bf(v.w);
    }
    int n = idx >> 14, h = idx & 15;
    unsigned short* dst = Kp + ((n * 16 + h) * 1024 + s) * 64;
#pragma unroll
    for (int bb = 0; bb < 8; ++bb) {
      int pb = bb ^ (s & 7);
      *(u32x4*)(dst + pb * 8) = *(const u32x4*)(&row[bb * 8]);
    }
  } else if (b < 1280) {
    // ---- V transpose: [n][h][d][s], per-64s-seg 16B blocks ^= (d&7) ----
    int vb = b - 256;
    int t = vb & 15, h = (vb >> 4) & 15, n = vb >> 8;
    {
      int s = tid >> 2, dq = (tid & 3) * 16;
      const float* src = V + ((n * 1024 + t * 64 + s) * 16 + h) * 64 + dq;
#pragma unroll
      for (int j = 0; j < 4; ++j) {
        float4 v = *(const float4*)(src + j * 4);
        ld[s][dq + j*4 + 0] = v.x; ld[s][dq + j*4 + 1] = v.y;
        ld[s][dq + j*4 + 2] = v.z; ld[s][dq + j*4 + 3] = v.w;
      }
    }
    __syncthreads();
    {
      int d = tid >> 2, sq = (tid & 3) * 16;
      unsigned short vals[16];
#pragma unroll
      for (int k = 0; k < 16; ++k) vals[k] = f2bf(ld[sq + k][d]);
      unsigned short* dst = Vt + ((n * 16 + h) * 64 + d) * 1024 + t * 64;
#pragma unroll
      for (int cb = 0; cb < 2; ++cb) {
        int blk = (sq >> 3) + cb;
        int pb = blk ^ (d & 7);
        *(u32x4*)(dst + pb * 8) = *(const u32x4*)(&vals[cb * 8]);
      }
    }
  } else if (b < 1536) {
    // ---- mask nonzero scan (each element once) ----
    if (!cmflag) return;
    int base = ((b - 1280) * 256 + tid) * 16;
    const float* m = mask + base;
    float acc = 0.f;
#pragma unroll
    for (int j = 0; j < 4; ++j) {
      float4 v = *(const float4*)(m + j * 4);
      acc += __builtin_fabsf(v.x) + __builtin_fabsf(v.y) +
             __builtin_fabsf(v.z) + __builtin_fabsf(v.w);
    }
    unsigned long long bal = __ballot(acc != 0.f);
    if ((tid & 63) == 0 && bal != 0ull) atomicOr(cmflag, 1);
  } else if (b == 1536) {
    // ---- klm nonzero scan ----
    if (!cmflag) return;
    const float* m = klm + tid * 16;
    float acc = 0.f;
#pragma unroll
    for (int j = 0; j < 4; ++j) {
      float4 v = *(const float4*)(m + j * 4);
      acc += __builtin_fabsf(v.x) + __builtin_fabsf(v.y) +
             __builtin_fabsf(v.z) + __builtin_fabsf(v.w);
    }
    unsigned long long bal = __ballot(acc != 0.f);
    if ((tid & 63) == 0 && bal != 0ull) atomicOr(cmflag, 1);
  } else {
    // ---- pack pos bits, TRANSPOSED: pospk[(n*32 + sword)*1024 + l] ----
    int gi = (b - 1537) * 256 + tid;   // flat [N][L][S]
    int v = pos[gi];
    unsigned long long m = __ballot(v & 1);
    int lane = tid & 63;
    if (lane == 0 || lane == 32) {
      int n = gi >> 20, l = (gi >> 10) & 1023, sw = (gi & 1023) >> 5;
      pospk[(n * 32 + sw) * 1024 + l] =
          (lane == 0) ? (unsigned int)m : (unsigned int)(m >> 32);
    }
  }
}

// ---------------- main flash-attention kernel ----------------
// grid 512 = lblk*64 + n*16 + h ; 512 thr = 2 s-groups x 4 waves x 64.
// Group g covers s-tiles [g*8, g*8+8); 128 q-rows per block.
__global__ __launch_bounds__(512) void k_attn(
    const float* __restrict__ Q, const float* __restrict__ mask,
    const float* __restrict__ klm, const float* __restrict__ ptab,
    const unsigned int* __restrict__ pospk,
    const unsigned short* __restrict__ Kp, const unsigned short* __restrict__ Vt,
    const int* __restrict__ cmf,
    float* __restrict__ out) {
  // 64 KB pool: per group g: Kt[2] (2x8KB) then Vts[2] (2x8KB).
  // Reused as the merge buffer after the final tile barrier.
  __shared__ __align__(16) char pool[65536];

  int bid = blockIdx.x;
  int nh = bid & 63;
  int n = nh >> 4, h = nh & 15, lblk = bid >> 6;
  int tid = threadIdx.x;
  int w8 = tid >> 6, lane = tid & 63;
  int g = w8 >> 2, w4 = w8 & 3;
  int l31 = lane & 31, h5 = lane >> 5;
  int l = lblk * 128 + w4 * 32 + l31;  // this lane's q-row (global)
  const int hcm = cmf ? *cmf : 1;      // uniform: masks nonzero anywhere?

  unsigned short* KtB  = (unsigned short*)pool + g * 16384;         // [2][4096]
  unsigned short* VtsB = (unsigned short*)pool + g * 16384 + 8192;  // [2][4096]

  // Q fragments (B of swapped QK^T), pre-scaled by temp2
  const float* qrow = Q + ((n * 1024 + l) * 16 + h) * 64;
  bf16x8 qf[4];
#pragma unroll
  for (int ke = 0; ke < 4; ++ke) {
    float4 a = *(const float4*)(qrow + ke * 16 + h5 * 8);
    float4 bq = *(const float4*)(qrow + ke * 16 + h5 * 8 + 4);
    u32x4 pk;
    pk[0] = cvtpk(a.x * TEMP2, a.y * TEMP2);
    pk[1] = cvtpk(a.z * TEMP2, a.w * TEMP2);
    pk[2] = cvtpk(bq.x * TEMP2, bq.y * TEMP2);
    pk[3] = cvtpk(bq.z * TEMP2, bq.w * TEMP2);
    qf[ke] = __builtin_bit_cast(bf16x8, pk);
  }
  const float delta2 = (ptab[16 + h] - ptab[h]) * LG2E;

  float mrun = -1e30f, lrun = 0.f;
  f32x16 Oc0 = {0,0,0,0,0,0,0,0,0,0,0,0,0,0,0,0};
  f32x16 Oc1 = {0,0,0,0,0,0,0,0,0,0,0,0,0,0,0,0};
  u32x4 pfA = {0,0,0,0}, pfB = {0,0,0,0}, pfC = {0,0,0,0}, pfD = {0,0,0,0};

  const unsigned short* KpB = Kp + nh * 65536;
  const unsigned short* VtB = Vt + nh * 65536;
  const float* mrowB = mask + l * 1024 + g * 512;
  const float* krowB = klm + n * 1024 + g * 512;
  // transposed pos: word (g*8+T)*2 + {0,1} at [n*32 + sw]*1024 + l
  const unsigned int* posB = pospk + (n * 32 + g * 16) * 1024 + l;
  const int h4 = h5 * 4;

  // loop-invariant LDS read offsets (shorts)
  const int x7 = l31 & 7;
  const int co0 = ((0 + h5) ^ x7) * 8;
  const int co1 = ((2 + h5) ^ x7) * 8;
  const int co2 = ((4 + h5) ^ x7) * 8;
  const int co3 = ((6 + h5) ^ x7) * 8;
  const int rb = l31 * 64;

  // staging addresses: group stages its tile tg = g*8 + T
  const unsigned short* kS = KpB + g * 32768 + w4 * 1024 + lane * 8;
  const unsigned short* vS = VtB + (w4 * 16 + (lane >> 3)) * 1024 + g * 512 + (lane & 7) * 8;
  const int kD = w4 * 1024 + lane * 8;  // dst offset within Kt/Vts buf (shorts)

#define BF(x) __builtin_bit_cast(bf16x8, x)
#define MFMA(A, B, C) __builtin_amdgcn_mfma_f32_32x32x16_bf16(A, B, C, 0, 0, 0)
#define LDK(B_, OFF) BF(*(const u32x4*)&KtB[(B_) * 4096 + (OFF)])
#define LDV(B_, OFF) BF(*(const u32x4*)&VtsB[(B_) * 4096 + (OFF)])

  // ---- prologue: stage tile (g*8) into buf 0 ----
#pragma unroll
  for (int j = 0; j < 2; ++j) {
    gload16(kS + j * 512, &KtB[kD + j * 512]);
    gload16(vS + j * 8192, &VtsB[kD + j * 512]);
  }
  __syncthreads();

#define BODY(T, DO_PV, STG)                                                    \
  {                                                                            \
    const int b_ = (T) & 1;                                                    \
    unsigned pwx = posB[((T) * 2) * 1024];       /* coalesced b32 */           \
    unsigned pwy = posB[((T) * 2 + 1) * 1024];                                 \
    /* ---- MFMA block: QK(T) from Kt[b], PV(T-1) from Vts[b^1] ---- */        \
    f32x16 sv0 = {0,0,0,0,0,0,0,0,0,0,0,0,0,0,0,0};                            \
    f32x16 sv1 = {0,0,0,0,0,0,0,0,0,0,0,0,0,0,0,0};                            \
    __builtin_amdgcn_s_setprio(1);                                             \
    sv0 = MFMA(LDK(b_, rb + co0), qf[0], sv0);                                 \
    sv1 = MFMA(LDK(b_, rb + 2048 + co0), qf[0], sv1);                          \
    if (DO_PV) {                                                               \
      Oc0 = MFMA(LDV(b_ ^ 1, rb + co0), BF(pfA), Oc0);                         \
      Oc1 = MFMA(LDV(b_ ^ 1, rb + 2048 + co0), BF(pfA), Oc1);                  \
    }                                                                          \
    sv0 = MFMA(LDK(b_, rb + co1), qf[1], sv0);                                 \
    sv1 = MFMA(LDK(b_, rb + 2048 + co1), qf[1], sv1);                          \
    if (DO_PV) {                                                               \
      Oc0 = MFMA(LDV(b_ ^ 1, rb + co1), BF(pfB), Oc0);                         \
      Oc1 = MFMA(LDV(b_ ^ 1, rb + 2048 + co1), BF(pfB), Oc1);                  \
    }                                                                          \
    sv0 = MFMA(LDK(b_, rb + co2), qf[2], sv0);                                 \
    sv1 = MFMA(LDK(b_, rb + 2048 + co2), qf[2], sv1);                          \
    if (DO_PV) {                                                               \
      Oc0 = MFMA(LDV(b_ ^ 1, rb + co2), BF(pfC), Oc0);                         \
      Oc1 = MFMA(LDV(b_ ^ 1, rb + 2048 + co2), BF(pfC), Oc1);                  \
    }                                                                          \
    sv0 = MFMA(LDK(b_, rb + co3), qf[3], sv0);                                 \
    sv1 = MFMA(LDK(b_, rb + 2048 + co3), qf[3], sv1);                          \
    if (DO_PV) {                                                               \
      Oc0 = MFMA(LDV(b_ ^ 1, rb + co3), BF(pfD), Oc0);                         \
      Oc1 = MFMA(LDV(b_ ^ 1, rb + 2048 + co3), BF(pfD), Oc1);                  \
    }                                                                          \
    __builtin_amdgcn_s_setprio(0);                                             \
    __syncthreads();   /* all LDS reads of Kt[b], Vts[b^1] complete */         \
    if (STG) {         /* stage tile T+1 into Kt[b^1], Vts[b^1] */             \
      _Pragma("unroll")                                                        \
      for (int j = 0; j < 2; ++j) {                                            \
        gload16(kS + ((T) + 1) * 4096 + j * 512, &KtB[(b_ ^ 1) * 4096 + kD + j * 512]); \
        gload16(vS + ((T) + 1) * 64 + j * 8192, &VtsB[(b_ ^ 1) * 4096 + kD + j * 512]); \
      }                                                                        \
    }                                                                          \
    /* ---- bias: mask+klm (skipped when masks==0) + pos bit ---- */           \
    if (hcm) {                                                                 \
      _Pragma("unroll")                                                        \
      for (int r2 = 0; r2 < 4; ++r2) {                                         \
        float4 mv0 = *(const float4*)(mrowB + (T) * 64 + r2 * 8 + h4);         \
        float4 kv0 = *(const float4*)(krowB + (T) * 64 + r2 * 8 + h4);         \
        float4 mv1 = *(const float4*)(mrowB + (T) * 64 + 32 + r2 * 8 + h4);    \
        float4 kv1 = *(const float4*)(krowB + (T) * 64 + 32 + r2 * 8 + h4);    \
        sv0[r2 * 4 + 0] += (mv0.x + kv0.x) * TEMP2;                            \
        sv0[r2 * 4 + 1] += (mv0.y + kv0.y) * TEMP2;                            \
        sv0[r2 * 4 + 2] += (mv0.z + kv0.z) * TEMP2;                            \
        sv0[r2 * 4 + 3] += (mv0.w + kv0.w) * TEMP2;                            \
        sv1[r2 * 4 + 0] += (mv1.x + kv1.x) * TEMP2;                            \
        sv1[r2 * 4 + 1] += (mv1.y + kv1.y) * TEMP2;                            \
        sv1[r2 * 4 + 2] += (mv1.z + kv1.z) * TEMP2;                            \
        sv1[r2 * 4 + 3] += (mv1.w + kv1.w) * TEMP2;                            \
      }                                                                        \
    }                                                                          \
    {                                                                          \
      unsigned pws0 = pwx >> h4;                                               \
      unsigned pws1 = pwy >> h4;                                               \
      _Pragma("unroll")                                                        \
      for (int r2 = 0; r2 < 4; ++r2)                                           \
        _Pragma("unroll")                                                      \
        for (int i = 0; i < 4; ++i) {                                          \
          float bit0 = (float)((pws0 >> (r2 * 8 + i)) & 1u);                   \
          float bit1 = (float)((pws1 >> (r2 * 8 + i)) & 1u);                   \
          sv0[r2 * 4 + i] = fmaf(bit0, delta2, sv0[r2 * 4 + i]);               \
          sv1[r2 * 4 + i] = fmaf(bit1, delta2, sv1[r2 * 4 + i]);               \
        }                                                                      \
    }                                                                          \
    /* ---- online softmax (row q: lanes l31, l31+32) ---- */                  \
    {                                                                          \
      float m8[8];                                                             \
      _Pragma("unroll")                                                        \
      for (int i = 0; i < 8; ++i)                                              \
        m8[i] = fmaxf(fmaxf(sv0[2 * i], sv0[2 * i + 1]),                       \
                      fmaxf(sv1[2 * i], sv1[2 * i + 1]));                      \
      float m4a = fmaxf(m8[0], m8[1]), m4b = fmaxf(m8[2], m8[3]);              \
      float m4c = fmaxf(m8[4], m8[5]), m4d = fmaxf(m8[6], m8[7]);              \
      float tmax = fmaxf(fmaxf(m4a, m4b), fmaxf(m4c, m4d));                    \
      tmax = fmaxf(tmax, __shfl_xor(tmax, 32));                                \
      if (!__all(tmax <= mrun + 4.0f)) {                                       \
        float mnew = fmaxf(mrun, tmax);                                        \
        float sc = __builtin_amdgcn_exp2f(mrun - mnew);                        \
        lrun *= sc;                                                            \
        Oc0 *= sc; Oc1 *= sc;                                                  \
        mrun = mnew;                                                           \
      }                                                                        \
      float s8[8];                                                             \
      _Pragma("unroll")                                                        \
      for (int i = 0; i < 8; ++i) {                                            \
        float p0 = __builtin_amdgcn_exp2f(sv0[2 * i] - mrun);                  \
        float p1 = __builtin_amdgcn_exp2f(sv0[2 * i + 1] - mrun);              \
        float p2 = __builtin_amdgcn_exp2f(sv1[2 * i] - mrun);                  \
        float p3 = __builtin_amdgcn_exp2f(sv1[2 * i + 1] - mrun);              \
        sv0[2 * i] = p0; sv0[2 * i + 1] = p1;                                  \
        sv1[2 * i] = p2; sv1[2 * i + 1] = p3;                                  \
        s8[i] = (p0 + p1) + (p2 + p3);                                         \
      }                                                                        \
      float s4a = s8[0] + s8[1], s4b = s8[2] + s8[3];                          \
      float s4c = s8[4] + s8[5], s4d = s8[6] + s8[7];                          \
      lrun += (s4a + s4b) + (s4c + s4d);   /* lane-partial; combined at end */ \
    }                                                                          \
    /* ---- pack P(T) -> pfA..pfD (pre-swapped B-frags) ---- */                \
    {                                                                          \
      unsigned a0 = cvtpk(sv0[0], sv0[1]),   a1 = cvtpk(sv0[2], sv0[3]);       \
      unsigned a2 = cvtpk(sv0[4], sv0[5]),   a3 = cvtpk(sv0[6], sv0[7]);       \
      plswap(a0, a2); plswap(a1, a3);                                          \
      pfA[0] = a0; pfA[1] = a1; pfA[2] = a2; pfA[3] = a3;                      \
      unsigned b0_ = cvtpk(sv0[8], sv0[9]),   b1_ = cvtpk(sv0[10], sv0[11]);   \
      unsigned b2_ = cvtpk(sv0[12], sv0[13]), b3_ = cvtpk(sv0[14], sv0[15]);   \
      plswap(b0_, b2_); plswap(b1_, b3_);                                      \
      pfB[0] = b0_; pfB[1] = b1_; pfB[2] = b2_; pfB[3] = b3_;                  \
      unsigned c0 = cvtpk(sv1[0], sv1[1]),   c1 = cvtpk(sv1[2], sv1[3]);       \
      unsigned c2 = cvtpk(sv1[4], sv1[5]),   c3 = cvtpk(sv1[6], sv1[7]);       \
      plswap(c0, c2); plswap(c1, c3);                                          \
      pfC[0] = c0; pfC[1] = c1; pfC[2] = c2; pfC[3] = c3;                      \
      unsigned d0 = cvtpk(sv1[8], sv1[9]),   d1 = cvtpk(sv1[10], sv1[11]);     \
      unsigned d2 = cvtpk(sv1[12], sv1[13]), d3 = cvtpk(sv1[14], sv1[15]);     \
      plswap(d0, d2); plswap(d1, d3);                                          \
      pfD[0] = d0; pfD[1] = d1; pfD[2] = d2; pfD[3] = d3;                      \
    }                                                                          \
    if (STG) __syncthreads();  /* staged tile ready (vmcnt drained) */         \
  }

  //     T  PV STG
  BODY( 0, 0, 1)
  BODY( 1, 1, 1)
  BODY( 2, 1, 1)
  BODY( 3, 1, 1)
  BODY( 4, 1, 1)
  BODY( 5, 1, 1)
  BODY( 6, 1, 1)
  BODY( 7, 1, 0)
#undef BODY

  // ---- epilogue PV(7): V(7) in Vts buf 1 (staged in body 6, intact) ----
  __builtin_amdgcn_s_setprio(1);
  Oc0 = MFMA(LDV(1, rb + co0), BF(pfA), Oc0);
  Oc1 = MFMA(LDV(1, rb + 2048 + co0), BF(pfA), Oc1);
  Oc0 = MFMA(LDV(1, rb + co1), BF(pfB), Oc0);
  Oc1 = MFMA(LDV(1, rb + 2048 + co1), BF(pfB), Oc1);
  Oc0 = MFMA(LDV(1, rb + co2), BF(pfC), Oc0);
  Oc1 = MFMA(LDV(1, rb + 2048 + co2), BF(pfC), Oc1);
  Oc0 = MFMA(LDV(1, rb + co3), BF(pfD), Oc0);
  Oc1 = MFMA(LDV(1, rb + 2048 + co3), BF(pfD), Oc1);
  __builtin_amdgcn_s_setprio(0);
#undef MFMA
#undef BF
#undef LDK
#undef LDV

  // ---- merge the two s-half groups (exact) and store ----
  float lw = lrun + __shfl_xor(lrun, 32);   // full row-sum for this s-half
  __syncthreads();                           // all K/V LDS reads done -> pool reusable
  float* mpool = (float*)pool;               // [256][36]
  if (g == 1) {
    float* row = mpool + (w4 * 64 + lane) * 36;
#pragma unroll
    for (int r2 = 0; r2 < 4; ++r2) {
      *(float4*)(row + r2 * 4) =
          make_float4(Oc0[4*r2+0], Oc0[4*r2+1], Oc0[4*r2+2], Oc0[4*r2+3]);
      *(float4*)(row + 16 + r2 * 4) =
          make_float4(Oc1[4*r2+0], Oc1[4*r2+1], Oc1[4*r2+2], Oc1[4*r2+3]);
    }
    row[32] = mrun;
    row[33] = lw;
  }
  __syncthreads();
  if (g == 0) {
    const float* row = mpool + (w4 * 64 + lane) * 36;
    float m1 = row[32], l1 = row[33];
    float mm = fmaxf(mrun, m1);
    float s0e = __builtin_amdgcn_exp2f(mrun - mm);
    float s1e = __builtin_amdgcn_exp2f(m1 - mm);
    float ltot = lw * s0e + l1 * s1e;
    float inv = 1.0f / ltot;
    float* orow = out + ((n * 1024 + l) * 16 + h) * 64;
#pragma unroll
    for (int r2 = 0; r2 < 4; ++r2) {
      float4 o;
      o.x = (Oc0[4*r2+0] * s0e + row[r2*4+0] * s1e) * inv;
      o.y = (Oc0[4*r2+1] * s0e + row[r2*4+1] * s1e) * inv;
      o.z = (Oc0[4*r2+2] * s0e + row[r2*4+2] * s1e) * inv;
      o.w = (Oc0[4*r2+3] * s0e + row[r2*4+3] * s1e) * inv;
      *(float4*)(orow + r2 * 8 + h4) = o;
      o.x = (Oc1[4*r2+0] * s0e + row[16+r2*4+0] * s1e) * inv;
      o.y = (Oc1[4*r2+1] * s0e + row[16+r2*4+1] * s1e) * inv;
      o.z = (Oc1[4*r2+2] * s0e + row[16+r2*4+2] * s1e) * inv;
      o.w = (Oc1[4*r2+3] * s0e + row[16+r2*4+3] * s1e) * inv;
      *(float4*)(orow + 32 + r2 * 8 + h4) = o;
    }
  }
}

extern "C" void kernel_launch(void* const* d_in, const int* in_sizes, int n_in,
                              void* d_out, int out_size, void* d_ws, size_t ws_size,
                              hipStream_t stream) {
  const float* Q    = (const float*)d_in[0];
  const float* K    = (const float*)d_in[1];
  const float* V    = (const float*)d_in[2];
  const float* mask = (const float*)d_in[3];
  const float* klm  = (const float*)d_in[4];
  const float* ptab = (const float*)d_in[5];
  const int*   pos  = (const int*)d_in[6];
  float* out = (float*)d_out;

  char* ws = (char*)d_ws;
  // layout: pospk 512K | Kp 8M | Vt 8M | flag 64B
  unsigned int*   pospk = (unsigned int*)ws;
  unsigned short* Kp    = (unsigned short*)(ws + (1 << 19));
  unsigned short* Vt    = (unsigned short*)(ws + (1 << 19) + (8 << 20));
  int*            cmf   = (int*)(ws + (1 << 19) + (16 << 20));
  const size_t need_flag = (size_t)(1 << 19) + (size_t)(16 << 20) + 64;
  const bool use_flag = ws_size >= need_flag;
  if (!use_flag) cmf = nullptr;

  if (use_flag) hipMemsetAsync(cmf, 0, 4, stream);
  k_prep<<<17921, 256, 0, stream>>>(pos, pospk, K, Kp, V, Vt, mask, klm, cmf);
  k_attn<<<512, 512, 0, stream>>>(Q, mask, klm, ptab, pospk, Kp, Vt, cmf, out);
}

// Round 13
// 64.377 us; speedup vs baseline: 3.8663x; 1.0731x over previous
//
#include <hip/hip_runtime.h>

// FullAttention_Spatial: N=4, L=S=1024, H=16, E=D=64, NUM_POS=2, fp32 in/out.
//
// score = temp*(QK + attn_mask[l,s] + klm[n,s]) + pos_table[pos[n,l,s]][h]
// pos in {0,1} => bias = T0[h] + bit*(T1[h]-T0[h]); T0 cancels in softmax.
// Log2-domain softmax; Q pre-scaled by temp2 = temp*log2e.
//
// R12 = R11 + single-barrier body (R4's schedule on the 8-wave S-split):
//  - stage K(T+1)/V(T+1) at TOP of body T; K dbuf x2, V tbuf x3;
//    ONE __syncthreads per body (drains gload_lds; full-body latency window).
//  - buffers are 5 separately-NAMED __shared__ arrays picked by macro
//    literals so alias analysis can't force an early vmcnt drain.
//  - LDS 80KB/block (KA,KB + VA,VB,VC, 16KB each) = 160KiB/2 blocks exactly.
//  - merge of the two s-half groups routed through VA/VB in 2 rounds.
// Kept: 32x32x16 swapped QK^T, in-register P (permlane32_swap), defer-max,
// mask-skip flag, transposed pospk, swizzled K/V panels, no occupancy attr
// (hipcc min-occ spec = arg*waves_per_block -> spills; natural ~110 VGPR ok).
//
// MFMA 32x32x16: C col=lane&31, row=(reg&3)+8*(reg>>2)+4*(lane>>5);
// A row=lane&31, k=8*(lane>>5)+j. B col=lane&31, k=8*(lane>>5)+j.

typedef __attribute__((ext_vector_type(8))) __bf16 bf16x8;
typedef __attribute__((ext_vector_type(16))) float f32x16;
typedef __attribute__((ext_vector_type(4))) unsigned int u32x4;

#define TEMP2 (0.125f * 1.4426950408889634f)
#define LG2E 1.4426950408889634f

static __device__ __forceinline__ unsigned short f2bf(float x) {
  unsigned int u = __builtin_bit_cast(unsigned int, x);
  u += 0x7FFFu + ((u >> 16) & 1u);
  return (unsigned short)(u >> 16);
}
static __device__ __forceinline__ unsigned int cvtpk(float lo, float hi) {
  unsigned int r;
  asm("v_cvt_pk_bf16_f32 %0, %1, %2" : "=v"(r) : "v"(lo), "v"(hi));
  return r;
}
static __device__ __forceinline__ void gload16(const void* g, void* l) {
  __builtin_amdgcn_global_load_lds((const __attribute__((address_space(1))) void*)g,
                                   (__attribute__((address_space(3))) void*)l, 16, 0, 0);
}
// After: a = {a.lo32, b.lo32}, b = {a.hi32, b.hi32}
static __device__ __forceinline__ void plswap(unsigned int& a, unsigned int& b) {
  asm("v_permlane32_swap_b32 %0, %1" : "+v"(a), "+v"(b));
}

// ---------------- fused prepass (unchanged from R11) ----------------
__global__ __launch_bounds__(256) void k_prep(
    const int* __restrict__ pos, unsigned int* __restrict__ pospk,
    const float* __restrict__ K, unsigned short* __restrict__ Kp,
    const float* __restrict__ V, unsigned short* __restrict__ Vt,
    const float* __restrict__ mask, const float* __restrict__ klm,
    int* __restrict__ cmflag) {
  __shared__ float ld[64][65];
  int b = blockIdx.x;
  int tid = threadIdx.x;
  if (b < 256) {
    int idx = b * 256 + tid;           // ((n*1024+s)*16+h)
    int s = (idx >> 4) & 1023;
    const float* src = K + idx * 64;
    unsigned short row[64];
#pragma unroll
    for (int j = 0; j < 16; ++j) {
      float4 v = *(const float4*)(src + j * 4);
      row[j*4+0] = f2bf(v.x); row[j*4+1] = f2bf(v.y);
      row[j*4+2] = f2bf(v.z); row[j*4+3] = f2bf(v.w);
    }
    int n = idx >> 14, h = idx & 15;
    unsigned short* dst = Kp + ((n * 16 + h) * 1024 + s) * 64;
#pragma unroll
    for (int bb = 0; bb < 8; ++bb) {
      int pb = bb ^ (s & 7);
      *(u32x4*)(dst + pb * 8) = *(const u32x4*)(&row[bb * 8]);
    }
  } else if (b < 1280) {
    int vb = b - 256;
    int t = vb & 15, h = (vb >> 4) & 15, n = vb >> 8;
    {
      int s = tid >> 2, dq = (tid & 3) * 16;
      const float* src = V + ((n * 1024 + t * 64 + s) * 16 + h) * 64 + dq;
#pragma unroll
      for (int j = 0; j < 4; ++j) {
        float4 v = *(const float4*)(src + j * 4);
        ld[s][dq + j*4 + 0] = v.x; ld[s][dq + j*4 + 1] = v.y;
        ld[s][dq + j*4 + 2] = v.z; ld[s][dq + j*4 + 3] = v.w;
      }
    }
    __syncthreads();
    {
      int d = tid >> 2, sq = (tid & 3) * 16;
      unsigned short vals[16];
#pragma unroll
      for (int k = 0; k < 16; ++k) vals[k] = f2bf(ld[sq + k][d]);
      unsigned short* dst = Vt + ((n * 16 + h) * 64 + d) * 1024 + t * 64;
#pragma unroll
      for (int cb = 0; cb < 2; ++cb) {
        int blk = (sq >> 3) + cb;
        int pb = blk ^ (d & 7);
        *(u32x4*)(dst + pb * 8) = *(const u32x4*)(&vals[cb * 8]);
      }
    }
  } else if (b < 1536) {
    if (!cmflag) return;
    int base = ((b - 1280) * 256 + tid) * 16;
    const float* m = mask + base;
    float acc = 0.f;
#pragma unroll
    for (int j = 0; j < 4; ++j) {
      float4 v = *(const float4*)(m + j * 4);
      acc += __builtin_fabsf(v.x) + __builtin_fabsf(v.y) +
             __builtin_fabsf(v.z) + __builtin_fabsf(v.w);
    }
    unsigned long long bal = __ballot(acc != 0.f);
    if ((tid & 63) == 0 && bal != 0ull) atomicOr(cmflag, 1);
  } else if (b == 1536) {
    if (!cmflag) return;
    const float* m = klm + tid * 16;
    float acc = 0.f;
#pragma unroll
    for (int j = 0; j < 4; ++j) {
      float4 v = *(const float4*)(m + j * 4);
      acc += __builtin_fabsf(v.x) + __builtin_fabsf(v.y) +
             __builtin_fabsf(v.z) + __builtin_fabsf(v.w);
    }
    unsigned long long bal = __ballot(acc != 0.f);
    if ((tid & 63) == 0 && bal != 0ull) atomicOr(cmflag, 1);
  } else {
    // pack pos bits, TRANSPOSED: pospk[(n*32 + sword)*1024 + l]
    int gi = (b - 1537) * 256 + tid;   // flat [N][L][S]
    int v = pos[gi];
    unsigned long long m = __ballot(v & 1);
    int lane = tid & 63;
    if (lane == 0 || lane == 32) {
      int n = gi >> 20, l = (gi >> 10) & 1023, sw = (gi & 1023) >> 5;
      pospk[(n * 32 + sw) * 1024 + l] =
          (lane == 0) ? (unsigned int)m : (unsigned int)(m >> 32);
    }
  }
}

// ---------------- main flash-attention kernel ----------------
// grid 512 = lblk*64 + n*16 + h ; 512 thr = 2 s-groups x 4 waves x 64.
// Group g covers s-tiles [g*8, g*8+8); 128 q-rows per block.
__global__ __launch_bounds__(512) void k_attn(
    const float* __restrict__ Q, const float* __restrict__ mask,
    const float* __restrict__ klm, const float* __restrict__ ptab,
    const unsigned int* __restrict__ pospk,
    const unsigned short* __restrict__ Kp, const unsigned short* __restrict__ Vt,
    const int* __restrict__ cmf,
    float* __restrict__ out) {
  // 5 x 16KB named buffers (K x2, V x3); [group][4096 shorts] each.
  __shared__ __align__(16) unsigned short KBA[2][4096];
  __shared__ __align__(16) unsigned short KBB[2][4096];
  __shared__ __align__(16) unsigned short VBA[2][4096];
  __shared__ __align__(16) unsigned short VBB[2][4096];
  __shared__ __align__(16) unsigned short VBC[2][4096];

  int bid = blockIdx.x;
  int nh = bid & 63;
  int n = nh >> 4, h = nh & 15, lblk = bid >> 6;
  int tid = threadIdx.x;
  int w8 = tid >> 6, lane = tid & 63;
  int g = w8 >> 2, w4 = w8 & 3;
  int l31 = lane & 31, h5 = lane >> 5;
  int l = lblk * 128 + w4 * 32 + l31;  // this lane's q-row (global)
  const int hcm = cmf ? *cmf : 1;      // uniform: masks nonzero anywhere?

  // Q fragments (B of swapped QK^T), pre-scaled by temp2
  const float* qrow = Q + ((n * 1024 + l) * 16 + h) * 64;
  bf16x8 qf[4];
#pragma unroll
  for (int ke = 0; ke < 4; ++ke) {
    float4 a = *(const float4*)(qrow + ke * 16 + h5 * 8);
    float4 bq = *(const float4*)(qrow + ke * 16 + h5 * 8 + 4);
    u32x4 pk;
    pk[0] = cvtpk(a.x * TEMP2, a.y * TEMP2);
    pk[1] = cvtpk(a.z * TEMP2, a.w * TEMP2);
    pk[2] = cvtpk(bq.x * TEMP2, bq.y * TEMP2);
    pk[3] = cvtpk(bq.z * TEMP2, bq.w * TEMP2);
    qf[ke] = __builtin_bit_cast(bf16x8, pk);
  }
  const float delta2 = (ptab[16 + h] - ptab[h]) * LG2E;

  float mrun = -1e30f, lrun = 0.f;
  f32x16 Oc0 = {0,0,0,0,0,0,0,0,0,0,0,0,0,0,0,0};
  f32x16 Oc1 = {0,0,0,0,0,0,0,0,0,0,0,0,0,0,0,0};
  u32x4 pfA = {0,0,0,0}, pfB = {0,0,0,0}, pfC = {0,0,0,0}, pfD = {0,0,0,0};

  const unsigned short* KpB = Kp + nh * 65536;
  const unsigned short* VtB = Vt + nh * 65536;
  const float* mrowB = mask + l * 1024 + g * 512;
  const float* krowB = klm + n * 1024 + g * 512;
  const unsigned int* posB = pospk + (n * 32 + g * 16) * 1024 + l;
  const int h4 = h5 * 4;

  // loop-invariant LDS read offsets (shorts)
  const int x7 = l31 & 7;
  const int co0 = ((0 + h5) ^ x7) * 8;
  const int co1 = ((2 + h5) ^ x7) * 8;
  const int co2 = ((4 + h5) ^ x7) * 8;
  const int co3 = ((6 + h5) ^ x7) * 8;
  const int rb = l31 * 64;

  // staging addresses: group stages its tile tg = g*8 + T
  const unsigned short* kS = KpB + g * 32768 + w4 * 1024 + lane * 8;
  const unsigned short* vS = VtB + (w4 * 16 + (lane >> 3)) * 1024 + g * 512 + (lane & 7) * 8;
  const int kD = w4 * 1024 + lane * 8;  // dst offset within a buffer (shorts)

#define BF(x) __builtin_bit_cast(bf16x8, x)
#define MFMA(A, B, C) __builtin_amdgcn_mfma_f32_32x32x16_bf16(A, B, C, 0, 0, 0)
#define LDB(ARR, OFF) BF(*(const u32x4*)&ARR[g][(OFF)])

  // ---- prologue: stage tile (g*8): K->KBA, V->VBA ----
#pragma unroll
  for (int j = 0; j < 2; ++j) {
    gload16(kS + j * 512, &KBA[g][kD + j * 512]);
    gload16(vS + j * 8192, &VBA[g][kD + j * 512]);
  }
  __syncthreads();

#define BODY(T, KR, KW, VR, VW, DO_PV, STG)                                    \
  {                                                                            \
    unsigned pwx = posB[((T) * 2) * 1024];       /* coalesced b32 */           \
    unsigned pwy = posB[((T) * 2 + 1) * 1024];                                 \
    /* ---- stage tile T+1 at TOP: latency hides under whole body ---- */      \
    if (STG) {                                                                 \
      _Pragma("unroll")                                                        \
      for (int j = 0; j < 2; ++j) {                                            \
        gload16(kS + ((T) + 1) * 4096 + j * 512, &KW[g][kD + j * 512]);        \
        gload16(vS + ((T) + 1) * 64 + j * 8192, &VW[g][kD + j * 512]);         \
      }                                                                        \
    }                                                                          \
    /* ---- MFMA block: QK(T) from KR, PV(T-1) from VR ---- */                 \
    f32x16 sv0 = {0,0,0,0,0,0,0,0,0,0,0,0,0,0,0,0};                            \
    f32x16 sv1 = {0,0,0,0,0,0,0,0,0,0,0,0,0,0,0,0};                            \
    __builtin_amdgcn_s_setprio(1);                                             \
    sv0 = MFMA(LDB(KR, rb + co0), qf[0], sv0);                                 \
    sv1 = MFMA(LDB(KR, rb + 2048 + co0), qf[0], sv1);                          \
    if (DO_PV) {                                                               \
      Oc0 = MFMA(LDB(VR, rb + co0), BF(pfA), Oc0);                             \
      Oc1 = MFMA(LDB(VR, rb + 2048 + co0), BF(pfA), Oc1);                      \
    }                                                                          \
    sv0 = MFMA(LDB(KR, rb + co1), qf[1], sv0);                                 \
    sv1 = MFMA(LDB(KR, rb + 2048 + co1), qf[1], sv1);                          \
    if (DO_PV) {                                                               \
      Oc0 = MFMA(LDB(VR, rb + co1), BF(pfB), Oc0);                             \
      Oc1 = MFMA(LDB(VR, rb + 2048 + co1), BF(pfB), Oc1);                      \
    }                                                                          \
    sv0 = MFMA(LDB(KR, rb + co2), qf[2], sv0);                                 \
    sv1 = MFMA(LDB(KR, rb + 2048 + co2), qf[2], sv1);                          \
    if (DO_PV) {                                                               \
      Oc0 = MFMA(LDB(VR, rb + co2), BF(pfC), Oc0);                             \
      Oc1 = MFMA(LDB(VR, rb + 2048 + co2), BF(pfC), Oc1);                      \
    }                                                                          \
    sv0 = MFMA(LDB(KR, rb + co3), qf[3], sv0);                                 \
    sv1 = MFMA(LDB(KR, rb + 2048 + co3), qf[3], sv1);                          \
    if (DO_PV) {                                                               \
      Oc0 = MFMA(LDB(VR, rb + co3), BF(pfD), Oc0);                             \
      Oc1 = MFMA(LDB(VR, rb + 2048 + co3), BF(pfD), Oc1);                      \
    }                                                                          \
    __builtin_amdgcn_s_setprio(0);                                             \
    /* ---- bias: mask+klm (skipped when masks==0) + pos bit ---- */           \
    if (hcm) {                                                                 \
      _Pragma("unroll")                                                        \
      for (int r2 = 0; r2 < 4; ++r2) {                                         \
        float4 mv0 = *(const float4*)(mrowB + (T) * 64 + r2 * 8 + h4);         \
        float4 kv0 = *(const float4*)(krowB + (T) * 64 + r2 * 8 + h4);         \
        float4 mv1 = *(const float4*)(mrowB + (T) * 64 + 32 + r2 * 8 + h4);    \
        float4 kv1 = *(const float4*)(krowB + (T) * 64 + 32 + r2 * 8 + h4);    \
        sv0[r2 * 4 + 0] += (mv0.x + kv0.x) * TEMP2;                            \
        sv0[r2 * 4 + 1] += (mv0.y + kv0.y) * TEMP2;                            \
        sv0[r2 * 4 + 2] += (mv0.z + kv0.z) * TEMP2;                            \
        sv0[r2 * 4 + 3] += (mv0.w + kv0.w) * TEMP2;                            \
        sv1[r2 * 4 + 0] += (mv1.x + kv1.x) * TEMP2;                            \
        sv1[r2 * 4 + 1] += (mv1.y + kv1.y) * TEMP2;                            \
        sv1[r2 * 4 + 2] += (mv1.z + kv1.z) * TEMP2;                            \
        sv1[r2 * 4 + 3] += (mv1.w + kv1.w) * TEMP2;                            \
      }                                                                        \
    }                                                                          \
    {                                                                          \
      unsigned pws0 = pwx >> h4;                                               \
      unsigned pws1 = pwy >> h4;                                               \
      _Pragma("unroll")                                                        \
      for (int r2 = 0; r2 < 4; ++r2)                                           \
        _Pragma("unroll")                                                      \
        for (int i = 0; i < 4; ++i) {                                          \
          float bit0 = (float)((pws0 >> (r2 * 8 + i)) & 1u);                   \
          float bit1 = (float)((pws1 >> (r2 * 8 + i)) & 1u);                   \
          sv0[r2 * 4 + i] = fmaf(bit0, delta2, sv0[r2 * 4 + i]);               \
          sv1[r2 * 4 + i] = fmaf(bit1, delta2, sv1[r2 * 4 + i]);               \
        }                                                                      \
    }                                                                          \
    /* ---- online softmax (row q: lanes l31, l31+32) ---- */                  \
    {                                                                          \
      float m8[8];                                                             \
      _Pragma("unroll")                                                        \
      for (int i = 0; i < 8; ++i)                                              \
        m8[i] = fmaxf(fmaxf(sv0[2 * i], sv0[2 * i + 1]),                       \
                      fmaxf(sv1[2 * i], sv1[2 * i + 1]));                      \
      float m4a = fmaxf(m8[0], m8[1]), m4b = fmaxf(m8[2], m8[3]);              \
      float m4c = fmaxf(m8[4], m8[5]), m4d = fmaxf(m8[6], m8[7]);              \
      float tmax = fmaxf(fmaxf(m4a, m4b), fmaxf(m4c, m4d));                    \
      tmax = fmaxf(tmax, __shfl_xor(tmax, 32));                                \
      if (!__all(tmax <= mrun + 4.0f)) {                                       \
        float mnew = fmaxf(mrun, tmax);                                        \
        float sc = __builtin_amdgcn_exp2f(mrun - mnew);                        \
        lrun *= sc;                                                            \
        Oc0 *= sc; Oc1 *= sc;                                                  \
        mrun = mnew;                                                           \
      }                                                                        \
      float s8[8];                                                             \
      _Pragma("unroll")                                                        \
      for (int i = 0; i < 8; ++i) {                                            \
        float p0 = __builtin_amdgcn_exp2f(sv0[2 * i] - mrun);                  \
        float p1 = __builtin_amdgcn_exp2f(sv0[2 * i + 1] - mrun);              \
        float p2 = __builtin_amdgcn_exp2f(sv1[2 * i] - mrun);                  \
        float p3 = __builtin_amdgcn_exp2f(sv1[2 * i + 1] - mrun);              \
        sv0[2 * i] = p0; sv0[2 * i + 1] = p1;                                  \
        sv1[2 * i] = p2; sv1[2 * i + 1] = p3;                                  \
        s8[i] = (p0 + p1) + (p2 + p3);                                         \
      }                                                                        \
      float s4a = s8[0] + s8[1], s4b = s8[2] + s8[3];                          \
      float s4c = s8[4] + s8[5], s4d = s8[6] + s8[7];                          \
      lrun += (s4a + s4b) + (s4c + s4d);   /* lane-partial; combined at end */ \
    }                                                                          \
    /* ---- pack P(T) -> pfA..pfD (pre-swapped B-frags) ---- */                \
    {                                                                          \
      unsigned a0 = cvtpk(sv0[0], sv0[1]),   a1 = cvtpk(sv0[2], sv0[3]);       \
      unsigned a2 = cvtpk(sv0[4], sv0[5]),   a3 = cvtpk(sv0[6], sv0[7]);       \
      plswap(a0, a2); plswap(a1, a3);                                          \
      pfA[0] = a0; pfA[1] = a1; pfA[2] = a2; pfA[3] = a3;                      \
      unsigned b0_ = cvtpk(sv0[8], sv0[9]),   b1_ = cvtpk(sv0[10], sv0[11]);   \
      unsigned b2_ = cvtpk(sv0[12], sv0[13]), b3_ = cvtpk(sv0[14], sv0[15]);   \
      plswap(b0_, b2_); plswap(b1_, b3_);                                      \
      pfB[0] = b0_; pfB[1] = b1_; pfB[2] = b2_; pfB[3] = b3_;                  \
      unsigned c0 = cvtpk(sv1[0], sv1[1]),   c1 = cvtpk(sv1[2], sv1[3]);       \
      unsigned c2 = cvtpk(sv1[4], sv1[5]),   c3 = cvtpk(sv1[6], sv1[7]);       \
      plswap(c0, c2); plswap(c1, c3);                                          \
      pfC[0] = c0; pfC[1] = c1; pfC[2] = c2; pfC[3] = c3;                      \
      unsigned d0 = cvtpk(sv1[8], sv1[9]),   d1 = cvtpk(sv1[10], sv1[11]);     \
      unsigned d2 = cvtpk(sv1[12], sv1[13]), d3 = cvtpk(sv1[14], sv1[15]);     \
      plswap(d0, d2); plswap(d1, d3);                                          \
      pfD[0] = d0; pfD[1] = d1; pfD[2] = d2; pfD[3] = d3;                      \
    }                                                                          \
    if (STG) __syncthreads();  /* drains this body's gloads: T+1 ready */      \
  }

  // V(t) lives in buf t%3 (A,B,C); K(t) in buf t&1 (A,B).
  //     T   KR   KW   VR   VW  PV STG
  BODY( 0, KBA, KBB, VBA, VBB, 0, 1)
  BODY( 1, KBB, KBA, VBA, VBC, 1, 1)
  BODY( 2, KBA, KBB, VBB, VBA, 1, 1)
  BODY( 3, KBB, KBA, VBC, VBB, 1, 1)
  BODY( 4, KBA, KBB, VBA, VBC, 1, 1)
  BODY( 5, KBB, KBA, VBB, VBA, 1, 1)
  BODY( 6, KBA, KBB, VBC, VBB, 1, 1)
  BODY( 7, KBB, KBB, VBA, VBB, 1, 0)
#undef BODY

  // ---- epilogue PV(7): V(7) in VBB (staged body 6, ready at its barrier) ----
  __builtin_amdgcn_s_setprio(1);
  Oc0 = MFMA(LDB(VBB, rb + co0), BF(pfA), Oc0);
  Oc1 = MFMA(LDB(VBB, rb + 2048 + co0), BF(pfA), Oc1);
  Oc0 = MFMA(LDB(VBB, rb + co1), BF(pfB), Oc0);
  Oc1 = MFMA(LDB(VBB, rb + 2048 + co1), BF(pfB), Oc1);
  Oc0 = MFMA(LDB(VBB, rb + co2), BF(pfC), Oc0);
  Oc1 = MFMA(LDB(VBB, rb + 2048 + co2), BF(pfC), Oc1);
  Oc0 = MFMA(LDB(VBB, rb + co3), BF(pfD), Oc0);
  Oc1 = MFMA(LDB(VBB, rb + 2048 + co3), BF(pfD), Oc1);
  __builtin_amdgcn_s_setprio(0);
#undef MFMA
#undef BF
#undef LDB

  // ---- merge the two s-half groups (exact), 2 rounds via VBA/VBB ----
  float lw = lrun + __shfl_xor(lrun, 32);   // full row-sum for this s-half
  __syncthreads();                          // all K/V LDS reads complete
#pragma unroll
  for (int r = 0; r < 2; ++r) {
    if (g == 1 && (w4 >> 1) == r) {
      float* row = ((w4 & 1) ? (float*)VBB : (float*)VBA) + lane * 36;
#pragma unroll
      for (int r2 = 0; r2 < 4; ++r2) {
        *(float4*)(row + r2 * 4) =
            make_float4(Oc0[4*r2+0], Oc0[4*r2+1], Oc0[4*r2+2], Oc0[4*r2+3]);
        *(float4*)(row + 16 + r2 * 4) =
            make_float4(Oc1[4*r2+0], Oc1[4*r2+1], Oc1[4*r2+2], Oc1[4*r2+3]);
      }
      row[32] = mrun;
      row[33] = lw;
    }
    __syncthreads();
    if (g == 0 && (w4 >> 1) == r) {
      const float* row = ((w4 & 1) ? (float*)VBB : (float*)VBA) + lane * 36;
      float m1 = row[32], l1 = row[33];
      float mm = fmaxf(mrun, m1);
      float s0e = __builtin_amdgcn_exp2f(mrun - mm);
      float s1e = __builtin_amdgcn_exp2f(m1 - mm);
      float ltot = lw * s0e + l1 * s1e;
      float inv = 1.0f / ltot;
      float* orow = out + ((n * 1024 + l) * 16 + h) * 64;
#pragma unroll
      for (int r2 = 0; r2 < 4; ++r2) {
        float4 o;
        o.x = (Oc0[4*r2+0] * s0e + row[r2*4+0] * s1e) * inv;
        o.y = (Oc0[4*r2+1] * s0e + row[r2*4+1] * s1e) * inv;
        o.z = (Oc0[4*r2+2] * s0e + row[r2*4+2] * s1e) * inv;
        o.w = (Oc0[4*r2+3] * s0e + row[r2*4+3] * s1e) * inv;
        *(float4*)(orow + r2 * 8 + h4) = o;
        o.x = (Oc1[4*r2+0] * s0e + row[16+r2*4+0] * s1e) * inv;
        o.y = (Oc1[4*r2+1] * s0e + row[16+r2*4+1] * s1e) * inv;
        o.z = (Oc1[4*r2+2] * s0e + row[16+r2*4+2] * s1e) * inv;
        o.w = (Oc1[4*r2+3] * s0e + row[16+r2*4+3] * s1e) * inv;
        *(float4*)(orow + 32 + r2 * 8 + h4) = o;
      }
    }
    __syncthreads();
  }
}

extern "C" void kernel_launch(void* const* d_in, const int* in_sizes, int n_in,
                              void* d_out, int out_size, void* d_ws, size_t ws_size,
                              hipStream_t stream) {
  const float* Q    = (const float*)d_in[0];
  const float* K    = (const float*)d_in[1];
  const float* V    = (const float*)d_in[2];
  const float* mask = (const float*)d_in[3];
  const float* klm  = (const float*)d_in[4];
  const float* ptab = (const float*)d_in[5];
  const int*   pos  = (const int*)d_in[6];
  float* out = (float*)d_out;

  char* ws = (char*)d_ws;
  // layout: pospk 512K | Kp 8M | Vt 8M | flag 64B
  unsigned int*   pospk = (unsigned int*)ws;
  unsigned short* Kp    = (unsigned short*)(ws + (1 << 19));
  unsigned short* Vt    = (unsigned short*)(ws + (1 << 19) + (8 << 20));
  int*            cmf   = (int*)(ws + (1 << 19) + (16 << 20));
  const size_t need_flag = (size_t)(1 << 19) + (size_t)(16 << 20) + 64;
  const bool use_flag = ws_size >= need_flag;
  if (!use_flag) cmf = nullptr;

  if (use_flag) hipMemsetAsync(cmf, 0, 4, stream);
  k_prep<<<17921, 256, 0, stream>>>(pos, pospk, K, Kp, V, Vt, mask, klm, cmf);
  k_attn<<<512, 512, 0, stream>>>(Q, mask, klm, ptab, pospk, Kp, Vt, cmf, out);
}

// Round 14
// 64.369 us; speedup vs baseline: 3.8668x; 1.0001x over previous
//
#include <hip/hip_runtime.h>
#include <hip/hip_cooperative_groups.h>

// FullAttention_Spatial: N=4, L=S=1024, H=16, E=D=64, NUM_POS=2, fp32 in/out.
//
// score = temp*(QK + attn_mask[l,s] + klm[n,s]) + pos_table[pos[n,l,s]][h]
// pos in {0,1} => bias = T0[h] + bit*(T1[h]-T0[h]); T0 cancels in softmax.
// Log2-domain softmax; Q pre-scaled by temp2 = temp*log2e.
//
// R13 = R12 main loop (best: 43.4us) FUSED with a load-balanced prepass in
// one cooperative kernel (512 blocks x 512 thr = exactly 2 blocks/CU,
// grid.sync between phases). Eliminates memset + 2-launch gap + the
// 17921-block imbalanced prepass (1280 heavy / 16k trivial). Per-block flag
// array (plain stores, no init) replaces atomicOr+memset. Falls back to the
// R12 two-kernel path if cooperative launch is unavailable.
//
// MFMA 32x32x16: C col=lane&31, row=(reg&3)+8*(reg>>2)+4*(lane>>5);
// A row=lane&31, k=8*(lane>>5)+j. B col=lane&31, k=8*(lane>>5)+j.

namespace cg = cooperative_groups;

typedef __attribute__((ext_vector_type(8))) __bf16 bf16x8;
typedef __attribute__((ext_vector_type(16))) float f32x16;
typedef __attribute__((ext_vector_type(4))) unsigned int u32x4;

#define TEMP2 (0.125f * 1.4426950408889634f)
#define LG2E 1.4426950408889634f

static __device__ __forceinline__ unsigned short f2bf(float x) {
  unsigned int u = __builtin_bit_cast(unsigned int, x);
  u += 0x7FFFu + ((u >> 16) & 1u);
  return (unsigned short)(u >> 16);
}
static __device__ __forceinline__ unsigned int cvtpk(float lo, float hi) {
  unsigned int r;
  asm("v_cvt_pk_bf16_f32 %0, %1, %2" : "=v"(r) : "v"(lo), "v"(hi));
  return r;
}
static __device__ __forceinline__ void gload16(const void* g, void* l) {
  __builtin_amdgcn_global_load_lds((const __attribute__((address_space(1))) void*)g,
                                   (__attribute__((address_space(3))) void*)l, 16, 0, 0);
}
// After: a = {a.lo32, b.lo32}, b = {a.hi32, b.hi32}
static __device__ __forceinline__ void plswap(unsigned int& a, unsigned int& b) {
  asm("v_permlane32_swap_b32 %0, %1" : "+v"(a), "+v"(b));
}

// ======================= fallback two-kernel path (R12) =====================
__global__ __launch_bounds__(256) void k_prep(
    const int* __restrict__ pos, unsigned int* __restrict__ pospk,
    const float* __restrict__ K, unsigned short* __restrict__ Kp,
    const float* __restrict__ V, unsigned short* __restrict__ Vt,
    const float* __restrict__ mask, const float* __restrict__ klm,
    int* __restrict__ cmflag) {
  __shared__ float ld[64][65];
  int b = blockIdx.x;
  int tid = threadIdx.x;
  if (b < 256) {
    int idx = b * 256 + tid;
    int s = (idx >> 4) & 1023;
    const float* src = K + idx * 64;
    unsigned short row[64];
#pragma unroll
    for (int j = 0; j < 16; ++j) {
      float4 v = *(const float4*)(src + j * 4);
      row[j*4+0] = f2bf(v.x); row[j*4+1] = f2bf(v.y);
      row[j*4+2] = f2bf(v.z); row[j*4+3] = f2bf(v.w);
    }
    int n = idx >> 14, h = idx & 15;
    unsigned short* dst = Kp + ((n * 16 + h) * 1024 + s) * 64;
#pragma unroll
    for (int bb = 0; bb < 8; ++bb) {
      int pb = bb ^ (s & 7);
      *(u32x4*)(dst + pb * 8) = *(const u32x4*)(&row[bb * 8]);
    }
  } else if (b < 1280) {
    int vb = b - 256;
    int t = vb & 15, h = (vb >> 4) & 15, n = vb >> 8;
    {
      int s = tid >> 2, dq = (tid & 3) * 16;
      const float* src = V + ((n * 1024 + t * 64 + s) * 16 + h) * 64 + dq;
#pragma unroll
      for (int j = 0; j < 4; ++j) {
        float4 v = *(const float4*)(src + j * 4);
        ld[s][dq + j*4 + 0] = v.x; ld[s][dq + j*4 + 1] = v.y;
        ld[s][dq + j*4 + 2] = v.z; ld[s][dq + j*4 + 3] = v.w;
      }
    }
    __syncthreads();
    {
      int d = tid >> 2, sq = (tid & 3) * 16;
      unsigned short vals[16];
#pragma unroll
      for (int k = 0; k < 16; ++k) vals[k] = f2bf(ld[sq + k][d]);
      unsigned short* dst = Vt + ((n * 16 + h) * 64 + d) * 1024 + t * 64;
#pragma unroll
      for (int cb = 0; cb < 2; ++cb) {
        int blk = (sq >> 3) + cb;
        int pb = blk ^ (d & 7);
        *(u32x4*)(dst + pb * 8) = *(const u32x4*)(&vals[cb * 8]);
      }
    }
  } else if (b < 1536) {
    if (!cmflag) return;
    int base = ((b - 1280) * 256 + tid) * 16;
    const float* m = mask + base;
    float acc = 0.f;
#pragma unroll
    for (int j = 0; j < 4; ++j) {
      float4 v = *(const float4*)(m + j * 4);
      acc += __builtin_fabsf(v.x) + __builtin_fabsf(v.y) +
             __builtin_fabsf(v.z) + __builtin_fabsf(v.w);
    }
    unsigned long long bal = __ballot(acc != 0.f);
    if ((tid & 63) == 0 && bal != 0ull) atomicOr(cmflag, 1);
  } else if (b == 1536) {
    if (!cmflag) return;
    const float* m = klm + tid * 16;
    float acc = 0.f;
#pragma unroll
    for (int j = 0; j < 4; ++j) {
      float4 v = *(const float4*)(m + j * 4);
      acc += __builtin_fabsf(v.x) + __builtin_fabsf(v.y) +
             __builtin_fabsf(v.z) + __builtin_fabsf(v.w);
    }
    unsigned long long bal = __ballot(acc != 0.f);
    if ((tid & 63) == 0 && bal != 0ull) atomicOr(cmflag, 1);
  } else {
    int gi = (b - 1537) * 256 + tid;
    int v = pos[gi];
    unsigned long long m = __ballot(v & 1);
    int lane = tid & 63;
    if (lane == 0 || lane == 32) {
      int n = gi >> 20, l = (gi >> 10) & 1023, sw = (gi & 1023) >> 5;
      pospk[(n * 32 + sw) * 1024 + l] =
          (lane == 0) ? (unsigned int)m : (unsigned int)(m >> 32);
    }
  }
}

// ---- the main-loop body, shared by fallback k_attn and fused kernel ----
// (expanded as a macro over the 5 named LDS buffers)
#define ATTN_MAIN(HCMEXPR)                                                     \
  int nh = bid & 63;                                                           \
  int n = nh >> 4, h = nh & 15, lblk = bid >> 6;                               \
  int w8 = tid >> 6, lane = tid & 63;                                          \
  int g = w8 >> 2, w4 = w8 & 3;                                                \
  int l31 = lane & 31, h5 = lane >> 5;                                         \
  int l = lblk * 128 + w4 * 32 + l31;                                          \
  const int hcm = (HCMEXPR);                                                   \
  const float* qrow = Q + ((n * 1024 + l) * 16 + h) * 64;                      \
  bf16x8 qf[4];                                                                \
  _Pragma("unroll")                                                            \
  for (int ke = 0; ke < 4; ++ke) {                                             \
    float4 a = *(const float4*)(qrow + ke * 16 + h5 * 8);                      \
    float4 bq = *(const float4*)(qrow + ke * 16 + h5 * 8 + 4);                 \
    u32x4 pk;                                                                  \
    pk[0] = cvtpk(a.x * TEMP2, a.y * TEMP2);                                   \
    pk[1] = cvtpk(a.z * TEMP2, a.w * TEMP2);                                   \
    pk[2] = cvtpk(bq.x * TEMP2, bq.y * TEMP2);                                 \
    pk[3] = cvtpk(bq.z * TEMP2, bq.w * TEMP2);                                 \
    qf[ke] = __builtin_bit_cast(bf16x8, pk);                                   \
  }                                                                            \
  const float delta2 = (ptab[16 + h] - ptab[h]) * LG2E;                        \
  float mrun = -1e30f, lrun = 0.f;                                             \
  f32x16 Oc0 = {0,0,0,0,0,0,0,0,0,0,0,0,0,0,0,0};                              \
  f32x16 Oc1 = {0,0,0,0,0,0,0,0,0,0,0,0,0,0,0,0};                              \
  u32x4 pfA = {0,0,0,0}, pfB = {0,0,0,0}, pfC = {0,0,0,0}, pfD = {0,0,0,0};    \
  const unsigned short* KpB = Kp + nh * 65536;                                 \
  const unsigned short* VtB = Vt + nh * 65536;                                 \
  const float* mrowB = mask + l * 1024 + g * 512;                              \
  const float* krowB = klm + n * 1024 + g * 512;                               \
  const unsigned int* posB = pospk + (n * 32 + g * 16) * 1024 + l;             \
  const int h4 = h5 * 4;                                                       \
  const int x7 = l31 & 7;                                                      \
  const int co0 = ((0 + h5) ^ x7) * 8;                                         \
  const int co1 = ((2 + h5) ^ x7) * 8;                                         \
  const int co2 = ((4 + h5) ^ x7) * 8;                                         \
  const int co3 = ((6 + h5) ^ x7) * 8;                                         \
  const int rb = l31 * 64;                                                     \
  const unsigned short* kS = KpB + g * 32768 + w4 * 1024 + lane * 8;           \
  const unsigned short* vS = VtB + (w4 * 16 + (lane >> 3)) * 1024 + g * 512 +  \
                             (lane & 7) * 8;                                   \
  const int kD = w4 * 1024 + lane * 8;                                         \
  _Pragma("unroll")                                                            \
  for (int j = 0; j < 2; ++j) {                                                \
    gload16(kS + j * 512, &KBA[g][kD + j * 512]);                              \
    gload16(vS + j * 8192, &VBA[g][kD + j * 512]);                             \
  }                                                                            \
  __syncthreads();                                                             \
  BODY( 0, KBA, KBB, VBA, VBB, 0, 1)                                           \
  BODY( 1, KBB, KBA, VBA, VBC, 1, 1)                                           \
  BODY( 2, KBA, KBB, VBB, VBA, 1, 1)                                           \
  BODY( 3, KBB, KBA, VBC, VBB, 1, 1)                                           \
  BODY( 4, KBA, KBB, VBA, VBC, 1, 1)                                           \
  BODY( 5, KBB, KBA, VBB, VBA, 1, 1)                                           \
  BODY( 6, KBA, KBB, VBC, VBB, 1, 1)                                           \
  BODY( 7, KBB, KBB, VBA, VBB, 1, 0)                                           \
  __builtin_amdgcn_s_setprio(1);                                               \
  Oc0 = MFMA(LDB(VBB, rb + co0), BF(pfA), Oc0);                                \
  Oc1 = MFMA(LDB(VBB, rb + 2048 + co0), BF(pfA), Oc1);                         \
  Oc0 = MFMA(LDB(VBB, rb + co1), BF(pfB), Oc0);                                \
  Oc1 = MFMA(LDB(VBB, rb + 2048 + co1), BF(pfB), Oc1);                         \
  Oc0 = MFMA(LDB(VBB, rb + co2), BF(pfC), Oc0);                                \
  Oc1 = MFMA(LDB(VBB, rb + 2048 + co2), BF(pfC), Oc1);                         \
  Oc0 = MFMA(LDB(VBB, rb + co3), BF(pfD), Oc0);                                \
  Oc1 = MFMA(LDB(VBB, rb + 2048 + co3), BF(pfD), Oc1);                         \
  __builtin_amdgcn_s_setprio(0);                                               \
  float lw = lrun + __shfl_xor(lrun, 32);                                      \
  __syncthreads();                                                             \
  _Pragma("unroll")                                                            \
  for (int r = 0; r < 2; ++r) {                                                \
    if (g == 1 && (w4 >> 1) == r) {                                            \
      float* row = ((w4 & 1) ? (float*)VBB : (float*)VBA) + lane * 36;         \
      _Pragma("unroll")                                                        \
      for (int r2 = 0; r2 < 4; ++r2) {                                         \
        *(float4*)(row + r2 * 4) =                                             \
            make_float4(Oc0[4*r2+0], Oc0[4*r2+1], Oc0[4*r2+2], Oc0[4*r2+3]);   \
        *(float4*)(row + 16 + r2 * 4) =                                        \
            make_float4(Oc1[4*r2+0], Oc1[4*r2+1], Oc1[4*r2+2], Oc1[4*r2+3]);   \
      }                                                                        \
      row[32] = mrun;                                                          \
      row[33] = lw;                                                            \
    }                                                                          \
    __syncthreads();                                                           \
    if (g == 0 && (w4 >> 1) == r) {                                            \
      const float* row = ((w4 & 1) ? (float*)VBB : (float*)VBA) + lane * 36;   \
      float m1 = row[32], l1 = row[33];                                        \
      float mm = fmaxf(mrun, m1);                                              \
      float s0e = __builtin_amdgcn_exp2f(mrun - mm);                           \
      float s1e = __builtin_amdgcn_exp2f(m1 - mm);                             \
      float ltot = lw * s0e + l1 * s1e;                                        \
      float inv = 1.0f / ltot;                                                 \
      float* orow = out + ((n * 1024 + l) * 16 + h) * 64;                      \
      _Pragma("unroll")                                                        \
      for (int r2 = 0; r2 < 4; ++r2) {                                         \
        float4 o;                                                              \
        o.x = (Oc0[4*r2+0] * s0e + row[r2*4+0] * s1e) * inv;                   \
        o.y = (Oc0[4*r2+1] * s0e + row[r2*4+1] * s1e) * inv;                   \
        o.z = (Oc0[4*r2+2] * s0e + row[r2*4+2] * s1e) * inv;                   \
        o.w = (Oc0[4*r2+3] * s0e + row[r2*4+3] * s1e) * inv;                   \
        *(float4*)(orow + r2 * 8 + h4) = o;                                    \
        o.x = (Oc1[4*r2+0] * s0e + row[16+r2*4+0] * s1e) * inv;                \
        o.y = (Oc1[4*r2+1] * s0e + row[16+r2*4+1] * s1e) * inv;                \
        o.z = (Oc1[4*r2+2] * s0e + row[16+r2*4+2] * s1e) * inv;                \
        o.w = (Oc1[4*r2+3] * s0e + row[16+r2*4+3] * s1e) * inv;                \
        *(float4*)(orow + 32 + r2 * 8 + h4) = o;                               \
      }                                                                        \
    }                                                                          \
    __syncthreads();                                                           \
  }

#define BF(x) __builtin_bit_cast(bf16x8, x)
#define MFMA(A, B, C) __builtin_amdgcn_mfma_f32_32x32x16_bf16(A, B, C, 0, 0, 0)
#define LDB(ARR, OFF) BF(*(const u32x4*)&ARR[g][(OFF)])

#define BODY(T, KR, KW, VR, VW, DO_PV, STG)                                    \
  {                                                                            \
    unsigned pwx = posB[((T) * 2) * 1024];                                     \
    unsigned pwy = posB[((T) * 2 + 1) * 1024];                                 \
    if (STG) {                                                                 \
      _Pragma("unroll")                                                        \
      for (int j = 0; j < 2; ++j) {                                            \
        gload16(kS + ((T) + 1) * 4096 + j * 512, &KW[g][kD + j * 512]);        \
        gload16(vS + ((T) + 1) * 64 + j * 8192, &VW[g][kD + j * 512]);         \
      }                                                                        \
    }                                                                          \
    f32x16 sv0 = {0,0,0,0,0,0,0,0,0,0,0,0,0,0,0,0};                            \
    f32x16 sv1 = {0,0,0,0,0,0,0,0,0,0,0,0,0,0,0,0};                            \
    __builtin_amdgcn_s_setprio(1);                                             \
    sv0 = MFMA(LDB(KR, rb + co0), qf[0], sv0);                                 \
    sv1 = MFMA(LDB(KR, rb + 2048 + co0), qf[0], sv1);                          \
    if (DO_PV) {                                                               \
      Oc0 = MFMA(LDB(VR, rb + co0), BF(pfA), Oc0);                             \
      Oc1 = MFMA(LDB(VR, rb + 2048 + co0), BF(pfA), Oc1);                      \
    }                                                                          \
    sv0 = MFMA(LDB(KR, rb + co1), qf[1], sv0);                                 \
    sv1 = MFMA(LDB(KR, rb + 2048 + co1), qf[1], sv1);                          \
    if (DO_PV) {                                                               \
      Oc0 = MFMA(LDB(VR, rb + co1), BF(pfB), Oc0);                             \
      Oc1 = MFMA(LDB(VR, rb + 2048 + co1), BF(pfB), Oc1);                      \
    }                                                                          \
    sv0 = MFMA(LDB(KR, rb + co2), qf[2], sv0);                                 \
    sv1 = MFMA(LDB(KR, rb + 2048 + co2), qf[2], sv1);                          \
    if (DO_PV) {                                                               \
      Oc0 = MFMA(LDB(VR, rb + co2), BF(pfC), Oc0);                             \
      Oc1 = MFMA(LDB(VR, rb + 2048 + co2), BF(pfC), Oc1);                      \
    }                                                                          \
    sv0 = MFMA(LDB(KR, rb + co3), qf[3], sv0);                                 \
    sv1 = MFMA(LDB(KR, rb + 2048 + co3), qf[3], sv1);                          \
    if (DO_PV) {                                                               \
      Oc0 = MFMA(LDB(VR, rb + co3), BF(pfD), Oc0);                             \
      Oc1 = MFMA(LDB(VR, rb + 2048 + co3), BF(pfD), Oc1);                      \
    }                                                                          \
    __builtin_amdgcn_s_setprio(0);                                             \
    if (hcm) {                                                                 \
      _Pragma("unroll")                                                        \
      for (int r2 = 0; r2 < 4; ++r2) {                                         \
        float4 mv0 = *(const float4*)(mrowB + (T) * 64 + r2 * 8 + h4);         \
        float4 kv0 = *(const float4*)(krowB + (T) * 64 + r2 * 8 + h4);         \
        float4 mv1 = *(const float4*)(mrowB + (T) * 64 + 32 + r2 * 8 + h4);    \
        float4 kv1 = *(const float4*)(krowB + (T) * 64 + 32 + r2 * 8 + h4);    \
        sv0[r2 * 4 + 0] += (mv0.x + kv0.x) * TEMP2;                            \
        sv0[r2 * 4 + 1] += (mv0.y + kv0.y) * TEMP2;                            \
        sv0[r2 * 4 + 2] += (mv0.z + kv0.z) * TEMP2;                            \
        sv0[r2 * 4 + 3] += (mv0.w + kv0.w) * TEMP2;                            \
        sv1[r2 * 4 + 0] += (mv1.x + kv1.x) * TEMP2;                            \
        sv1[r2 * 4 + 1] += (mv1.y + kv1.y) * TEMP2;                            \
        sv1[r2 * 4 + 2] += (mv1.z + kv1.z) * TEMP2;                            \
        sv1[r2 * 4 + 3] += (mv1.w + kv1.w) * TEMP2;                            \
      }                                                                        \
    }                                                                          \
    {                                                                          \
      unsigned pws0 = pwx >> h4;                                               \
      unsigned pws1 = pwy >> h4;                                               \
      _Pragma("unroll")                                                        \
      for (int r2 = 0; r2 < 4; ++r2)                                           \
        _Pragma("unroll")                                                      \
        for (int i = 0; i < 4; ++i) {                                          \
          float bit0 = (float)((pws0 >> (r2 * 8 + i)) & 1u);                   \
          float bit1 = (float)((pws1 >> (r2 * 8 + i)) & 1u);                   \
          sv0[r2 * 4 + i] = fmaf(bit0, delta2, sv0[r2 * 4 + i]);               \
          sv1[r2 * 4 + i] = fmaf(bit1, delta2, sv1[r2 * 4 + i]);               \
        }                                                                      \
    }                                                                          \
    {                                                                          \
      float m8[8];                                                             \
      _Pragma("unroll")                                                        \
      for (int i = 0; i < 8; ++i)                                              \
        m8[i] = fmaxf(fmaxf(sv0[2 * i], sv0[2 * i + 1]),                       \
                      fmaxf(sv1[2 * i], sv1[2 * i + 1]));                      \
      float m4a = fmaxf(m8[0], m8[1]), m4b = fmaxf(m8[2], m8[3]);              \
      float m4c = fmaxf(m8[4], m8[5]), m4d = fmaxf(m8[6], m8[7]);              \
      float tmax = fmaxf(fmaxf(m4a, m4b), fmaxf(m4c, m4d));                    \
      tmax = fmaxf(tmax, __shfl_xor(tmax, 32));                                \
      if (!__all(tmax <= mrun + 4.0f)) {                                       \
        float mnew = fmaxf(mrun, tmax);                                        \
        float sc = __builtin_amdgcn_exp2f(mrun - mnew);                        \
        lrun *= sc;                                                            \
        Oc0 *= sc; Oc1 *= sc;                                                  \
        mrun = mnew;                                                           \
      }                                                                        \
      float s8[8];                                                             \
      _Pragma("unroll")                                                        \
      for (int i = 0; i < 8; ++i) {                                            \
        float p0 = __builtin_amdgcn_exp2f(sv0[2 * i] - mrun);                  \
        float p1 = __builtin_amdgcn_exp2f(sv0[2 * i + 1] - mrun);              \
        float p2 = __builtin_amdgcn_exp2f(sv1[2 * i] - mrun);                  \
        float p3 = __builtin_amdgcn_exp2f(sv1[2 * i + 1] - mrun);              \
        sv0[2 * i] = p0; sv0[2 * i + 1] = p1;                                  \
        sv1[2 * i] = p2; sv1[2 * i + 1] = p3;                                  \
        s8[i] = (p0 + p1) + (p2 + p3);                                         \
      }                                                                        \
      float s4a = s8[0] + s8[1], s4b = s8[2] + s8[3];                          \
      float s4c = s8[4] + s8[5], s4d = s8[6] + s8[7];                          \
      lrun += (s4a + s4b) + (s4c + s4d);                                       \
    }                                                                          \
    {                                                                          \
      unsigned a0 = cvtpk(sv0[0], sv0[1]),   a1 = cvtpk(sv0[2], sv0[3]);       \
      unsigned a2 = cvtpk(sv0[4], sv0[5]),   a3 = cvtpk(sv0[6], sv0[7]);       \
      plswap(a0, a2); plswap(a1, a3);                                          \
      pfA[0] = a0; pfA[1] = a1; pfA[2] = a2; pfA[3] = a3;                      \
      unsigned b0_ = cvtpk(sv0[8], sv0[9]),   b1_ = cvtpk(sv0[10], sv0[11]);   \
      unsigned b2_ = cvtpk(sv0[12], sv0[13]), b3_ = cvtpk(sv0[14], sv0[15]);   \
      plswap(b0_, b2_); plswap(b1_, b3_);                                      \
      pfB[0] = b0_; pfB[1] = b1_; pfB[2] = b2_; pfB[3] = b3_;                  \
      unsigned c0 = cvtpk(sv1[0], sv1[1]),   c1 = cvtpk(sv1[2], sv1[3]);       \
      unsigned c2 = cvtpk(sv1[4], sv1[5]),   c3 = cvtpk(sv1[6], sv1[7]);       \
      plswap(c0, c2); plswap(c1, c3);                                          \
      pfC[0] = c0; pfC[1] = c1; pfC[2] = c2; pfC[3] = c3;                      \
      unsigned d0 = cvtpk(sv1[8], sv1[9]),   d1 = cvtpk(sv1[10], sv1[11]);     \
      unsigned d2 = cvtpk(sv1[12], sv1[13]), d3 = cvtpk(sv1[14], sv1[15]);     \
      plswap(d0, d2); plswap(d1, d3);                                          \
      pfD[0] = d0; pfD[1] = d1; pfD[2] = d2; pfD[3] = d3;                      \
    }                                                                          \
    if (STG) __syncthreads();                                                  \
  }

// ------------------- fallback attention kernel (R12) -----------------------
__global__ __launch_bounds__(512) void k_attn(
    const float* __restrict__ Q, const float* __restrict__ mask,
    const float* __restrict__ klm, const float* __restrict__ ptab,
    const unsigned int* __restrict__ pospk,
    const unsigned short* __restrict__ Kp, const unsigned short* __restrict__ Vt,
    const int* __restrict__ cmf,
    float* __restrict__ out) {
  __shared__ __align__(16) unsigned short KBA[2][4096];
  __shared__ __align__(16) unsigned short KBB[2][4096];
  __shared__ __align__(16) unsigned short VBA[2][4096];
  __shared__ __align__(16) unsigned short VBB[2][4096];
  __shared__ __align__(16) unsigned short VBC[2][4096];
  int bid = blockIdx.x;
  int tid = threadIdx.x;
  ATTN_MAIN(cmf ? *cmf : 1)
}

// ------------------------- fused cooperative kernel -------------------------
// grid 512 x 512 thr (2 blocks/CU). Phase 1: balanced prepass. grid.sync.
// Phase 2: flag reduce + R12 main loop.
__global__ __launch_bounds__(512) void k_fused(
    const float* __restrict__ Q, const float* __restrict__ K,
    const float* __restrict__ V, const float* __restrict__ mask,
    const float* __restrict__ klm, const float* __restrict__ ptab,
    const int* __restrict__ pos,
    unsigned int* __restrict__ pospk, unsigned short* __restrict__ Kp,
    unsigned short* __restrict__ Vt, int* __restrict__ flags,
    float* __restrict__ out) {
  __shared__ __align__(16) unsigned short KBA[2][4096];
  __shared__ __align__(16) unsigned short KBB[2][4096];
  __shared__ __align__(16) unsigned short VBA[2][4096];
  __shared__ __align__(16) unsigned short VBB[2][4096];
  __shared__ __align__(16) unsigned short VBC[2][4096];

  int bid = blockIdx.x;
  int tid = threadIdx.x;
  int gt = bid * 512 + tid;

  // ---- P1a: K relayout (4 threads per (n,s,h) row) ----
  {
    int row = gt >> 2, q = gt & 3;
    int s = (row >> 4) & 1023;
    const float* src = K + row * 64 + q * 16;
    unsigned short rv[16];
#pragma unroll
    for (int j = 0; j < 4; ++j) {
      float4 v = *(const float4*)(src + j * 4);
      rv[j*4+0] = f2bf(v.x); rv[j*4+1] = f2bf(v.y);
      rv[j*4+2] = f2bf(v.z); rv[j*4+3] = f2bf(v.w);
    }
    int n = row >> 14, h = row & 15;
    unsigned short* dst = Kp + ((n * 16 + h) * 1024 + s) * 64;
#pragma unroll
    for (int c = 0; c < 2; ++c) {
      int bb = q * 2 + c;
      int pb = bb ^ (s & 7);
      *(u32x4*)(dst + pb * 8) = *(const u32x4*)(&rv[c * 8]);
    }
  }
  // ---- P1b: mask + klm nonzero scan (result kept in register) ----
  float acc = 0.f;
  {
    const float* m = mask + gt * 4;
    float4 v = *(const float4*)m;
    acc += __builtin_fabsf(v.x) + __builtin_fabsf(v.y) +
           __builtin_fabsf(v.z) + __builtin_fabsf(v.w);
    if (gt < 1024) {
      float4 kv = *(const float4*)(klm + gt * 4);
      acc += __builtin_fabsf(kv.x) + __builtin_fabsf(kv.y) +
             __builtin_fabsf(kv.z) + __builtin_fabsf(kv.w);
    }
  }
  // ---- P1c: pos pack (one l-row per wave, 16 strided ballots) ----
  {
    int r = bid * 8 + (tid >> 6);        // [0,4096) = (n,l)
    int n = r >> 10, l = r & 1023;
    int lane = tid & 63;
    const int* prow = pos + r * 1024 + lane;
#pragma unroll
    for (int j = 0; j < 16; ++j) {
      unsigned long long m = __ballot(prow[j * 64] & 1);
      if (lane == 0) pospk[(n * 32 + 2 * j) * 1024 + l] = (unsigned int)m;
      else if (lane == 32) pospk[(n * 32 + 2 * j + 1) * 1024 + l] = (unsigned int)(m >> 32);
    }
  }
  // ---- P1d: V transpose, 2 tiles per block, half-tiles through KBA pool ----
  {
    float* ld = (float*)KBA;             // [32][65] floats = 8320B <= 16KB
#pragma unroll
    for (int tt = 0; tt < 2; ++tt) {
      int vt = bid * 2 + tt;             // [0,1024)
      int t16 = vt & 15, h = (vt >> 4) & 15, n = vt >> 8;
#pragma unroll
      for (int hf = 0; hf < 2; ++hf) {
        __syncthreads();
        {
          int sl = (tid >> 4), dq = (tid & 15) * 4;
          int s_glob = t16 * 64 + hf * 32 + sl;
          float4 v = *(const float4*)(V + ((n * 1024 + s_glob) * 16 + h) * 64 + dq);
          ld[sl * 65 + dq + 0] = v.x; ld[sl * 65 + dq + 1] = v.y;
          ld[sl * 65 + dq + 2] = v.z; ld[sl * 65 + dq + 3] = v.w;
        }
        __syncthreads();
        if (tid < 256) {
          int d = tid >> 2, bq = (tid & 3) + hf * 4;
          int sl0 = (tid & 3) * 8;
          unsigned short vals[8];
#pragma unroll
          for (int k = 0; k < 8; ++k) vals[k] = f2bf(ld[(sl0 + k) * 65 + d]);
          int pb = bq ^ (d & 7);
          unsigned short* dst = Vt + ((n * 16 + h) * 64 + d) * 1024 + t16 * 64;
          *(u32x4*)(dst + pb * 8) = *(const u32x4*)(&vals[0]);
        }
      }
    }
  }
  // ---- per-block flag (plain store, no init needed) ----
  {
    __syncthreads();
    unsigned long long bal = __ballot(acc != 0.f);
    int* wf = (int*)KBB;
    if ((tid & 63) == 0) wf[tid >> 6] = (bal != 0ull) ? 1 : 0;
    __syncthreads();
    if (tid == 0) {
      int v = 0;
#pragma unroll
      for (int i = 0; i < 8; ++i) v |= wf[i];
      flags[bid] = v;
    }
  }
  __threadfence();
  cg::this_grid().sync();

  // ---- P2: global flag reduce ----
  int hcmg;
  {
    int v = flags[tid];
    unsigned long long bal = __ballot(v != 0);
    int* wf = (int*)KBB;
    if ((tid & 63) == 0) wf[tid >> 6] = (bal != 0ull) ? 1 : 0;
    __syncthreads();
    int r = 0;
#pragma unroll
    for (int i = 0; i < 8; ++i) r |= wf[i];
    hcmg = r;
    __syncthreads();
  }

  // ---- P3: main attention loop (identical to R12) ----
  ATTN_MAIN(hcmg)
}

extern "C" void kernel_launch(void* const* d_in, const int* in_sizes, int n_in,
                              void* d_out, int out_size, void* d_ws, size_t ws_size,
                              hipStream_t stream) {
  const float* Q    = (const float*)d_in[0];
  const float* K    = (const float*)d_in[1];
  const float* V    = (const float*)d_in[2];
  const float* mask = (const float*)d_in[3];
  const float* klm  = (const float*)d_in[4];
  const float* ptab = (const float*)d_in[5];
  const int*   pos  = (const int*)d_in[6];
  float* out = (float*)d_out;

  char* ws = (char*)d_ws;
  // layout: pospk 512K | Kp 8M | Vt 8M | flags 2KB
  unsigned int*   pospk = (unsigned int*)ws;
  unsigned short* Kp    = (unsigned short*)(ws + (1 << 19));
  unsigned short* Vt    = (unsigned short*)(ws + (1 << 19) + (8 << 20));
  int*            flags = (int*)(ws + (1 << 19) + (16 << 20));
  const size_t need = (size_t)(1 << 19) + (size_t)(16 << 20) + 2048;
  const bool ws_ok = ws_size >= need;

  bool coop_done = false;
  if (ws_ok) {
    int maxb = 0;
    hipError_t qe = hipOccupancyMaxActiveBlocksPerMultiprocessor(
        &maxb, (const void*)k_fused, 512, 0);
    if (qe == hipSuccess && maxb >= 2) {
      void* args[] = {(void*)&Q, (void*)&K, (void*)&V, (void*)&mask,
                      (void*)&klm, (void*)&ptab, (void*)&pos, (void*)&pospk,
                      (void*)&Kp, (void*)&Vt, (void*)&flags, (void*)&out};
      hipError_t le = hipLaunchCooperativeKernel((const void*)k_fused,
                                                 dim3(512), dim3(512), args,
                                                 0, stream);
      if (le == hipSuccess) coop_done = true;
      else (void)hipGetLastError();
    } else {
      (void)hipGetLastError();
    }
  }
  if (!coop_done) {
    int* cmf = ws_ok ? flags : nullptr;
    if (ws_ok) hipMemsetAsync(cmf, 0, 4, stream);
    k_prep<<<17921, 256, 0, stream>>>(pos, pospk, K, Kp, V, Vt, mask, klm, cmf);
    k_attn<<<512, 512, 0, stream>>>(Q, mask, klm, ptab, pospk, Kp, Vt, cmf, out);
  }
}

// Round 15
// 55.778 us; speedup vs baseline: 4.4623x; 1.1540x over previous
//
#include <hip/hip_runtime.h>

// FullAttention_Spatial: N=4, L=S=1024, H=16, E=D=64, NUM_POS=2, fp32 in/out.
//
// score = temp*(QK + attn_mask[l,s] + klm[n,s]) + pos_table[pos[n,l,s]][h]
// pos in {0,1} => bias = T0[h] + bit*(T1[h]-T0[h]); T0 cancels in softmax.
// Log2-domain softmax; Q pre-scaled by temp2 = temp*log2e.
//
// R14 = R12 k_attn (proven 43.4us) + BALANCED prepass k_prep2 (512x512):
// every thread does the same work mix (K-relayout quarter-row + mask scan +
// per-wave pos-row pack + 2 V-transpose tiles/block via 8.3KB LDS pool).
// Per-block flag stores (no memset, no atomics); k_attn OR-reduces the 512
// flags at entry. Replaces the imbalanced 17921-block prepass + memset
// (R13's cooperative fusion was rejected by the runtime; fallback ran).
//
// MFMA 32x32x16: C col=lane&31, row=(reg&3)+8*(reg>>2)+4*(lane>>5);
// A row=lane&31, k=8*(lane>>5)+j. B col=lane&31, k=8*(lane>>5)+j.

typedef __attribute__((ext_vector_type(8))) __bf16 bf16x8;
typedef __attribute__((ext_vector_type(16))) float f32x16;
typedef __attribute__((ext_vector_type(4))) unsigned int u32x4;

#define TEMP2 (0.125f * 1.4426950408889634f)
#define LG2E 1.4426950408889634f

static __device__ __forceinline__ unsigned short f2bf(float x) {
  unsigned int u = __builtin_bit_cast(unsigned int, x);
  u += 0x7FFFu + ((u >> 16) & 1u);
  return (unsigned short)(u >> 16);
}
static __device__ __forceinline__ unsigned int cvtpk(float lo, float hi) {
  unsigned int r;
  asm("v_cvt_pk_bf16_f32 %0, %1, %2" : "=v"(r) : "v"(lo), "v"(hi));
  return r;
}
static __device__ __forceinline__ void gload16(const void* g, void* l) {
  __builtin_amdgcn_global_load_lds((const __attribute__((address_space(1))) void*)g,
                                   (__attribute__((address_space(3))) void*)l, 16, 0, 0);
}
// After: a = {a.lo32, b.lo32}, b = {a.hi32, b.hi32}
static __device__ __forceinline__ void plswap(unsigned int& a, unsigned int& b) {
  asm("v_permlane32_swap_b32 %0, %1" : "+v"(a), "+v"(b));
}

// ---------------- balanced prepass: 512 blocks x 512 threads ----------------
__global__ __launch_bounds__(512) void k_prep2(
    const int* __restrict__ pos, unsigned int* __restrict__ pospk,
    const float* __restrict__ K, unsigned short* __restrict__ Kp,
    const float* __restrict__ V, unsigned short* __restrict__ Vt,
    const float* __restrict__ mask, const float* __restrict__ klm,
    int* __restrict__ flags) {
  __shared__ float ld[32][65];   // 8.3 KB transpose pool
  __shared__ int wf[8];
  int bid = blockIdx.x, tid = threadIdx.x;
  int gt = bid * 512 + tid;

  // ---- K relayout: 4 threads per (n,s,h) row ----
  {
    int row = gt >> 2, q = gt & 3;
    int s = (row >> 4) & 1023;
    const float* src = K + row * 64 + q * 16;
    unsigned short rv[16];
#pragma unroll
    for (int j = 0; j < 4; ++j) {
      float4 v = *(const float4*)(src + j * 4);
      rv[j*4+0] = f2bf(v.x); rv[j*4+1] = f2bf(v.y);
      rv[j*4+2] = f2bf(v.z); rv[j*4+3] = f2bf(v.w);
    }
    int n = row >> 14, h = row & 15;
    unsigned short* dst = Kp + ((n * 16 + h) * 1024 + s) * 64;
#pragma unroll
    for (int c = 0; c < 2; ++c) {
      int bb = q * 2 + c;
      int pb = bb ^ (s & 7);
      *(u32x4*)(dst + pb * 8) = *(const u32x4*)(&rv[c * 8]);
    }
  }
  // ---- mask + klm nonzero scan ----
  float acc = 0.f;
  {
    float4 v = *(const float4*)(mask + gt * 4);
    acc += __builtin_fabsf(v.x) + __builtin_fabsf(v.y) +
           __builtin_fabsf(v.z) + __builtin_fabsf(v.w);
    if (gt < 1024) {
      float4 kv = *(const float4*)(klm + gt * 4);
      acc += __builtin_fabsf(kv.x) + __builtin_fabsf(kv.y) +
             __builtin_fabsf(kv.z) + __builtin_fabsf(kv.w);
    }
  }
  // ---- pos pack: one (n,l) row per wave, transposed out ----
  {
    int r = bid * 8 + (tid >> 6);        // [0,4096) = (n,l)
    int n = r >> 10, l = r & 1023;
    int lane = tid & 63;
    const int* prow = pos + r * 1024 + lane;
#pragma unroll
    for (int j = 0; j < 16; ++j) {
      unsigned long long m = __ballot(prow[j * 64] & 1);
      if (lane == 0) pospk[(n * 32 + 2 * j) * 1024 + l] = (unsigned int)m;
      else if (lane == 32) pospk[(n * 32 + 2 * j + 1) * 1024 + l] = (unsigned int)(m >> 32);
    }
  }
  // ---- V transpose: 2 tiles per block, half-tiles through LDS ----
#pragma unroll
  for (int tt = 0; tt < 2; ++tt) {
    int vt = bid * 2 + tt;               // [0,1024)
    int t16 = vt & 15, h = (vt >> 4) & 15, n = vt >> 8;
#pragma unroll
    for (int hf = 0; hf < 2; ++hf) {
      __syncthreads();
      {
        int sl = tid >> 4, dq = (tid & 15) * 4;
        int s_glob = t16 * 64 + hf * 32 + sl;
        float4 v = *(const float4*)(V + ((n * 1024 + s_glob) * 16 + h) * 64 + dq);
        ld[sl][dq + 0] = v.x; ld[sl][dq + 1] = v.y;
        ld[sl][dq + 2] = v.z; ld[sl][dq + 3] = v.w;
      }
      __syncthreads();
      if (tid < 256) {
        int d = tid >> 2, bq = (tid & 3) + hf * 4;
        int sl0 = (tid & 3) * 8;
        unsigned short vals[8];
#pragma unroll
        for (int k = 0; k < 8; ++k) vals[k] = f2bf(ld[sl0 + k][d]);
        int pb = bq ^ (d & 7);
        unsigned short* dst = Vt + ((n * 16 + h) * 64 + d) * 1024 + t16 * 64;
        *(u32x4*)(dst + pb * 8) = *(const u32x4*)(&vals[0]);
      }
    }
  }
  // ---- per-block flag (plain store, no init needed) ----
  __syncthreads();
  {
    unsigned long long bal = __ballot(acc != 0.f);
    if ((tid & 63) == 0) wf[tid >> 6] = (bal != 0ull) ? 1 : 0;
    __syncthreads();
    if (tid == 0 && flags) {
      int v = 0;
#pragma unroll
      for (int i = 0; i < 8; ++i) v |= wf[i];
      flags[bid] = v;
    }
  }
}

// ---------------- main flash-attention kernel (R12 + flag reduce) ----------
// grid 512 = lblk*64 + n*16 + h ; 512 thr = 2 s-groups x 4 waves x 64.
__global__ __launch_bounds__(512) void k_attn(
    const float* __restrict__ Q, const float* __restrict__ mask,
    const float* __restrict__ klm, const float* __restrict__ ptab,
    const unsigned int* __restrict__ pospk,
    const unsigned short* __restrict__ Kp, const unsigned short* __restrict__ Vt,
    const int* __restrict__ flags,
    float* __restrict__ out) {
  __shared__ __align__(16) unsigned short KBA[2][4096];
  __shared__ __align__(16) unsigned short KBB[2][4096];
  __shared__ __align__(16) unsigned short VBA[2][4096];
  __shared__ __align__(16) unsigned short VBB[2][4096];
  __shared__ __align__(16) unsigned short VBC[2][4096];

  int bid = blockIdx.x;
  int tid = threadIdx.x;

  // ---- reduce the 512 per-block mask flags (blockDim == 512) ----
  int hcmg = 1;
  if (flags) {
    int v = flags[tid];
    unsigned long long bal = __ballot(v != 0);
    int* wf = (int*)KBB;
    if ((tid & 63) == 0) wf[tid >> 6] = (bal != 0ull) ? 1 : 0;
    __syncthreads();
    int r = 0;
#pragma unroll
    for (int i = 0; i < 8; ++i) r |= wf[i];
    hcmg = r;
    __syncthreads();
  }

  int nh = bid & 63;
  int n = nh >> 4, h = nh & 15, lblk = bid >> 6;
  int w8 = tid >> 6, lane = tid & 63;
  int g = w8 >> 2, w4 = w8 & 3;
  int l31 = lane & 31, h5 = lane >> 5;
  int l = lblk * 128 + w4 * 32 + l31;  // this lane's q-row (global)
  const int hcm = hcmg;

  // Q fragments (B of swapped QK^T), pre-scaled by temp2
  const float* qrow = Q + ((n * 1024 + l) * 16 + h) * 64;
  bf16x8 qf[4];
#pragma unroll
  for (int ke = 0; ke < 4; ++ke) {
    float4 a = *(const float4*)(qrow + ke * 16 + h5 * 8);
    float4 bq = *(const float4*)(qrow + ke * 16 + h5 * 8 + 4);
    u32x4 pk;
    pk[0] = cvtpk(a.x * TEMP2, a.y * TEMP2);
    pk[1] = cvtpk(a.z * TEMP2, a.w * TEMP2);
    pk[2] = cvtpk(bq.x * TEMP2, bq.y * TEMP2);
    pk[3] = cvtpk(bq.z * TEMP2, bq.w * TEMP2);
    qf[ke] = __builtin_bit_cast(bf16x8, pk);
  }
  const float delta2 = (ptab[16 + h] - ptab[h]) * LG2E;

  float mrun = -1e30f, lrun = 0.f;
  f32x16 Oc0 = {0,0,0,0,0,0,0,0,0,0,0,0,0,0,0,0};
  f32x16 Oc1 = {0,0,0,0,0,0,0,0,0,0,0,0,0,0,0,0};
  u32x4 pfA = {0,0,0,0}, pfB = {0,0,0,0}, pfC = {0,0,0,0}, pfD = {0,0,0,0};

  const unsigned short* KpB = Kp + nh * 65536;
  const unsigned short* VtB = Vt + nh * 65536;
  const float* mrowB = mask + l * 1024 + g * 512;
  const float* krowB = klm + n * 1024 + g * 512;
  const unsigned int* posB = pospk + (n * 32 + g * 16) * 1024 + l;
  const int h4 = h5 * 4;

  const int x7 = l31 & 7;
  const int co0 = ((0 + h5) ^ x7) * 8;
  const int co1 = ((2 + h5) ^ x7) * 8;
  const int co2 = ((4 + h5) ^ x7) * 8;
  const int co3 = ((6 + h5) ^ x7) * 8;
  const int rb = l31 * 64;

  const unsigned short* kS = KpB + g * 32768 + w4 * 1024 + lane * 8;
  const unsigned short* vS = VtB + (w4 * 16 + (lane >> 3)) * 1024 + g * 512 + (lane & 7) * 8;
  const int kD = w4 * 1024 + lane * 8;

#define BF(x) __builtin_bit_cast(bf16x8, x)
#define MFMA(A, B, C) __builtin_amdgcn_mfma_f32_32x32x16_bf16(A, B, C, 0, 0, 0)
#define LDB(ARR, OFF) BF(*(const u32x4*)&ARR[g][(OFF)])

  // ---- prologue: stage tile (g*8): K->KBA, V->VBA ----
#pragma unroll
  for (int j = 0; j < 2; ++j) {
    gload16(kS + j * 512, &KBA[g][kD + j * 512]);
    gload16(vS + j * 8192, &VBA[g][kD + j * 512]);
  }
  __syncthreads();

#define BODY(T, KR, KW, VR, VW, DO_PV, STG)                                    \
  {                                                                            \
    unsigned pwx = posB[((T) * 2) * 1024];                                     \
    unsigned pwy = posB[((T) * 2 + 1) * 1024];                                 \
    if (STG) {                                                                 \
      _Pragma("unroll")                                                        \
      for (int j = 0; j < 2; ++j) {                                            \
        gload16(kS + ((T) + 1) * 4096 + j * 512, &KW[g][kD + j * 512]);        \
        gload16(vS + ((T) + 1) * 64 + j * 8192, &VW[g][kD + j * 512]);         \
      }                                                                        \
    }                                                                          \
    f32x16 sv0 = {0,0,0,0,0,0,0,0,0,0,0,0,0,0,0,0};                            \
    f32x16 sv1 = {0,0,0,0,0,0,0,0,0,0,0,0,0,0,0,0};                            \
    __builtin_amdgcn_s_setprio(1);                                             \
    sv0 = MFMA(LDB(KR, rb + co0), qf[0], sv0);                                 \
    sv1 = MFMA(LDB(KR, rb + 2048 + co0), qf[0], sv1);                          \
    if (DO_PV) {                                                               \
      Oc0 = MFMA(LDB(VR, rb + co0), BF(pfA), Oc0);                             \
      Oc1 = MFMA(LDB(VR, rb + 2048 + co0), BF(pfA), Oc1);                      \
    }                                                                          \
    sv0 = MFMA(LDB(KR, rb + co1), qf[1], sv0);                                 \
    sv1 = MFMA(LDB(KR, rb + 2048 + co1), qf[1], sv1);                          \
    if (DO_PV) {                                                               \
      Oc0 = MFMA(LDB(VR, rb + co1), BF(pfB), Oc0);                             \
      Oc1 = MFMA(LDB(VR, rb + 2048 + co1), BF(pfB), Oc1);                      \
    }                                                                          \
    sv0 = MFMA(LDB(KR, rb + co2), qf[2], sv0);                                 \
    sv1 = MFMA(LDB(KR, rb + 2048 + co2), qf[2], sv1);                          \
    if (DO_PV) {                                                               \
      Oc0 = MFMA(LDB(VR, rb + co2), BF(pfC), Oc0);                             \
      Oc1 = MFMA(LDB(VR, rb + 2048 + co2), BF(pfC), Oc1);                      \
    }                                                                          \
    sv0 = MFMA(LDB(KR, rb + co3), qf[3], sv0);                                 \
    sv1 = MFMA(LDB(KR, rb + 2048 + co3), qf[3], sv1);                          \
    if (DO_PV) {                                                               \
      Oc0 = MFMA(LDB(VR, rb + co3), BF(pfD), Oc0);                             \
      Oc1 = MFMA(LDB(VR, rb + 2048 + co3), BF(pfD), Oc1);                      \
    }                                                                          \
    __builtin_amdgcn_s_setprio(0);                                             \
    if (hcm) {                                                                 \
      _Pragma("unroll")                                                        \
      for (int r2 = 0; r2 < 4; ++r2) {                                         \
        float4 mv0 = *(const float4*)(mrowB + (T) * 64 + r2 * 8 + h4);         \
        float4 kv0 = *(const float4*)(krowB + (T) * 64 + r2 * 8 + h4);         \
        float4 mv1 = *(const float4*)(mrowB + (T) * 64 + 32 + r2 * 8 + h4);    \
        float4 kv1 = *(const float4*)(krowB + (T) * 64 + 32 + r2 * 8 + h4);    \
        sv0[r2 * 4 + 0] += (mv0.x + kv0.x) * TEMP2;                            \
        sv0[r2 * 4 + 1] += (mv0.y + kv0.y) * TEMP2;                            \
        sv0[r2 * 4 + 2] += (mv0.z + kv0.z) * TEMP2;                            \
        sv0[r2 * 4 + 3] += (mv0.w + kv0.w) * TEMP2;                            \
        sv1[r2 * 4 + 0] += (mv1.x + kv1.x) * TEMP2;                            \
        sv1[r2 * 4 + 1] += (mv1.y + kv1.y) * TEMP2;                            \
        sv1[r2 * 4 + 2] += (mv1.z + kv1.z) * TEMP2;                            \
        sv1[r2 * 4 + 3] += (mv1.w + kv1.w) * TEMP2;                            \
      }                                                                        \
    }                                                                          \
    {                                                                          \
      unsigned pws0 = pwx >> h4;                                               \
      unsigned pws1 = pwy >> h4;                                               \
      _Pragma("unroll")                                                        \
      for (int r2 = 0; r2 < 4; ++r2)                                           \
        _Pragma("unroll")                                                      \
        for (int i = 0; i < 4; ++i) {                                          \
          float bit0 = (float)((pws0 >> (r2 * 8 + i)) & 1u);                   \
          float bit1 = (float)((pws1 >> (r2 * 8 + i)) & 1u);                   \
          sv0[r2 * 4 + i] = fmaf(bit0, delta2, sv0[r2 * 4 + i]);               \
          sv1[r2 * 4 + i] = fmaf(bit1, delta2, sv1[r2 * 4 + i]);               \
        }                                                                      \
    }                                                                          \
    {                                                                          \
      float m8[8];                                                             \
      _Pragma("unroll")                                                        \
      for (int i = 0; i < 8; ++i)                                              \
        m8[i] = fmaxf(fmaxf(sv0[2 * i], sv0[2 * i + 1]),                       \
                      fmaxf(sv1[2 * i], sv1[2 * i + 1]));                      \
      float m4a = fmaxf(m8[0], m8[1]), m4b = fmaxf(m8[2], m8[3]);              \
      float m4c = fmaxf(m8[4], m8[5]), m4d = fmaxf(m8[6], m8[7]);              \
      float tmax = fmaxf(fmaxf(m4a, m4b), fmaxf(m4c, m4d));                    \
      tmax = fmaxf(tmax, __shfl_xor(tmax, 32));                                \
      if (!__all(tmax <= mrun + 4.0f)) {                                       \
        float mnew = fmaxf(mrun, tmax);                                        \
        float sc = __builtin_amdgcn_exp2f(mrun - mnew);                        \
        lrun *= sc;                                                            \
        Oc0 *= sc; Oc1 *= sc;                                                  \
        mrun = mnew;                                                           \
      }                                                                        \
      float s8[8];                                                             \
      _Pragma("unroll")                                                        \
      for (int i = 0; i < 8; ++i) {                                            \
        float p0 = __builtin_amdgcn_exp2f(sv0[2 * i] - mrun);                  \
        float p1 = __builtin_amdgcn_exp2f(sv0[2 * i + 1] - mrun);              \
        float p2 = __builtin_amdgcn_exp2f(sv1[2 * i] - mrun);                  \
        float p3 = __builtin_amdgcn_exp2f(sv1[2 * i + 1] - mrun);              \
        sv0[2 * i] = p0; sv0[2 * i + 1] = p1;                                  \
        sv1[2 * i] = p2; sv1[2 * i + 1] = p3;                                  \
        s8[i] = (p0 + p1) + (p2 + p3);                                         \
      }                                                                        \
      float s4a = s8[0] + s8[1], s4b = s8[2] + s8[3];                          \
      float s4c = s8[4] + s8[5], s4d = s8[6] + s8[7];                          \
      lrun += (s4a + s4b) + (s4c + s4d);                                       \
    }                                                                          \
    {                                                                          \
      unsigned a0 = cvtpk(sv0[0], sv0[1]),   a1 = cvtpk(sv0[2], sv0[3]);       \
      unsigned a2 = cvtpk(sv0[4], sv0[5]),   a3 = cvtpk(sv0[6], sv0[7]);       \
      plswap(a0, a2); plswap(a1, a3);                                          \
      pfA[0] = a0; pfA[1] = a1; pfA[2] = a2; pfA[3] = a3;                      \
      unsigned b0_ = cvtpk(sv0[8], sv0[9]),   b1_ = cvtpk(sv0[10], sv0[11]);   \
      unsigned b2_ = cvtpk(sv0[12], sv0[13]), b3_ = cvtpk(sv0[14], sv0[15]);   \
      plswap(b0_, b2_); plswap(b1_, b3_);                                      \
      pfB[0] = b0_; pfB[1] = b1_; pfB[2] = b2_; pfB[3] = b3_;                  \
      unsigned c0 = cvtpk(sv1[0], sv1[1]),   c1 = cvtpk(sv1[2], sv1[3]);       \
      unsigned c2 = cvtpk(sv1[4], sv1[5]),   c3 = cvtpk(sv1[6], sv1[7]);       \
      plswap(c0, c2); plswap(c1, c3);                                          \
      pfC[0] = c0; pfC[1] = c1; pfC[2] = c2; pfC[3] = c3;                      \
      unsigned d0 = cvtpk(sv1[8], sv1[9]),   d1 = cvtpk(sv1[10], sv1[11]);     \
      unsigned d2 = cvtpk(sv1[12], sv1[13]), d3 = cvtpk(sv1[14], sv1[15]);     \
      plswap(d0, d2); plswap(d1, d3);                                          \
      pfD[0] = d0; pfD[1] = d1; pfD[2] = d2; pfD[3] = d3;                      \
    }                                                                          \
    if (STG) __syncthreads();                                                  \
  }

  // V(t) lives in buf t%3 (A,B,C); K(t) in buf t&1 (A,B).
  //     T   KR   KW   VR   VW  PV STG
  BODY( 0, KBA, KBB, VBA, VBB, 0, 1)
  BODY( 1, KBB, KBA, VBA, VBC, 1, 1)
  BODY( 2, KBA, KBB, VBB, VBA, 1, 1)
  BODY( 3, KBB, KBA, VBC, VBB, 1, 1)
  BODY( 4, KBA, KBB, VBA, VBC, 1, 1)
  BODY( 5, KBB, KBA, VBB, VBA, 1, 1)
  BODY( 6, KBA, KBB, VBC, VBB, 1, 1)
  BODY( 7, KBB, KBB, VBA, VBB, 1, 0)
#undef BODY

  // ---- epilogue PV(7): V(7) in VBB (staged body 6) ----
  __builtin_amdgcn_s_setprio(1);
  Oc0 = MFMA(LDB(VBB, rb + co0), BF(pfA), Oc0);
  Oc1 = MFMA(LDB(VBB, rb + 2048 + co0), BF(pfA), Oc1);
  Oc0 = MFMA(LDB(VBB, rb + co1), BF(pfB), Oc0);
  Oc1 = MFMA(LDB(VBB, rb + 2048 + co1), BF(pfB), Oc1);
  Oc0 = MFMA(LDB(VBB, rb + co2), BF(pfC), Oc0);
  Oc1 = MFMA(LDB(VBB, rb + 2048 + co2), BF(pfC), Oc1);
  Oc0 = MFMA(LDB(VBB, rb + co3), BF(pfD), Oc0);
  Oc1 = MFMA(LDB(VBB, rb + 2048 + co3), BF(pfD), Oc1);
  __builtin_amdgcn_s_setprio(0);
#undef MFMA
#undef BF
#undef LDB

  // ---- merge the two s-half groups (exact), 2 rounds via VBA/VBB ----
  float lw = lrun + __shfl_xor(lrun, 32);
  __syncthreads();
#pragma unroll
  for (int r = 0; r < 2; ++r) {
    if (g == 1 && (w4 >> 1) == r) {
      float* row = ((w4 & 1) ? (float*)VBB : (float*)VBA) + lane * 36;
#pragma unroll
      for (int r2 = 0; r2 < 4; ++r2) {
        *(float4*)(row + r2 * 4) =
            make_float4(Oc0[4*r2+0], Oc0[4*r2+1], Oc0[4*r2+2], Oc0[4*r2+3]);
        *(float4*)(row + 16 + r2 * 4) =
            make_float4(Oc1[4*r2+0], Oc1[4*r2+1], Oc1[4*r2+2], Oc1[4*r2+3]);
      }
      row[32] = mrun;
      row[33] = lw;
    }
    __syncthreads();
    if (g == 0 && (w4 >> 1) == r) {
      const float* row = ((w4 & 1) ? (float*)VBB : (float*)VBA) + lane * 36;
      float m1 = row[32], l1 = row[33];
      float mm = fmaxf(mrun, m1);
      float s0e = __builtin_amdgcn_exp2f(mrun - mm);
      float s1e = __builtin_amdgcn_exp2f(m1 - mm);
      float ltot = lw * s0e + l1 * s1e;
      float inv = 1.0f / ltot;
      float* orow = out + ((n * 1024 + l) * 16 + h) * 64;
#pragma unroll
      for (int r2 = 0; r2 < 4; ++r2) {
        float4 o;
        o.x = (Oc0[4*r2+0] * s0e + row[r2*4+0] * s1e) * inv;
        o.y = (Oc0[4*r2+1] * s0e + row[r2*4+1] * s1e) * inv;
        o.z = (Oc0[4*r2+2] * s0e + row[r2*4+2] * s1e) * inv;
        o.w = (Oc0[4*r2+3] * s0e + row[r2*4+3] * s1e) * inv;
        *(float4*)(orow + r2 * 8 + h4) = o;
        o.x = (Oc1[4*r2+0] * s0e + row[16+r2*4+0] * s1e) * inv;
        o.y = (Oc1[4*r2+1] * s0e + row[16+r2*4+1] * s1e) * inv;
        o.z = (Oc1[4*r2+2] * s0e + row[16+r2*4+2] * s1e) * inv;
        o.w = (Oc1[4*r2+3] * s0e + row[16+r2*4+3] * s1e) * inv;
        *(float4*)(orow + 32 + r2 * 8 + h4) = o;
      }
    }
    __syncthreads();
  }
}

extern "C" void kernel_launch(void* const* d_in, const int* in_sizes, int n_in,
                              void* d_out, int out_size, void* d_ws, size_t ws_size,
                              hipStream_t stream) {
  const float* Q    = (const float*)d_in[0];
  const float* K    = (const float*)d_in[1];
  const float* V    = (const float*)d_in[2];
  const float* mask = (const float*)d_in[3];
  const float* klm  = (const float*)d_in[4];
  const float* ptab = (const float*)d_in[5];
  const int*   pos  = (const int*)d_in[6];
  float* out = (float*)d_out;

  char* ws = (char*)d_ws;
  // layout: pospk 512K | Kp 8M | Vt 8M | flags 2KB
  unsigned int*   pospk = (unsigned int*)ws;
  unsigned short* Kp    = (unsigned short*)(ws + (1 << 19));
  unsigned short* Vt    = (unsigned short*)(ws + (1 << 19) + (8 << 20));
  int*            flags = (int*)(ws + (1 << 19) + (16 << 20));
  const size_t need = (size_t)(1 << 19) + (size_t)(16 << 20) + 2048;
  if (ws_size < need) flags = nullptr;   // k_attn falls back to hcm=1

  k_prep2<<<512, 512, 0, stream>>>(pos, pospk, K, Kp, V, Vt, mask, klm, flags);
  k_attn<<<512, 512, 0, stream>>>(Q, mask, klm, ptab, pospk, Kp, Vt, flags, out);
}